// Round 12
// baseline (3702.544 us; speedup 1.0000x reference)
//
#include <hip/hip_runtime.h>
#include <math.h>

#define NN   10000
#define NE   80000
#define NG   64
#define HID  256
#define RBFK 16
#define NDEP 6
#define KA   16
#define KC   6
#define KE   5
#define DE   85
#define CATW 784

typedef __attribute__((ext_vector_type(8))) short bf16x8;
typedef __attribute__((ext_vector_type(4))) float f32x4;

static __device__ __forceinline__ float silu_f(float v) { return v / (1.0f + expf(-v)); }

static __device__ __forceinline__ unsigned short f2bf(float f) {
  union { float f; unsigned int u; } v; v.f = f;
  unsigned int r = v.u + 0x7fff + ((v.u >> 16) & 1);
  return (unsigned short)(r >> 16);
}
static __device__ __forceinline__ float bf2f(unsigned short h) {
  union { unsigned int u; float f; } v; v.u = ((unsigned int)h) << 16;
  return v.f;
}

static __device__ __forceinline__ void gload16(const void* g, void* l) {
  __builtin_amdgcn_global_load_lds((const __attribute__((address_space(1))) unsigned int*)g,
                                   (__attribute__((address_space(3))) unsigned int*)l, 16, 0, 0);
}

// ---------------- weight transpose-converts ----------------
__global__ void convw_plain(const float* __restrict__ W, unsigned short* __restrict__ Wt, int K,
                            long long wt_dstride, int wt_rowoff) {
  __shared__ float T[32][65];
  int k0 = blockIdx.x * 32, n0 = blockIdx.y * 64, d = blockIdx.z;
  int tid = threadIdx.x;
  int nn = tid & 63, kr = tid >> 6;
  const float* Wd = W + (size_t)d * K * 256;
#pragma unroll
  for (int i = 0; i < 8; ++i) {
    int k = kr + i * 4;
    T[k][nn] = Wd[(size_t)(k0 + k) * 256 + n0 + nn];
  }
  __syncthreads();
  unsigned short* Wtd = Wt + (size_t)d * wt_dstride;
  int kk = tid & 31, nr = tid >> 5;
#pragma unroll
  for (int i = 0; i < 8; ++i) {
    int n = nr + i * 8;
    Wtd[(size_t)(wt_rowoff + n0 + n) * K + k0 + kk] = f2bf(T[kk][n]);
  }
}

__global__ void convw_nodeblk(const float* __restrict__ W, unsigned short* __restrict__ Wt,
                              int src_k0, int nt_base) {
  __shared__ float T[32][65];
  int k0 = blockIdx.x * 32, n0 = blockIdx.y * 64, d = blockIdx.z;
  int tid = threadIdx.x;
  int nn = tid & 63, kr = tid >> 6;
  const float* Wd = W + (size_t)d * CATW * 256;
#pragma unroll
  for (int i = 0; i < 8; ++i) {
    int k = kr + i * 4;
    T[k][nn] = Wd[(size_t)(src_k0 + k0 + k) * 256 + n0 + nn];
  }
  __syncthreads();
  unsigned short* Wtd = Wt + (size_t)d * 1024 * 256;
  int kk = tid & 31, nr = tid >> 5;
#pragma unroll
  for (int i = 0; i < 8; ++i) {
    int n = nr + i * 8;
    Wtd[(size_t)(nt_base + n0 + n) * 256 + k0 + kk] = f2bf(T[kk][n]);
  }
}

// wR [D][16][512] bf16: rbf rows (512..527) of phim_W1 (cols 0:256) / psim_W1 (cols 256:512)
__global__ void convw_rbf(const float* __restrict__ phimW1, const float* __restrict__ psimW1,
                          unsigned short* __restrict__ wR) {
  int d = blockIdx.x, j = threadIdx.x;
  int jj = j & 255;
  const float* W = (j < 256) ? phimW1 : psimW1;
  for (int k = 0; k < 16; ++k)
    wR[((size_t)d * 16 + k) * 512 + j] = f2bf(W[(size_t)d * CATW * 256 + (size_t)(512 + k) * 256 + jj]);
}

// ---------------- tables ----------------
__global__ void tables_kernel(const float* __restrict__ atom_W, const float* __restrict__ charge_W,
                              const float* __restrict__ bond_W, const float* __restrict__ fuse_W,
                              const float* __restrict__ fuse_b, const float* __restrict__ lift_W,
                              const float* __restrict__ lift_b,
                              float* __restrict__ tabA, float* __restrict__ tabC,
                              float* __restrict__ tabEf) {
  int r = blockIdx.x, k = threadIdx.x;
  if (r < KA) {
    float s = 0.f;
    for (int d = 0; d < DE; ++d) s += atom_W[r*DE + d] * fuse_W[d*HID + k];
    tabA[r*HID + k] = s + fuse_b[k];
  } else if (r < KA + KC) {
    int rr = r - KA;
    float s = 0.f;
    for (int d = 0; d < DE; ++d) s += charge_W[rr*DE + d] * fuse_W[(DE + d)*HID + k];
    tabC[rr*HID + k] = s;
  } else {
    int rr = r - KA - KC;
    float s = 0.f;
    for (int d = 0; d < DE; ++d) s += bond_W[rr*DE + d] * lift_W[d*HID + k];
    tabEf[rr*HID + k] = s + lift_b[k];
  }
}

// tabE1 [D][5][512] bf16 = tabEf @ W1_eemb (+ b1), phim cols 0:256, psim cols 256:512
__global__ void tabe1_kernel(const float* __restrict__ tabEf,
                             const float* __restrict__ phimW1, const float* __restrict__ phimb1,
                             const float* __restrict__ psimW1, const float* __restrict__ psimb1,
                             unsigned short* __restrict__ tabE1) {
  int r = blockIdx.x, d = blockIdx.y, j = threadIdx.x;
  const float* W = (j < 256) ? phimW1 : psimW1;
  const float* b = (j < 256) ? phimb1 : psimb1;
  int jj = j & 255;
  float s = b[d*256 + jj];
  for (int k = 0; k < 256; ++k)
    s += tabEf[r*256 + k] * W[(size_t)d*CATW*256 + (size_t)(528 + k)*256 + jj];
  tabE1[((size_t)d*5 + r)*512 + j] = f2bf(s);
}

// ---------------- node / edge init ----------------
__global__ void node_init_kernel(const float* __restrict__ a_t, const float* __restrict__ c_t,
                                 const float* __restrict__ g_a, const float* __restrict__ g_c,
                                 const float* __restrict__ x_t, const float* __restrict__ tabA,
                                 const float* __restrict__ tabC, float* __restrict__ h,
                                 unsigned short* __restrict__ hbf, float* __restrict__ x) {
  int n = blockIdx.x;
  __shared__ int s_ia, s_ic;
  if (threadIdx.x == 0) {
    float best = -1e30f; int bi = 0;
    for (int j = 0; j < KA; ++j) {
      float v = logf(fmaxf(a_t[n*KA + j], 1e-12f)) + g_a[n*KA + j];
      if (v > best) { best = v; bi = j; }
    }
    s_ia = bi;
  }
  if (threadIdx.x == 1) {
    float best = -1e30f; int bi = 0;
    for (int j = 0; j < KC; ++j) {
      float v = logf(fmaxf(c_t[n*KC + j], 1e-12f)) + g_c[n*KC + j];
      if (v > best) { best = v; bi = j; }
    }
    s_ic = bi;
  }
  __syncthreads();
  int k = threadIdx.x;
  float v = tabA[s_ia*HID + k] + tabC[s_ic*HID + k];
  h[n*HID + k] = v;
  hbf[n*HID + k] = f2bf(v);
  if (k < 3) x[n*3 + k] = x_t[n*3 + k];
}

__global__ void edge_init_kernel(const float* __restrict__ e_t, const float* __restrict__ g_e,
                                 int* __restrict__ ie) {
  int e = blockIdx.x * blockDim.x + threadIdx.x;
  if (e >= NE) return;
  float best = -1e30f; int bi = 0;
  for (int j = 0; j < KE; ++j) {
    float v = logf(fmaxf(e_t[e*KE + j], 1e-12f)) + g_e[e*KE + j];
    if (v > best) { best = v; bi = j; }
  }
  ie[e] = bi;
}

// ---------------- CSR build ----------------
__global__ void hist_kernel(const int* __restrict__ dst, int* __restrict__ deg) {
  int e = blockIdx.x * 256 + threadIdx.x;
  if (e < NE) atomicAdd(&deg[dst[e]], 1);
}

__global__ void scan_kernel(const int* __restrict__ deg, int* __restrict__ rowstart,
                            int* __restrict__ cursor) {
  __shared__ int tmp[1024];
  int t = threadIdx.x;
  int base = t * 10;
  int local[10];
  int s = 0;
#pragma unroll
  for (int i = 0; i < 10; ++i) { local[i] = deg[base + i]; s += local[i]; }
  tmp[t] = s;
  __syncthreads();
  for (int off = 1; off < 1024; off <<= 1) {
    int v = (t >= off) ? tmp[t - off] : 0;
    __syncthreads();
    tmp[t] += v;
    __syncthreads();
  }
  int run = (t == 0) ? 0 : tmp[t - 1];
#pragma unroll
  for (int i = 0; i < 10; ++i) {
    rowstart[base + i] = run; cursor[base + i] = run; run += local[i];
  }
  if (t == 1023) rowstart[10240] = run;
}

__global__ void fill_kernel(const int* __restrict__ dst, int* __restrict__ cursor,
                            int* __restrict__ eids) {
  int e = blockIdx.x * 256 + threadIdx.x;
  if (e >= NE) return;
  int pos = atomicAdd(&cursor[dst[e]], 1);
  eids[pos] = e;
}

__global__ void sortrows_kernel(const int* __restrict__ rowstart, int* __restrict__ eids) {
  int n = blockIdx.x * 256 + threadIdx.x;
  if (n >= NN) return;
  int s = rowstart[n], e = rowstart[n + 1];
  for (int i = s + 1; i < e; ++i) {
    int v = eids[i]; int j = i - 1;
    while (j >= s && eids[j] > v) { eids[j + 1] = eids[j]; --j; }
    eids[j + 1] = v;
  }
}

// ---------------- per-depth: rij + rbf(bf16) ----------------
__global__ void rbf_kernel(const float* __restrict__ x, const int* __restrict__ srcp,
                           const int* __restrict__ dstp, float* __restrict__ rij,
                           unsigned short* __restrict__ rbfb) {
  int e = blockIdx.x * blockDim.x + threadIdx.x;
  if (e >= NE) return;
  int s = srcp[e], d = dstp[e];
  float r0 = x[d*3+0] - x[s*3+0];
  float r1 = x[d*3+1] - x[s*3+1];
  float r2 = x[d*3+2] - x[s*3+2];
  rij[e*3+0] = r0; rij[e*3+1] = r1; rij[e*3+2] = r2;
  float dist = sqrtf(r0*r0 + r1*r1 + r2*r2);
#pragma unroll
  for (int k = 0; k < RBFK; ++k) {
    float z = (dist - 0.66666667f * (float)k) * 1.6f;
    rbfb[e*RBFK + k] = f2bf(expf(-0.5f * z * z));
  }
}

// ---------------- MFMA bf16 GEMM: BN=256, BK=64; BM=128 (512 thr) or SMALL BM=64 (256 thr) ----------------
// MODE 0: A bf16 [M][256], Kp=256
// MODE 2: A = [A | A2] (each [M][256]), Kp=512
// MODE 3: multi-chunk C: Cw = C + (bn>>8)*M*256 (no silu; bias = zeros)
// MODE 4: merged dual GEMM: rows >= Msplit use weight chunk 1 / bias2 / C2
// MODE 5: MODE 4 + fused combine A-staging: A-row(e) = silu(P[dst]+P[src]+tabE1[ie]+rbf@wR)
// GATE:   gout[row] = sum_col silu(acc+b1[col]) * gw2[col]
// LNOUT:  h/hbf = LayerNorm(h + acc + bias) * lng + lnb  (fused upd2+LN)
template<int MODE, bool SILU, bool GATE, bool LNOUT, bool SMALL>
__global__ __launch_bounds__(SMALL ? 256 : 512, 4) void mfma_gemm(
    const unsigned short* __restrict__ A, const unsigned short* __restrict__ A2,
    const unsigned short* __restrict__ Wt,
    const float* __restrict__ bias, const float* __restrict__ bias2,
    unsigned short* __restrict__ C, unsigned short* __restrict__ C2,
    int M, int Kp, int Msplit,
    const float* __restrict__ gw2, float* __restrict__ gout,
    float* __restrict__ hf, unsigned short* __restrict__ hb,
    const float* __restrict__ lng, const float* __restrict__ lnb,
    const int* __restrict__ srcp, const int* __restrict__ dstp, const int* __restrict__ iep,
    const unsigned short* __restrict__ Pg, const unsigned short* __restrict__ rbfb,
    const unsigned short* __restrict__ tE1, const unsigned short* __restrict__ wRt) {
  constexpr int BM = SMALL ? 64 : 128;
  constexpr int BQ = SMALL ? 8 : 4;            // B-stage issues per wave
  __shared__ unsigned short lds[SMALL ? 20480 : 24576];   // As BM*64 + Bs 256*64
  unsigned short* As = lds;                    // [BM][64] XOR-swizzled
  unsigned short* Bs = lds + BM * 64;          // [256][64] XOR-swizzled
  const int tid = threadIdx.x;
  const int bn = blockIdx.x * 256;
  const int bm = blockIdx.y * BM;
  const int lane = tid & 63;
  const int w = tid >> 6;
  const int wr = SMALL ? 0 : (w >> 2);
  const int wc = SMALL ? w : (w & 3);
  const int subrow = lane >> 3;
  const int kd = 8 * ((lane & 7) ^ subrow);

  const bool half2 = (MODE == 4 || MODE == 5) && (bm >= Msplit);
  const unsigned short* Wb = Wt + (half2 ? 256 * 256 : 0);

  unsigned int offB[BQ];
#pragma unroll
  for (int q = 0; q < BQ; ++q)
    offB[q] = (unsigned)(bn + w * (BQ * 8) + q * 8 + subrow) * (unsigned)Kp;

  unsigned int offA[2];
  // MODE5 per-row combine state
  const unsigned short* p0a[2];
  const unsigned short* p1a[2];
  const unsigned short* tea[2];
  float rbv[2][16];
  const int wcol0 = half2 ? 256 : 0;
#pragma unroll
  for (int q = 0; q < 2; ++q) {
    int m = bm + w * 16 + q * 8 + subrow;
    int mc = (m < M) ? m : (M - 1);
    offA[q] = (unsigned)mc * 256u;
    if (MODE == 5) {
      int e = m - (half2 ? Msplit : 0);
      int ds = dstp[e], sr = srcp[e], ib = iep[e];
      p0a[q] = Pg + ((size_t)(half2 ? 2 : 0) * NN + ds) * 256;
      p1a[q] = Pg + ((size_t)(half2 ? 3 : 1) * NN + sr) * 256;
      tea[q] = tE1 + (size_t)ib * 512 + wcol0;
      bf16x8 rv0 = *(const bf16x8*)&rbfb[(size_t)e * RBFK];
      bf16x8 rv1 = *(const bf16x8*)&rbfb[(size_t)e * RBFK + 8];
#pragma unroll
      for (int j = 0; j < 8; ++j) {
        rbv[q][j]     = bf2f((unsigned short)rv0[j]);
        rbv[q][8 + j] = bf2f((unsigned short)rv1[j]);
      }
    }
  }

  const int nt = Kp >> 6;
  f32x4 acc[4][4] = {};

  for (int t = 0; t < nt; ++t) {
    const int k0 = t << 6;
    if (MODE == 5) {
#pragma unroll
      for (int q = 0; q < 2; ++q) {
        const int j0 = k0 + kd;
        bf16x8 pa = *(const bf16x8*)&p0a[q][j0];
        bf16x8 pb = *(const bf16x8*)&p1a[q][j0];
        bf16x8 te = *(const bf16x8*)&tea[q][j0];
        float zv[8];
#pragma unroll
        for (int j = 0; j < 8; ++j)
          zv[j] = bf2f((unsigned short)pa[j]) + bf2f((unsigned short)pb[j]) + bf2f((unsigned short)te[j]);
#pragma unroll
        for (int k = 0; k < 16; ++k) {
          bf16x8 wv = *(const bf16x8*)&wRt[k * 512 + wcol0 + j0];
          float rk = rbv[q][k];
#pragma unroll
          for (int j = 0; j < 8; ++j)
            zv[j] += rk * bf2f((unsigned short)wv[j]);
        }
        unsigned short ov[8];
#pragma unroll
        for (int j = 0; j < 8; ++j) ov[j] = f2bf(silu_f(zv[j]));
        *(uint4*)((char*)As + w * 2048 + q * 1024 + lane * 16) = *(uint4*)ov;
      }
    } else {
#pragma unroll
      for (int q = 0; q < 2; ++q) {
        const unsigned short* gp;
        if (MODE == 2) gp = (k0 < 256) ? (A + offA[q] + k0 + kd) : (A2 + offA[q] + (k0 - 256) + kd);
        else gp = A + offA[q] + k0 + kd;
        gload16(gp, (char*)As + w * 2048 + q * 1024);
      }
    }
#pragma unroll
    for (int q = 0; q < BQ; ++q)
      gload16(Wb + offB[q] + k0 + kd, (char*)Bs + w * (BQ * 1024) + q * 1024);
    __syncthreads();
#pragma unroll
    for (int ks = 0; ks < 2; ++ks) {
      const int kb = (ks * 64 + ((lane >> 4) << 4)) ^ ((lane & 7) << 4);
      bf16x8 bfv[4];
#pragma unroll
      for (int j = 0; j < 4; ++j)
        bfv[j] = *(const bf16x8*)((const char*)Bs + (wc * 64 + j * 16 + (lane & 15)) * 128 + kb);
#pragma unroll
      for (int i = 0; i < 4; ++i) {
        bf16x8 af = *(const bf16x8*)((const char*)As + (wr * 64 + i * 16 + (lane & 15)) * 128 + kb);
#pragma unroll
        for (int j = 0; j < 4; ++j)
          acc[i][j] = __builtin_amdgcn_mfma_f32_16x16x32_bf16(af, bfv[j], acc[i][j], 0, 0, 0);
      }
    }
    __syncthreads();
  }

  if (GATE) {
    float bcol[4], wcol[4];
#pragma unroll
    for (int j = 0; j < 4; ++j) {
      int col = wc * 64 + j * 16 + (lane & 15);
      bcol[j] = bias[col];
      wcol[j] = gw2[col];
    }
    float* part = (float*)lds;   // [4][BM]
#pragma unroll
    for (int i = 0; i < 4; ++i) {
#pragma unroll
      for (int q = 0; q < 4; ++q) {
        float lsum = 0.f;
#pragma unroll
        for (int j = 0; j < 4; ++j)
          lsum += silu_f(acc[i][j][q] + bcol[j]) * wcol[j];
        lsum += __shfl_xor(lsum, 1, 64);
        lsum += __shfl_xor(lsum, 2, 64);
        lsum += __shfl_xor(lsum, 4, 64);
        lsum += __shfl_xor(lsum, 8, 64);
        if ((lane & 15) == 0) {
          int rl = wr * 64 + i * 16 + ((lane >> 4) << 2) + q;
          part[wc * BM + rl] = lsum;
        }
      }
    }
    __syncthreads();
    if (tid < BM)
      gout[bm + tid] = part[tid] + part[BM + tid] + part[2*BM + tid] + part[3*BM + tid];
    return;
  }

  if (LNOUT) {
    float bcol[4], lgc[4], lbc[4];
#pragma unroll
    for (int j = 0; j < 4; ++j) {
      int col = wc * 64 + j * 16 + (lane & 15);
      bcol[j] = bias[col]; lgc[j] = lng[col]; lbc[j] = lnb[col];
    }
    float* part = (float*)lds;       // [4][BM]
    float* stat = part + 4 * BM;     // mu[BM], rstd[BM]
#pragma unroll
    for (int i = 0; i < 4; ++i)
#pragma unroll
      for (int q = 0; q < 4; ++q) {
        int rl = wr * 64 + i * 16 + ((lane >> 4) << 2) + q;
        int grow = bm + rl;
        float s = 0.f;
#pragma unroll
        for (int j = 0; j < 4; ++j) {
          int col = wc * 64 + j * 16 + (lane & 15);
          float hv = (grow < M) ? hf[(size_t)grow * 256 + col] : 0.f;
          float zz = acc[i][j][q] + bcol[j] + hv;
          acc[i][j][q] = zz;
          s += zz;
        }
        s += __shfl_xor(s, 1, 64); s += __shfl_xor(s, 2, 64);
        s += __shfl_xor(s, 4, 64); s += __shfl_xor(s, 8, 64);
        if ((lane & 15) == 0) part[wc * BM + rl] = s;
      }
    __syncthreads();
    if (tid < BM)
      stat[tid] = (part[tid] + part[BM + tid] + part[2*BM + tid] + part[3*BM + tid]) * (1.f / 256.f);
    __syncthreads();
#pragma unroll
    for (int i = 0; i < 4; ++i)
#pragma unroll
      for (int q = 0; q < 4; ++q) {
        int rl = wr * 64 + i * 16 + ((lane >> 4) << 2) + q;
        float mu = stat[rl];
        float s2 = 0.f;
#pragma unroll
        for (int j = 0; j < 4; ++j) { float d_ = acc[i][j][q] - mu; s2 += d_ * d_; }
        s2 += __shfl_xor(s2, 1, 64); s2 += __shfl_xor(s2, 2, 64);
        s2 += __shfl_xor(s2, 4, 64); s2 += __shfl_xor(s2, 8, 64);
        if ((lane & 15) == 0) part[wc * BM + rl] = s2;
      }
    __syncthreads();
    if (tid < BM)
      stat[BM + tid] = 1.f / sqrtf((part[tid] + part[BM + tid] + part[2*BM + tid] + part[3*BM + tid]) * (1.f / 256.f) + 1e-5f);
    __syncthreads();
#pragma unroll
    for (int i = 0; i < 4; ++i)
#pragma unroll
      for (int q = 0; q < 4; ++q) {
        int rl = wr * 64 + i * 16 + ((lane >> 4) << 2) + q;
        int grow = bm + rl;
        if (grow < M) {
          float mu = stat[rl], rs = stat[BM + rl];
#pragma unroll
          for (int j = 0; j < 4; ++j) {
            int col = wc * 64 + j * 16 + (lane & 15);
            float o = (acc[i][j][q] - mu) * rs * lgc[j] + lbc[j];
            hf[(size_t)grow * 256 + col] = o;
            hb[(size_t)grow * 256 + col] = f2bf(o);
          }
        }
      }
    return;
  }

  // normal epilogue: coalesced C-store via LDS transpose
  const float* biasw = bias;
  unsigned short* Cw = C;
  int rowoff = 0;
  if (MODE == 3) Cw = C + (size_t)(bn >> 8) * (size_t)M * 256;
  if ((MODE == 4 || MODE == 5) && half2) { biasw = bias2; Cw = C2; rowoff = Msplit; }

  float bcol[4];
#pragma unroll
  for (int j = 0; j < 4; ++j) bcol[j] = biasw[wc * 64 + j * 16 + (lane & 15)];

  unsigned short* T = lds;   // [BM][136]
#pragma unroll
  for (int hh = 0; hh < 2; ++hh) {
    if ((wc >> 1) == hh) {
#pragma unroll
      for (int i = 0; i < 4; ++i)
#pragma unroll
        for (int j = 0; j < 4; ++j)
#pragma unroll
          for (int q = 0; q < 4; ++q) {
            int rl = wr * 64 + i * 16 + ((lane >> 4) << 2) + q;
            int cl = (wc & 1) * 64 + j * 16 + (lane & 15);
            float v = acc[i][j][q] + bcol[j];
            if (SILU) v = silu_f(v);
            T[rl * 136 + cl] = f2bf(v);
          }
    }
    __syncthreads();
#pragma unroll
    for (int it = 0; it < 4; ++it) {
      int row = it * (BM / 4) + (tid >> 4);
      int grow = bm + row;
      if (grow < M) {
        uint4 v = *(const uint4*)&T[row * 136 + (tid & 15) * 8];
        *(uint4*)&Cw[(size_t)(grow - rowoff) * 256 + hh * 128 + (tid & 15) * 8] = v;
      }
    }
    __syncthreads();
  }
}

// ---------------- CSR gather: pm_sum (bf16 out) + dx + x update ----------------
__global__ void gather_pm_dx(const unsigned short* __restrict__ pm, const float* __restrict__ gate,
                             const float* __restrict__ rij, const int* __restrict__ rowstart,
                             const int* __restrict__ eids, const float* __restrict__ gb2,
                             unsigned short* __restrict__ pmbf, float* __restrict__ x) {
  int n = blockIdx.x, k = threadIdx.x;
  int s = rowstart[n], e1 = rowstart[n + 1];
  float acc = 0.f, dx = 0.f;
  float b2 = gb2[0];
  for (int t = s; t < e1; ++t) {
    int e = eids[t];
    acc += bf2f(pm[(size_t)e*HID + k]);
    if (k < 3) dx += rij[e*3 + k] * (gate[e] + b2);
  }
  pmbf[(size_t)n*HID + k] = f2bf(acc);
  if (k < 3) x[n*3 + k] += dx;
}

// ---------------- readout ----------------
__global__ void graph_acc_kernel(const float* __restrict__ h, const int* __restrict__ ng,
                                 float* __restrict__ hg, float* __restrict__ cnt) {
  int n = blockIdx.x, k = threadIdx.x;
  int g = ng[n];
  atomicAdd(&hg[(size_t)g*HID + k], h[(size_t)n*HID + k]);
  if (k == 0) atomicAdd(&cnt[g], 1.0f);
}

__global__ void head_kernel(const float* __restrict__ hg, const float* __restrict__ cnt,
                            const float* __restrict__ head_W, const float* __restrict__ head_b,
                            float* __restrict__ out) {
  int g = threadIdx.x;
  if (g >= NG) return;
  float dot = 0.f;
  for (int k = 0; k < HID; ++k) dot += hg[(size_t)g*HID + k] * head_W[k];
  float c = fmaxf(cnt[g], 1.0f);
  float v = (dot / c + head_b[0]) * 0.5f;
  out[g] = 1.0f / (1.0f + expf(-v));
}

extern "C" void kernel_launch(void* const* d_in, const int* in_sizes, int n_in,
                              void* d_out, int out_size, void* d_ws, size_t ws_size,
                              hipStream_t stream) {
  (void)in_sizes; (void)n_in; (void)out_size; (void)ws_size;
  const float* a_t      = (const float*)d_in[0];
  const float* c_t      = (const float*)d_in[1];
  const float* e_t      = (const float*)d_in[2];
  const float* x_t      = (const float*)d_in[3];
  const float* g_a      = (const float*)d_in[4];
  const float* g_c      = (const float*)d_in[5];
  const float* g_e      = (const float*)d_in[6];
  const float* atom_W   = (const float*)d_in[7];
  const float* charge_W = (const float*)d_in[8];
  const float* bond_W   = (const float*)d_in[9];
  const float* fuse_W   = (const float*)d_in[10];
  const float* fuse_b   = (const float*)d_in[11];
  const float* lift_W   = (const float*)d_in[12];
  const float* lift_b   = (const float*)d_in[13];
  const float* phim_W1  = (const float*)d_in[14];
  const float* phim_b1  = (const float*)d_in[15];
  const float* phim_W2  = (const float*)d_in[16];
  const float* phim_b2  = (const float*)d_in[17];
  const float* phix_W1  = (const float*)d_in[18];
  const float* phix_b1  = (const float*)d_in[19];
  const float* phix_W2  = (const float*)d_in[20];
  const float* phix_b2  = (const float*)d_in[21];
  const float* psim_W1  = (const float*)d_in[22];
  const float* psim_b1  = (const float*)d_in[23];
  const float* psim_W2  = (const float*)d_in[24];
  const float* psim_b2  = (const float*)d_in[25];
  const float* updh_W1  = (const float*)d_in[26];
  const float* updh_b1  = (const float*)d_in[27];
  const float* updh_W2  = (const float*)d_in[28];
  const float* updh_b2  = (const float*)d_in[29];
  const float* ln_g     = (const float*)d_in[30];
  const float* ln_b     = (const float*)d_in[31];
  const float* head_W   = (const float*)d_in[32];
  const float* head_b   = (const float*)d_in[33];
  const int*   src      = (const int*)d_in[34];
  const int*   dst      = (const int*)d_in[35];
  const int*   ngraph   = (const int*)d_in[36];
  float* out = (float*)d_out;

  char* p = (char*)d_ws;
  auto carve = [&](size_t bytes) -> char* {
    char* r = p; p += (bytes + 255) & ~(size_t)255; return r;
  };
  float*          h     = (float*)carve((size_t)NN*HID*4);
  unsigned short* hbf   = (unsigned short*)carve((size_t)NN*HID*2);
  float*          xpos  = (float*)carve((size_t)NN*3*4);
  int*            ie    = (int*)carve((size_t)NE*4);
  float*          tabA  = (float*)carve((size_t)KA*HID*4);
  float*          tabC  = (float*)carve((size_t)KC*HID*4);
  float*          tabEf = (float*)carve((size_t)KE*HID*4);
  unsigned short* rbfb  = (unsigned short*)carve((size_t)NE*RBFK*2);
  float*          rij   = (float*)carve((size_t)NE*3*4);
  float*          gate  = (float*)carve((size_t)NE*4);
  unsigned short* pmbf  = (unsigned short*)carve((size_t)NN*HID*2);
  float*          zbias = (float*)carve(256*4);
  size_t hg_bytes = (size_t)NG*HID*4 + (size_t)NG*4;
  float*          hg    = (float*)carve(hg_bytes);
  float*          cnt   = hg + (size_t)NG*HID;
  unsigned short* bufM  = (unsigned short*)carve((size_t)NE*HID*2);    // m
  unsigned short* bufPM = (unsigned short*)carve((size_t)NE*HID*2);    // pm
  unsigned short* P     = (unsigned short*)carve((size_t)4*NN*HID*2);
  // CSR
  int* deg      = (int*)carve(10240*4);
  int* cursor   = (int*)carve(10240*4);
  int* rowstart = (int*)carve(10241*4);
  int* eids     = (int*)carve((size_t)NE*4);
  // transposed bf16 weights
  unsigned short* wNode  = (unsigned short*)carve((size_t)NDEP*1024*256*2);
  unsigned short* wMPM   = (unsigned short*)carve((size_t)NDEP*512*256*2);   // [phimW2 | psimW2]
  unsigned short* wPhix1 = (unsigned short*)carve((size_t)NDEP*256*256*2);
  unsigned short* wUpd1  = (unsigned short*)carve((size_t)NDEP*256*512*2);
  unsigned short* wUpd2  = (unsigned short*)carve((size_t)NDEP*256*256*2);
  unsigned short* wRbf   = (unsigned short*)carve((size_t)NDEP*16*512*2);
  unsigned short* tabE1  = (unsigned short*)carve((size_t)NDEP*5*512*2);

  // ---- weight conversion ----
  convw_nodeblk<<<dim3(8,4,NDEP), 256, 0, stream>>>(phim_W1, wNode, 0,   0);
  convw_nodeblk<<<dim3(8,4,NDEP), 256, 0, stream>>>(phim_W1, wNode, 256, 256);
  convw_nodeblk<<<dim3(8,4,NDEP), 256, 0, stream>>>(psim_W1, wNode, 0,   512);
  convw_nodeblk<<<dim3(8,4,NDEP), 256, 0, stream>>>(psim_W1, wNode, 256, 768);
  convw_plain<<<dim3(8,4,NDEP), 256, 0, stream>>>(phim_W2, wMPM, 256, 512*256, 0);
  convw_plain<<<dim3(8,4,NDEP), 256, 0, stream>>>(psim_W2, wMPM, 256, 512*256, 256);
  convw_plain<<<dim3(8,4,NDEP), 256, 0, stream>>>(phix_W1, wPhix1, 256, 256*256, 0);
  convw_plain<<<dim3(8,4,NDEP), 256, 0, stream>>>(updh_W2, wUpd2, 256, 256*256, 0);
  convw_plain<<<dim3(16,4,NDEP), 256, 0, stream>>>(updh_W1, wUpd1, 512, 256*512, 0);
  convw_rbf<<<NDEP, 512, 0, stream>>>(phim_W1, psim_W1, wRbf);
  hipMemsetAsync(zbias, 0, 256*4, stream);

  tables_kernel<<<KA + KC + KE, 256, 0, stream>>>(atom_W, charge_W, bond_W, fuse_W, fuse_b,
                                                  lift_W, lift_b, tabA, tabC, tabEf);
  tabe1_kernel<<<dim3(5, NDEP), 512, 0, stream>>>(tabEf, phim_W1, phim_b1, psim_W1, psim_b1, tabE1);
  node_init_kernel<<<NN, 256, 0, stream>>>(a_t, c_t, g_a, g_c, x_t, tabA, tabC, h, hbf, xpos);
  edge_init_kernel<<<(NE + 255)/256, 256, 0, stream>>>(e_t, g_e, ie);

  // ---- CSR build ----
  hipMemsetAsync(deg, 0, 10240*4, stream);
  hist_kernel<<<(NE + 255)/256, 256, 0, stream>>>(dst, deg);
  scan_kernel<<<1, 1024, 0, stream>>>(deg, rowstart, cursor);
  fill_kernel<<<(NE + 255)/256, 256, 0, stream>>>(dst, cursor, eids);
  sortrows_kernel<<<(NN + 255)/256, 256, 0, stream>>>(rowstart, eids);

  dim3 gridP(4, (NN + 63)/64);     // SMALL: BM=64
  dim3 gridE(1, NE/128);
  dim3 gridE2(1, 2*NE/128);
  dim3 gridNS(1, (NN + 63)/64);    // SMALL node GEMMs

  for (int d = 0; d < NDEP; ++d) {
    const float* pb2m = phim_b2 + (size_t)d*HID;
    const float* pxb1 = phix_b1 + (size_t)d*HID;
    const float* pxW2 = phix_W2 + (size_t)d*HID;
    const float* pxb2 = phix_b2 + (size_t)d;
    const float* psb2 = psim_b2 + (size_t)d*HID;
    const float* pub1 = updh_b1 + (size_t)d*HID;
    const float* pub2 = updh_b2 + (size_t)d*HID;

    // rij + rbf (bf16)
    rbf_kernel<<<(NE + 255)/256, 256, 0, stream>>>(xpos, src, dst, rij, rbfb);
    // P = h @ [W1_phim_dst | W1_phim_src | W1_psim_dst | W1_psim_src]  (SMALL tiles)
    mfma_gemm<3, false, false, false, true><<<gridP, 256, 0, stream>>>(
        hbf, nullptr, wNode + (size_t)d*1024*256, zbias, nullptr, P, nullptr, NN, 256, 0,
        nullptr, nullptr, nullptr, nullptr, nullptr, nullptr,
        nullptr, nullptr, nullptr, nullptr, nullptr, nullptr, nullptr);
    // fused: {c1,ps1} built in-staging; m = silu(c1 @ phim_W2 + b2) ; pm = silu(ps1 @ psim_W2 + b2)
    mfma_gemm<5, true, false, false, false><<<gridE2, 512, 0, stream>>>(
        nullptr, nullptr, wMPM + (size_t)d*512*256, pb2m, psb2, bufM, bufPM, 2*NE, 256, NE,
        nullptr, nullptr, nullptr, nullptr, nullptr, nullptr,
        src, dst, ie, P, rbfb, tabE1 + (size_t)d*5*512, wRbf + (size_t)d*16*512);
    // gate = silu(m @ phix_W1 + b1) @ phix_W2
    mfma_gemm<0, false, true, false, false><<<gridE, 512, 0, stream>>>(
        bufM, nullptr, wPhix1 + (size_t)d*256*256, pxb1, nullptr, nullptr, nullptr, NE, 256, 0,
        pxW2, gate, nullptr, nullptr, nullptr, nullptr,
        nullptr, nullptr, nullptr, nullptr, nullptr, nullptr, nullptr);
    // pm_sum -> pmbf ; x += dx
    gather_pm_dx<<<NN, 256, 0, stream>>>(bufPM, gate, rij, rowstart, eids, pxb2, pmbf, xpos);
    // u1 = silu([h, pm] @ updh_W1 + b1)  (SMALL tiles)
    mfma_gemm<2, true, false, false, true><<<gridNS, 256, 0, stream>>>(
        hbf, pmbf, wUpd1 + (size_t)d*256*512, pub1, nullptr, bufM, nullptr, NN, 512, 0,
        nullptr, nullptr, nullptr, nullptr, nullptr, nullptr,
        nullptr, nullptr, nullptr, nullptr, nullptr, nullptr, nullptr);
    // h = LN(h + u1 @ updh_W2 + b2)  (fused, SMALL tiles)
    mfma_gemm<0, false, false, true, true><<<gridNS, 256, 0, stream>>>(
        bufM, nullptr, wUpd2 + (size_t)d*256*256, pub2, nullptr, nullptr, nullptr, NN, 256, 0,
        nullptr, nullptr, h, hbf, ln_g + (size_t)d*HID, ln_b + (size_t)d*HID,
        nullptr, nullptr, nullptr, nullptr, nullptr, nullptr, nullptr);
  }

  hipMemsetAsync(hg, 0, hg_bytes, stream);
  graph_acc_kernel<<<NN, 256, 0, stream>>>(h, ngraph, hg, cnt);
  head_kernel<<<1, 64, 0, stream>>>(hg, cnt, head_W, head_b, out);
}

// Round 13
// 1873.616 us; speedup vs baseline: 1.9761x; 1.9761x over previous
//
#include <hip/hip_runtime.h>
#include <math.h>

#define NN   10000
#define NE   80000
#define NG   64
#define HID  256
#define RBFK 16
#define NDEP 6
#define KA   16
#define KC   6
#define KE   5
#define DE   85
#define CATW 784

typedef __attribute__((ext_vector_type(8))) short bf16x8;
typedef __attribute__((ext_vector_type(4))) float f32x4;

static __device__ __forceinline__ float silu_f(float v) { return v / (1.0f + expf(-v)); }

static __device__ __forceinline__ unsigned short f2bf(float f) {
  union { float f; unsigned int u; } v; v.f = f;
  unsigned int r = v.u + 0x7fff + ((v.u >> 16) & 1);
  return (unsigned short)(r >> 16);
}
static __device__ __forceinline__ float bf2f(unsigned short h) {
  union { unsigned int u; float f; } v; v.u = ((unsigned int)h) << 16;
  return v.f;
}

static __device__ __forceinline__ void gload16(const void* g, void* l) {
  __builtin_amdgcn_global_load_lds((const __attribute__((address_space(1))) unsigned int*)g,
                                   (__attribute__((address_space(3))) unsigned int*)l, 16, 0, 0);
}

// ---------------- weight transpose-converts ----------------
__global__ void convw_plain(const float* __restrict__ W, unsigned short* __restrict__ Wt, int K,
                            long long wt_dstride, int wt_rowoff) {
  __shared__ float T[32][65];
  int k0 = blockIdx.x * 32, n0 = blockIdx.y * 64, d = blockIdx.z;
  int tid = threadIdx.x;
  int nn = tid & 63, kr = tid >> 6;
  const float* Wd = W + (size_t)d * K * 256;
#pragma unroll
  for (int i = 0; i < 8; ++i) {
    int k = kr + i * 4;
    T[k][nn] = Wd[(size_t)(k0 + k) * 256 + n0 + nn];
  }
  __syncthreads();
  unsigned short* Wtd = Wt + (size_t)d * wt_dstride;
  int kk = tid & 31, nr = tid >> 5;
#pragma unroll
  for (int i = 0; i < 8; ++i) {
    int n = nr + i * 8;
    Wtd[(size_t)(wt_rowoff + n0 + n) * K + k0 + kk] = f2bf(T[kk][n]);
  }
}

__global__ void convw_nodeblk(const float* __restrict__ W, unsigned short* __restrict__ Wt,
                              int src_k0, int nt_base) {
  __shared__ float T[32][65];
  int k0 = blockIdx.x * 32, n0 = blockIdx.y * 64, d = blockIdx.z;
  int tid = threadIdx.x;
  int nn = tid & 63, kr = tid >> 6;
  const float* Wd = W + (size_t)d * CATW * 256;
#pragma unroll
  for (int i = 0; i < 8; ++i) {
    int k = kr + i * 4;
    T[k][nn] = Wd[(size_t)(src_k0 + k0 + k) * 256 + n0 + nn];
  }
  __syncthreads();
  unsigned short* Wtd = Wt + (size_t)d * 1024 * 256;
  int kk = tid & 31, nr = tid >> 5;
#pragma unroll
  for (int i = 0; i < 8; ++i) {
    int n = nr + i * 8;
    Wtd[(size_t)(nt_base + n0 + n) * 256 + k0 + kk] = f2bf(T[kk][n]);
  }
}

// wR [D][16][512] bf16: rbf rows (512..527) of phim_W1 (cols 0:256) / psim_W1 (cols 256:512)
__global__ void convw_rbf(const float* __restrict__ phimW1, const float* __restrict__ psimW1,
                          unsigned short* __restrict__ wR) {
  int d = blockIdx.x, j = threadIdx.x;
  int jj = j & 255;
  const float* W = (j < 256) ? phimW1 : psimW1;
  for (int k = 0; k < 16; ++k)
    wR[((size_t)d * 16 + k) * 512 + j] = f2bf(W[(size_t)d * CATW * 256 + (size_t)(512 + k) * 256 + jj]);
}

// ---------------- tables ----------------
__global__ void tables_kernel(const float* __restrict__ atom_W, const float* __restrict__ charge_W,
                              const float* __restrict__ bond_W, const float* __restrict__ fuse_W,
                              const float* __restrict__ fuse_b, const float* __restrict__ lift_W,
                              const float* __restrict__ lift_b,
                              float* __restrict__ tabA, float* __restrict__ tabC,
                              float* __restrict__ tabEf) {
  int r = blockIdx.x, k = threadIdx.x;
  if (r < KA) {
    float s = 0.f;
    for (int d = 0; d < DE; ++d) s += atom_W[r*DE + d] * fuse_W[d*HID + k];
    tabA[r*HID + k] = s + fuse_b[k];
  } else if (r < KA + KC) {
    int rr = r - KA;
    float s = 0.f;
    for (int d = 0; d < DE; ++d) s += charge_W[rr*DE + d] * fuse_W[(DE + d)*HID + k];
    tabC[rr*HID + k] = s;
  } else {
    int rr = r - KA - KC;
    float s = 0.f;
    for (int d = 0; d < DE; ++d) s += bond_W[rr*DE + d] * lift_W[d*HID + k];
    tabEf[rr*HID + k] = s + lift_b[k];
  }
}

// tabE1 [D][5][512] bf16 = tabEf @ W1_eemb (+ b1), phim cols 0:256, psim cols 256:512
__global__ void tabe1_kernel(const float* __restrict__ tabEf,
                             const float* __restrict__ phimW1, const float* __restrict__ phimb1,
                             const float* __restrict__ psimW1, const float* __restrict__ psimb1,
                             unsigned short* __restrict__ tabE1) {
  int r = blockIdx.x, d = blockIdx.y, j = threadIdx.x;
  const float* W = (j < 256) ? phimW1 : psimW1;
  const float* b = (j < 256) ? phimb1 : psimb1;
  int jj = j & 255;
  float s = b[d*256 + jj];
  for (int k = 0; k < 256; ++k)
    s += tabEf[r*256 + k] * W[(size_t)d*CATW*256 + (size_t)(528 + k)*256 + jj];
  tabE1[((size_t)d*5 + r)*512 + j] = f2bf(s);
}

// ---------------- node / edge init ----------------
__global__ void node_init_kernel(const float* __restrict__ a_t, const float* __restrict__ c_t,
                                 const float* __restrict__ g_a, const float* __restrict__ g_c,
                                 const float* __restrict__ x_t, const float* __restrict__ tabA,
                                 const float* __restrict__ tabC, float* __restrict__ h,
                                 unsigned short* __restrict__ hbf, float* __restrict__ x) {
  int n = blockIdx.x;
  __shared__ int s_ia, s_ic;
  if (threadIdx.x == 0) {
    float best = -1e30f; int bi = 0;
    for (int j = 0; j < KA; ++j) {
      float v = logf(fmaxf(a_t[n*KA + j], 1e-12f)) + g_a[n*KA + j];
      if (v > best) { best = v; bi = j; }
    }
    s_ia = bi;
  }
  if (threadIdx.x == 1) {
    float best = -1e30f; int bi = 0;
    for (int j = 0; j < KC; ++j) {
      float v = logf(fmaxf(c_t[n*KC + j], 1e-12f)) + g_c[n*KC + j];
      if (v > best) { best = v; bi = j; }
    }
    s_ic = bi;
  }
  __syncthreads();
  int k = threadIdx.x;
  float v = tabA[s_ia*HID + k] + tabC[s_ic*HID + k];
  h[n*HID + k] = v;
  hbf[n*HID + k] = f2bf(v);
  if (k < 3) x[n*3 + k] = x_t[n*3 + k];
}

__global__ void edge_init_kernel(const float* __restrict__ e_t, const float* __restrict__ g_e,
                                 int* __restrict__ ie) {
  int e = blockIdx.x * blockDim.x + threadIdx.x;
  if (e >= NE) return;
  float best = -1e30f; int bi = 0;
  for (int j = 0; j < KE; ++j) {
    float v = logf(fmaxf(e_t[e*KE + j], 1e-12f)) + g_e[e*KE + j];
    if (v > best) { best = v; bi = j; }
  }
  ie[e] = bi;
}

// ---------------- CSR build ----------------
__global__ void hist_kernel(const int* __restrict__ dst, int* __restrict__ deg) {
  int e = blockIdx.x * 256 + threadIdx.x;
  if (e < NE) atomicAdd(&deg[dst[e]], 1);
}

__global__ void scan_kernel(const int* __restrict__ deg, int* __restrict__ rowstart,
                            int* __restrict__ cursor) {
  __shared__ int tmp[1024];
  int t = threadIdx.x;
  int base = t * 10;
  int local[10];
  int s = 0;
#pragma unroll
  for (int i = 0; i < 10; ++i) { local[i] = deg[base + i]; s += local[i]; }
  tmp[t] = s;
  __syncthreads();
  for (int off = 1; off < 1024; off <<= 1) {
    int v = (t >= off) ? tmp[t - off] : 0;
    __syncthreads();
    tmp[t] += v;
    __syncthreads();
  }
  int run = (t == 0) ? 0 : tmp[t - 1];
#pragma unroll
  for (int i = 0; i < 10; ++i) {
    rowstart[base + i] = run; cursor[base + i] = run; run += local[i];
  }
  if (t == 1023) rowstart[10240] = run;
}

__global__ void fill_kernel(const int* __restrict__ dst, int* __restrict__ cursor,
                            int* __restrict__ eids) {
  int e = blockIdx.x * 256 + threadIdx.x;
  if (e >= NE) return;
  int pos = atomicAdd(&cursor[dst[e]], 1);
  eids[pos] = e;
}

__global__ void sortrows_kernel(const int* __restrict__ rowstart, int* __restrict__ eids) {
  int n = blockIdx.x * 256 + threadIdx.x;
  if (n >= NN) return;
  int s = rowstart[n], e = rowstart[n + 1];
  for (int i = s + 1; i < e; ++i) {
    int v = eids[i]; int j = i - 1;
    while (j >= s && eids[j] > v) { eids[j + 1] = eids[j]; --j; }
    eids[j + 1] = v;
  }
}

// ---------------- per-depth: rij ----------------
__global__ void rij_kernel(const float* __restrict__ x, const int* __restrict__ srcp,
                           const int* __restrict__ dstp, float* __restrict__ rij) {
  int e = blockIdx.x * blockDim.x + threadIdx.x;
  if (e >= NE) return;
  int s = srcp[e], d = dstp[e];
  rij[e*3+0] = x[d*3+0] - x[s*3+0];
  rij[e*3+1] = x[d*3+1] - x[s*3+1];
  rij[e*3+2] = x[d*3+2] - x[s*3+2];
}

// ---------------- combine2: one edge per 64 lanes; windowed rbf (8 centers) ----------------
// c1/ps1[e] = silu(P[dst] + P[src] + tabE1[ie] + sum_{k in window} rbf_k * wR[k])
__global__ __launch_bounds__(256) void combine2_kernel(
    const int* __restrict__ srcp, const int* __restrict__ dstp, const int* __restrict__ iep,
    const float* __restrict__ x,
    const unsigned short* __restrict__ P,      // [4][NN][256] bf16
    const unsigned short* __restrict__ tabE1,  // [5][512] bf16, this depth
    const unsigned short* __restrict__ wR,     // [16][512] bf16, this depth
    unsigned short* __restrict__ c1, unsigned short* __restrict__ ps1) {
  const int tid = threadIdx.x;
  const int lane = tid & 63;
  const int e = blockIdx.x * 4 + (tid >> 6);
  const int half = lane >> 5;            // 0: phim, 1: psim
  const int c8 = (lane & 31) * 8;        // col within 256
  const int ds = dstp[e], sr = srcp[e], ib = iep[e];
  float r0 = x[ds*3+0] - x[sr*3+0];
  float r1 = x[ds*3+1] - x[sr*3+1];
  float r2 = x[ds*3+2] - x[sr*3+2];
  float dist = sqrtf(r0*r0 + r1*r1 + r2*r2);
  int klo = (int)(dist * 1.5f) - 3;
  klo = klo < 0 ? 0 : (klo > 8 ? 8 : klo);
  const unsigned short* Pb0 = P + (size_t)(half * 2) * NN * 256;
  const unsigned short* Pb1 = P + (size_t)(half * 2 + 1) * NN * 256;
  bf16x8 pa = *(const bf16x8*)&Pb0[(size_t)ds * 256 + c8];
  bf16x8 pb = *(const bf16x8*)&Pb1[(size_t)sr * 256 + c8];
  bf16x8 te = *(const bf16x8*)&tabE1[(size_t)ib * 512 + lane * 8];
  float zv[8];
#pragma unroll
  for (int j = 0; j < 8; ++j)
    zv[j] = bf2f((unsigned short)pa[j]) + bf2f((unsigned short)pb[j]) + bf2f((unsigned short)te[j]);
#pragma unroll
  for (int kk = 0; kk < 8; ++kk) {
    int k = klo + kk;
    float z = (dist - 0.66666667f * (float)k) * 1.6f;
    float rk = expf(-0.5f * z * z);
    bf16x8 wv = *(const bf16x8*)&wR[k * 512 + lane * 8];
#pragma unroll
    for (int j = 0; j < 8; ++j)
      zv[j] += rk * bf2f((unsigned short)wv[j]);
  }
  unsigned short ov[8];
#pragma unroll
  for (int j = 0; j < 8; ++j) ov[j] = f2bf(silu_f(zv[j]));
  unsigned short* outp = half ? ps1 : c1;
  *(uint4*)&outp[(size_t)e * 256 + c8] = *(uint4*)ov;
}

// ---------------- MFMA bf16 GEMM: BN=256, BK=64; BM=128 (512 thr) or SMALL BM=64 (256 thr) ----------------
// MODE 0: A bf16 [M][256], Kp=256
// MODE 2: A = [A | A2] (each [M][256]), Kp=512
// MODE 3: multi-chunk C: Cw = C + (bn>>8)*M*256 (no silu; bias = zeros)
// MODE 4: merged dual GEMM: rows >= Msplit use weight chunk 1 / bias2 / C2
// GATE:   gout[row] = sum_col silu(acc+b1[col]) * gw2[col]
// LNOUT:  h/hbf = LayerNorm(h + acc + bias) * lng + lnb  (fused upd2+LN)
template<int MODE, bool SILU, bool GATE, bool LNOUT, bool SMALL>
__global__ __launch_bounds__(SMALL ? 256 : 512, 4) void mfma_gemm(
    const unsigned short* __restrict__ A, const unsigned short* __restrict__ A2,
    const unsigned short* __restrict__ Wt,
    const float* __restrict__ bias, const float* __restrict__ bias2,
    unsigned short* __restrict__ C, unsigned short* __restrict__ C2,
    int M, int Kp, int Msplit,
    const float* __restrict__ gw2, float* __restrict__ gout,
    float* __restrict__ hf, unsigned short* __restrict__ hb,
    const float* __restrict__ lng, const float* __restrict__ lnb) {
  constexpr int BM = SMALL ? 64 : 128;
  constexpr int BQ = SMALL ? 8 : 4;            // B-stage issues per wave
  __shared__ unsigned short lds[SMALL ? 20480 : 24576];   // As BM*64 + Bs 256*64
  unsigned short* As = lds;                    // [BM][64] XOR-swizzled
  unsigned short* Bs = lds + BM * 64;          // [256][64] XOR-swizzled
  const int tid = threadIdx.x;
  const int bn = blockIdx.x * 256;
  const int bm = blockIdx.y * BM;
  const int lane = tid & 63;
  const int w = tid >> 6;
  const int wr = SMALL ? 0 : (w >> 2);
  const int wc = SMALL ? w : (w & 3);
  const int subrow = lane >> 3;
  const int kd = 8 * ((lane & 7) ^ subrow);

  const bool half2 = (MODE == 4) && (bm >= Msplit);
  const unsigned short* Wb = Wt + (half2 ? 256 * 256 : 0);

  unsigned int offB[BQ];
#pragma unroll
  for (int q = 0; q < BQ; ++q)
    offB[q] = (unsigned)(bn + w * (BQ * 8) + q * 8 + subrow) * (unsigned)Kp;

  unsigned int offA[2];
#pragma unroll
  for (int q = 0; q < 2; ++q) {
    int m = bm + w * 16 + q * 8 + subrow;
    int mc = (m < M) ? m : (M - 1);
    offA[q] = (unsigned)mc * 256u;
  }

  const int nt = Kp >> 6;
  f32x4 acc[4][4] = {};

  for (int t = 0; t < nt; ++t) {
    const int k0 = t << 6;
#pragma unroll
    for (int q = 0; q < 2; ++q) {
      const unsigned short* gp;
      if (MODE == 2) gp = (k0 < 256) ? (A + offA[q] + k0 + kd) : (A2 + offA[q] + (k0 - 256) + kd);
      else gp = A + offA[q] + k0 + kd;
      gload16(gp, (char*)As + w * 2048 + q * 1024);
    }
#pragma unroll
    for (int q = 0; q < BQ; ++q)
      gload16(Wb + offB[q] + k0 + kd, (char*)Bs + w * (BQ * 1024) + q * 1024);
    __syncthreads();
#pragma unroll
    for (int ks = 0; ks < 2; ++ks) {
      const int kb = (ks * 64 + ((lane >> 4) << 4)) ^ ((lane & 7) << 4);
      bf16x8 bfv[4];
#pragma unroll
      for (int j = 0; j < 4; ++j)
        bfv[j] = *(const bf16x8*)((const char*)Bs + (wc * 64 + j * 16 + (lane & 15)) * 128 + kb);
#pragma unroll
      for (int i = 0; i < 4; ++i) {
        bf16x8 af = *(const bf16x8*)((const char*)As + (wr * 64 + i * 16 + (lane & 15)) * 128 + kb);
#pragma unroll
        for (int j = 0; j < 4; ++j)
          acc[i][j] = __builtin_amdgcn_mfma_f32_16x16x32_bf16(af, bfv[j], acc[i][j], 0, 0, 0);
      }
    }
    __syncthreads();
  }

  if (GATE) {
    float bcol[4], wcol[4];
#pragma unroll
    for (int j = 0; j < 4; ++j) {
      int col = wc * 64 + j * 16 + (lane & 15);
      bcol[j] = bias[col];
      wcol[j] = gw2[col];
    }
    float* part = (float*)lds;   // [4][BM]
#pragma unroll
    for (int i = 0; i < 4; ++i) {
#pragma unroll
      for (int q = 0; q < 4; ++q) {
        float lsum = 0.f;
#pragma unroll
        for (int j = 0; j < 4; ++j)
          lsum += silu_f(acc[i][j][q] + bcol[j]) * wcol[j];
        lsum += __shfl_xor(lsum, 1, 64);
        lsum += __shfl_xor(lsum, 2, 64);
        lsum += __shfl_xor(lsum, 4, 64);
        lsum += __shfl_xor(lsum, 8, 64);
        if ((lane & 15) == 0) {
          int rl = wr * 64 + i * 16 + ((lane >> 4) << 2) + q;
          part[wc * BM + rl] = lsum;
        }
      }
    }
    __syncthreads();
    if (tid < BM)
      gout[bm + tid] = part[tid] + part[BM + tid] + part[2*BM + tid] + part[3*BM + tid];
    return;
  }

  if (LNOUT) {
    float bcol[4], lgc[4], lbc[4];
#pragma unroll
    for (int j = 0; j < 4; ++j) {
      int col = wc * 64 + j * 16 + (lane & 15);
      bcol[j] = bias[col]; lgc[j] = lng[col]; lbc[j] = lnb[col];
    }
    float* part = (float*)lds;       // [4][BM]
    float* stat = part + 4 * BM;     // mu[BM], rstd[BM]
#pragma unroll
    for (int i = 0; i < 4; ++i)
#pragma unroll
      for (int q = 0; q < 4; ++q) {
        int rl = wr * 64 + i * 16 + ((lane >> 4) << 2) + q;
        int grow = bm + rl;
        float s = 0.f;
#pragma unroll
        for (int j = 0; j < 4; ++j) {
          int col = wc * 64 + j * 16 + (lane & 15);
          float hv = (grow < M) ? hf[(size_t)grow * 256 + col] : 0.f;
          float zz = acc[i][j][q] + bcol[j] + hv;
          acc[i][j][q] = zz;
          s += zz;
        }
        s += __shfl_xor(s, 1, 64); s += __shfl_xor(s, 2, 64);
        s += __shfl_xor(s, 4, 64); s += __shfl_xor(s, 8, 64);
        if ((lane & 15) == 0) part[wc * BM + rl] = s;
      }
    __syncthreads();
    if (tid < BM)
      stat[tid] = (part[tid] + part[BM + tid] + part[2*BM + tid] + part[3*BM + tid]) * (1.f / 256.f);
    __syncthreads();
#pragma unroll
    for (int i = 0; i < 4; ++i)
#pragma unroll
      for (int q = 0; q < 4; ++q) {
        int rl = wr * 64 + i * 16 + ((lane >> 4) << 2) + q;
        float mu = stat[rl];
        float s2 = 0.f;
#pragma unroll
        for (int j = 0; j < 4; ++j) { float d_ = acc[i][j][q] - mu; s2 += d_ * d_; }
        s2 += __shfl_xor(s2, 1, 64); s2 += __shfl_xor(s2, 2, 64);
        s2 += __shfl_xor(s2, 4, 64); s2 += __shfl_xor(s2, 8, 64);
        if ((lane & 15) == 0) part[wc * BM + rl] = s2;
      }
    __syncthreads();
    if (tid < BM)
      stat[BM + tid] = 1.f / sqrtf((part[tid] + part[BM + tid] + part[2*BM + tid] + part[3*BM + tid]) * (1.f / 256.f) + 1e-5f);
    __syncthreads();
#pragma unroll
    for (int i = 0; i < 4; ++i)
#pragma unroll
      for (int q = 0; q < 4; ++q) {
        int rl = wr * 64 + i * 16 + ((lane >> 4) << 2) + q;
        int grow = bm + rl;
        if (grow < M) {
          float mu = stat[rl], rs = stat[BM + rl];
#pragma unroll
          for (int j = 0; j < 4; ++j) {
            int col = wc * 64 + j * 16 + (lane & 15);
            float o = (acc[i][j][q] - mu) * rs * lgc[j] + lbc[j];
            hf[(size_t)grow * 256 + col] = o;
            hb[(size_t)grow * 256 + col] = f2bf(o);
          }
        }
      }
    return;
  }

  // normal epilogue: coalesced C-store via LDS transpose
  const float* biasw = bias;
  unsigned short* Cw = C;
  int rowoff = 0;
  if (MODE == 3) Cw = C + (size_t)(bn >> 8) * (size_t)M * 256;
  if (MODE == 4 && half2) { biasw = bias2; Cw = C2; rowoff = Msplit; }

  float bcol[4];
#pragma unroll
  for (int j = 0; j < 4; ++j) bcol[j] = biasw[wc * 64 + j * 16 + (lane & 15)];

  unsigned short* T = lds;   // [BM][136]
#pragma unroll
  for (int hh = 0; hh < 2; ++hh) {
    if ((wc >> 1) == hh) {
#pragma unroll
      for (int i = 0; i < 4; ++i)
#pragma unroll
        for (int j = 0; j < 4; ++j)
#pragma unroll
          for (int q = 0; q < 4; ++q) {
            int rl = wr * 64 + i * 16 + ((lane >> 4) << 2) + q;
            int cl = (wc & 1) * 64 + j * 16 + (lane & 15);
            float v = acc[i][j][q] + bcol[j];
            if (SILU) v = silu_f(v);
            T[rl * 136 + cl] = f2bf(v);
          }
    }
    __syncthreads();
#pragma unroll
    for (int it = 0; it < 4; ++it) {
      int row = it * (BM / 4) + (tid >> 4);
      int grow = bm + row;
      if (grow < M) {
        uint4 v = *(const uint4*)&T[row * 136 + (tid & 15) * 8];
        *(uint4*)&Cw[(size_t)(grow - rowoff) * 256 + hh * 128 + (tid & 15) * 8] = v;
      }
    }
    __syncthreads();
  }
}

// ---------------- CSR gather: pm_sum (bf16 out) + dx + x update ----------------
__global__ void gather_pm_dx(const unsigned short* __restrict__ pm, const float* __restrict__ gate,
                             const float* __restrict__ rij, const int* __restrict__ rowstart,
                             const int* __restrict__ eids, const float* __restrict__ gb2,
                             unsigned short* __restrict__ pmbf, float* __restrict__ x) {
  int n = blockIdx.x, k = threadIdx.x;
  int s = rowstart[n], e1 = rowstart[n + 1];
  float acc = 0.f, dx = 0.f;
  float b2 = gb2[0];
  for (int t = s; t < e1; ++t) {
    int e = eids[t];
    acc += bf2f(pm[(size_t)e*HID + k]);
    if (k < 3) dx += rij[e*3 + k] * (gate[e] + b2);
  }
  pmbf[(size_t)n*HID + k] = f2bf(acc);
  if (k < 3) x[n*3 + k] += dx;
}

// ---------------- readout ----------------
__global__ void graph_acc_kernel(const float* __restrict__ h, const int* __restrict__ ng,
                                 float* __restrict__ hg, float* __restrict__ cnt) {
  int n = blockIdx.x, k = threadIdx.x;
  int g = ng[n];
  atomicAdd(&hg[(size_t)g*HID + k], h[(size_t)n*HID + k]);
  if (k == 0) atomicAdd(&cnt[g], 1.0f);
}

__global__ void head_kernel(const float* __restrict__ hg, const float* __restrict__ cnt,
                            const float* __restrict__ head_W, const float* __restrict__ head_b,
                            float* __restrict__ out) {
  int g = threadIdx.x;
  if (g >= NG) return;
  float dot = 0.f;
  for (int k = 0; k < HID; ++k) dot += hg[(size_t)g*HID + k] * head_W[k];
  float c = fmaxf(cnt[g], 1.0f);
  float v = (dot / c + head_b[0]) * 0.5f;
  out[g] = 1.0f / (1.0f + expf(-v));
}

extern "C" void kernel_launch(void* const* d_in, const int* in_sizes, int n_in,
                              void* d_out, int out_size, void* d_ws, size_t ws_size,
                              hipStream_t stream) {
  (void)in_sizes; (void)n_in; (void)out_size; (void)ws_size;
  const float* a_t      = (const float*)d_in[0];
  const float* c_t      = (const float*)d_in[1];
  const float* e_t      = (const float*)d_in[2];
  const float* x_t      = (const float*)d_in[3];
  const float* g_a      = (const float*)d_in[4];
  const float* g_c      = (const float*)d_in[5];
  const float* g_e      = (const float*)d_in[6];
  const float* atom_W   = (const float*)d_in[7];
  const float* charge_W = (const float*)d_in[8];
  const float* bond_W   = (const float*)d_in[9];
  const float* fuse_W   = (const float*)d_in[10];
  const float* fuse_b   = (const float*)d_in[11];
  const float* lift_W   = (const float*)d_in[12];
  const float* lift_b   = (const float*)d_in[13];
  const float* phim_W1  = (const float*)d_in[14];
  const float* phim_b1  = (const float*)d_in[15];
  const float* phim_W2  = (const float*)d_in[16];
  const float* phim_b2  = (const float*)d_in[17];
  const float* phix_W1  = (const float*)d_in[18];
  const float* phix_b1  = (const float*)d_in[19];
  const float* phix_W2  = (const float*)d_in[20];
  const float* phix_b2  = (const float*)d_in[21];
  const float* psim_W1  = (const float*)d_in[22];
  const float* psim_b1  = (const float*)d_in[23];
  const float* psim_W2  = (const float*)d_in[24];
  const float* psim_b2  = (const float*)d_in[25];
  const float* updh_W1  = (const float*)d_in[26];
  const float* updh_b1  = (const float*)d_in[27];
  const float* updh_W2  = (const float*)d_in[28];
  const float* updh_b2  = (const float*)d_in[29];
  const float* ln_g     = (const float*)d_in[30];
  const float* ln_b     = (const float*)d_in[31];
  const float* head_W   = (const float*)d_in[32];
  const float* head_b   = (const float*)d_in[33];
  const int*   src      = (const int*)d_in[34];
  const int*   dst      = (const int*)d_in[35];
  const int*   ngraph   = (const int*)d_in[36];
  float* out = (float*)d_out;

  char* p = (char*)d_ws;
  auto carve = [&](size_t bytes) -> char* {
    char* r = p; p += (bytes + 255) & ~(size_t)255; return r;
  };
  float*          h     = (float*)carve((size_t)NN*HID*4);
  unsigned short* hbf   = (unsigned short*)carve((size_t)NN*HID*2);
  float*          xpos  = (float*)carve((size_t)NN*3*4);
  int*            ie    = (int*)carve((size_t)NE*4);
  float*          tabA  = (float*)carve((size_t)KA*HID*4);
  float*          tabC  = (float*)carve((size_t)KC*HID*4);
  float*          tabEf = (float*)carve((size_t)KE*HID*4);
  float*          rij   = (float*)carve((size_t)NE*3*4);
  float*          gate  = (float*)carve((size_t)NE*4);
  unsigned short* pmbf  = (unsigned short*)carve((size_t)NN*HID*2);
  float*          zbias = (float*)carve(256*4);
  size_t hg_bytes = (size_t)NG*HID*4 + (size_t)NG*4;
  float*          hg    = (float*)carve(hg_bytes);
  float*          cnt   = hg + (size_t)NG*HID;
  unsigned short* buf01 = (unsigned short*)carve((size_t)2*NE*HID*2);  // c1 | ps1 contiguous
  unsigned short* bufM  = (unsigned short*)carve((size_t)NE*HID*2);    // m
  unsigned short* bufPM = (unsigned short*)carve((size_t)NE*HID*2);    // pm
  unsigned short* P     = (unsigned short*)carve((size_t)4*NN*HID*2);
  // CSR
  int* deg      = (int*)carve(10240*4);
  int* cursor   = (int*)carve(10240*4);
  int* rowstart = (int*)carve(10241*4);
  int* eids     = (int*)carve((size_t)NE*4);
  // transposed bf16 weights
  unsigned short* wNode  = (unsigned short*)carve((size_t)NDEP*1024*256*2);
  unsigned short* wMPM   = (unsigned short*)carve((size_t)NDEP*512*256*2);   // [phimW2 | psimW2]
  unsigned short* wPhix1 = (unsigned short*)carve((size_t)NDEP*256*256*2);
  unsigned short* wUpd1  = (unsigned short*)carve((size_t)NDEP*256*512*2);
  unsigned short* wUpd2  = (unsigned short*)carve((size_t)NDEP*256*256*2);
  unsigned short* wRbf   = (unsigned short*)carve((size_t)NDEP*16*512*2);
  unsigned short* tabE1  = (unsigned short*)carve((size_t)NDEP*5*512*2);

  unsigned short* c1buf = buf01;
  unsigned short* psbuf = buf01 + (size_t)NE*HID;

  // ---- weight conversion ----
  convw_nodeblk<<<dim3(8,4,NDEP), 256, 0, stream>>>(phim_W1, wNode, 0,   0);
  convw_nodeblk<<<dim3(8,4,NDEP), 256, 0, stream>>>(phim_W1, wNode, 256, 256);
  convw_nodeblk<<<dim3(8,4,NDEP), 256, 0, stream>>>(psim_W1, wNode, 0,   512);
  convw_nodeblk<<<dim3(8,4,NDEP), 256, 0, stream>>>(psim_W1, wNode, 256, 768);
  convw_plain<<<dim3(8,4,NDEP), 256, 0, stream>>>(phim_W2, wMPM, 256, 512*256, 0);
  convw_plain<<<dim3(8,4,NDEP), 256, 0, stream>>>(psim_W2, wMPM, 256, 512*256, 256);
  convw_plain<<<dim3(8,4,NDEP), 256, 0, stream>>>(phix_W1, wPhix1, 256, 256*256, 0);
  convw_plain<<<dim3(8,4,NDEP), 256, 0, stream>>>(updh_W2, wUpd2, 256, 256*256, 0);
  convw_plain<<<dim3(16,4,NDEP), 256, 0, stream>>>(updh_W1, wUpd1, 512, 256*512, 0);
  convw_rbf<<<NDEP, 512, 0, stream>>>(phim_W1, psim_W1, wRbf);
  hipMemsetAsync(zbias, 0, 256*4, stream);

  tables_kernel<<<KA + KC + KE, 256, 0, stream>>>(atom_W, charge_W, bond_W, fuse_W, fuse_b,
                                                  lift_W, lift_b, tabA, tabC, tabEf);
  tabe1_kernel<<<dim3(5, NDEP), 512, 0, stream>>>(tabEf, phim_W1, phim_b1, psim_W1, psim_b1, tabE1);
  node_init_kernel<<<NN, 256, 0, stream>>>(a_t, c_t, g_a, g_c, x_t, tabA, tabC, h, hbf, xpos);
  edge_init_kernel<<<(NE + 255)/256, 256, 0, stream>>>(e_t, g_e, ie);

  // ---- CSR build ----
  hipMemsetAsync(deg, 0, 10240*4, stream);
  hist_kernel<<<(NE + 255)/256, 256, 0, stream>>>(dst, deg);
  scan_kernel<<<1, 1024, 0, stream>>>(deg, rowstart, cursor);
  fill_kernel<<<(NE + 255)/256, 256, 0, stream>>>(dst, cursor, eids);
  sortrows_kernel<<<(NN + 255)/256, 256, 0, stream>>>(rowstart, eids);

  dim3 gridP(4, (NN + 63)/64);     // SMALL: BM=64
  dim3 gridE(1, NE/128);
  dim3 gridE2(1, 2*NE/128);
  dim3 gridNS(1, (NN + 63)/64);    // SMALL node GEMMs

  for (int d = 0; d < NDEP; ++d) {
    const float* pb2m = phim_b2 + (size_t)d*HID;
    const float* pxb1 = phix_b1 + (size_t)d*HID;
    const float* pxW2 = phix_W2 + (size_t)d*HID;
    const float* pxb2 = phix_b2 + (size_t)d;
    const float* psb2 = psim_b2 + (size_t)d*HID;
    const float* pub1 = updh_b1 + (size_t)d*HID;
    const float* pub2 = updh_b2 + (size_t)d*HID;

    // rij
    rij_kernel<<<(NE + 255)/256, 256, 0, stream>>>(xpos, src, dst, rij);
    // P = h @ [W1_phim_dst | W1_phim_src | W1_psim_dst | W1_psim_src]  (SMALL tiles)
    mfma_gemm<3, false, false, false, true><<<gridP, 256, 0, stream>>>(
        hbf, nullptr, wNode + (size_t)d*1024*256, zbias, nullptr, P, nullptr, NN, 256, 0,
        nullptr, nullptr, nullptr, nullptr, nullptr, nullptr);
    // c1, ps1 = silu(P[dst]+P[src]+tabE1[ie]+windowed rbf@Wrbf)
    combine2_kernel<<<NE/4, 256, 0, stream>>>(
        src, dst, ie, xpos, P, tabE1 + (size_t)d*5*512, wRbf + (size_t)d*16*512, c1buf, psbuf);
    // merged: m = silu(c1 @ phim_W2 + b2) ; pm = silu(ps1 @ psim_W2 + b2)
    mfma_gemm<4, true, false, false, false><<<gridE2, 512, 0, stream>>>(
        buf01, nullptr, wMPM + (size_t)d*512*256, pb2m, psb2, bufM, bufPM, 2*NE, 256, NE,
        nullptr, nullptr, nullptr, nullptr, nullptr, nullptr);
    // gate = silu(m @ phix_W1 + b1) @ phix_W2
    mfma_gemm<0, false, true, false, false><<<gridE, 512, 0, stream>>>(
        bufM, nullptr, wPhix1 + (size_t)d*256*256, pxb1, nullptr, nullptr, nullptr, NE, 256, 0,
        pxW2, gate, nullptr, nullptr, nullptr, nullptr);
    // pm_sum -> pmbf ; x += dx
    gather_pm_dx<<<NN, 256, 0, stream>>>(bufPM, gate, rij, rowstart, eids, pxb2, pmbf, xpos);
    // u1 = silu([h, pm] @ updh_W1 + b1)  (SMALL tiles)
    mfma_gemm<2, true, false, false, true><<<gridNS, 256, 0, stream>>>(
        hbf, pmbf, wUpd1 + (size_t)d*256*512, pub1, nullptr, bufM, nullptr, NN, 512, 0,
        nullptr, nullptr, nullptr, nullptr, nullptr, nullptr);
    // h = LN(h + u1 @ updh_W2 + b2)  (fused, SMALL tiles)
    mfma_gemm<0, false, false, true, true><<<gridNS, 256, 0, stream>>>(
        bufM, nullptr, wUpd2 + (size_t)d*256*256, pub2, nullptr, nullptr, nullptr, NN, 256, 0,
        nullptr, nullptr, h, hbf, ln_g + (size_t)d*HID, ln_b + (size_t)d*HID);
  }

  hipMemsetAsync(hg, 0, hg_bytes, stream);
  graph_acc_kernel<<<NN, 256, 0, stream>>>(h, ngraph, hg, cnt);
  head_kernel<<<1, 64, 0, stream>>>(hg, cnt, head_W, head_b, out);
}

// Round 14
// 1856.042 us; speedup vs baseline: 1.9949x; 1.0095x over previous
//
#include <hip/hip_runtime.h>
#include <math.h>

#define NN   10000
#define NE   80000
#define NG   64
#define HID  256
#define RBFK 16
#define NDEP 6
#define KA   16
#define KC   6
#define KE   5
#define DE   85
#define CATW 784

typedef __attribute__((ext_vector_type(8))) short bf16x8;
typedef __attribute__((ext_vector_type(4))) float f32x4;

static __device__ __forceinline__ float silu_f(float v) { return v / (1.0f + expf(-v)); }

static __device__ __forceinline__ unsigned short f2bf(float f) {
  union { float f; unsigned int u; } v; v.f = f;
  unsigned int r = v.u + 0x7fff + ((v.u >> 16) & 1);
  return (unsigned short)(r >> 16);
}
static __device__ __forceinline__ float bf2f(unsigned short h) {
  union { unsigned int u; float f; } v; v.u = ((unsigned int)h) << 16;
  return v.f;
}

static __device__ __forceinline__ void gload16(const void* g, void* l) {
  __builtin_amdgcn_global_load_lds((const __attribute__((address_space(1))) unsigned int*)g,
                                   (__attribute__((address_space(3))) unsigned int*)l, 16, 0, 0);
}

// ---------------- weight transpose-converts ----------------
__global__ void convw_plain(const float* __restrict__ W, unsigned short* __restrict__ Wt, int K,
                            long long wt_dstride, int wt_rowoff) {
  __shared__ float T[32][65];
  int k0 = blockIdx.x * 32, n0 = blockIdx.y * 64, d = blockIdx.z;
  int tid = threadIdx.x;
  int nn = tid & 63, kr = tid >> 6;
  const float* Wd = W + (size_t)d * K * 256;
#pragma unroll
  for (int i = 0; i < 8; ++i) {
    int k = kr + i * 4;
    T[k][nn] = Wd[(size_t)(k0 + k) * 256 + n0 + nn];
  }
  __syncthreads();
  unsigned short* Wtd = Wt + (size_t)d * wt_dstride;
  int kk = tid & 31, nr = tid >> 5;
#pragma unroll
  for (int i = 0; i < 8; ++i) {
    int n = nr + i * 8;
    Wtd[(size_t)(wt_rowoff + n0 + n) * K + k0 + kk] = f2bf(T[kk][n]);
  }
}

__global__ void convw_nodeblk(const float* __restrict__ W, unsigned short* __restrict__ Wt,
                              int src_k0, int nt_base) {
  __shared__ float T[32][65];
  int k0 = blockIdx.x * 32, n0 = blockIdx.y * 64, d = blockIdx.z;
  int tid = threadIdx.x;
  int nn = tid & 63, kr = tid >> 6;
  const float* Wd = W + (size_t)d * CATW * 256;
#pragma unroll
  for (int i = 0; i < 8; ++i) {
    int k = kr + i * 4;
    T[k][nn] = Wd[(size_t)(src_k0 + k0 + k) * 256 + n0 + nn];
  }
  __syncthreads();
  unsigned short* Wtd = Wt + (size_t)d * 1024 * 256;
  int kk = tid & 31, nr = tid >> 5;
#pragma unroll
  for (int i = 0; i < 8; ++i) {
    int n = nr + i * 8;
    Wtd[(size_t)(nt_base + n0 + n) * 256 + k0 + kk] = f2bf(T[kk][n]);
  }
}

// wR [D][16][512] bf16: rbf rows (512..527) of phim_W1 (cols 0:256) / psim_W1 (cols 256:512)
__global__ void convw_rbf(const float* __restrict__ phimW1, const float* __restrict__ psimW1,
                          unsigned short* __restrict__ wR) {
  int d = blockIdx.x, j = threadIdx.x;
  int jj = j & 255;
  const float* W = (j < 256) ? phimW1 : psimW1;
  for (int k = 0; k < 16; ++k)
    wR[((size_t)d * 16 + k) * 512 + j] = f2bf(W[(size_t)d * CATW * 256 + (size_t)(512 + k) * 256 + jj]);
}

// ---------------- tables ----------------
__global__ void tables_kernel(const float* __restrict__ atom_W, const float* __restrict__ charge_W,
                              const float* __restrict__ bond_W, const float* __restrict__ fuse_W,
                              const float* __restrict__ fuse_b, const float* __restrict__ lift_W,
                              const float* __restrict__ lift_b,
                              float* __restrict__ tabA, float* __restrict__ tabC,
                              float* __restrict__ tabEf) {
  int r = blockIdx.x, k = threadIdx.x;
  if (r < KA) {
    float s = 0.f;
    for (int d = 0; d < DE; ++d) s += atom_W[r*DE + d] * fuse_W[d*HID + k];
    tabA[r*HID + k] = s + fuse_b[k];
  } else if (r < KA + KC) {
    int rr = r - KA;
    float s = 0.f;
    for (int d = 0; d < DE; ++d) s += charge_W[rr*DE + d] * fuse_W[(DE + d)*HID + k];
    tabC[rr*HID + k] = s;
  } else {
    int rr = r - KA - KC;
    float s = 0.f;
    for (int d = 0; d < DE; ++d) s += bond_W[rr*DE + d] * lift_W[d*HID + k];
    tabEf[rr*HID + k] = s + lift_b[k];
  }
}

// tabE1 [D][5][512] bf16 = tabEf @ W1_eemb (+ b1), phim cols 0:256, psim cols 256:512
__global__ void tabe1_kernel(const float* __restrict__ tabEf,
                             const float* __restrict__ phimW1, const float* __restrict__ phimb1,
                             const float* __restrict__ psimW1, const float* __restrict__ psimb1,
                             unsigned short* __restrict__ tabE1) {
  int r = blockIdx.x, d = blockIdx.y, j = threadIdx.x;
  const float* W = (j < 256) ? phimW1 : psimW1;
  const float* b = (j < 256) ? phimb1 : psimb1;
  int jj = j & 255;
  float s = b[d*256 + jj];
  for (int k = 0; k < 256; ++k)
    s += tabEf[r*256 + k] * W[(size_t)d*CATW*256 + (size_t)(528 + k)*256 + jj];
  tabE1[((size_t)d*5 + r)*512 + j] = f2bf(s);
}

// ---------------- node / edge init ----------------
__global__ void node_init_kernel(const float* __restrict__ a_t, const float* __restrict__ c_t,
                                 const float* __restrict__ g_a, const float* __restrict__ g_c,
                                 const float* __restrict__ x_t, const float* __restrict__ tabA,
                                 const float* __restrict__ tabC, float* __restrict__ h,
                                 unsigned short* __restrict__ hbf, float* __restrict__ x) {
  int n = blockIdx.x;
  __shared__ int s_ia, s_ic;
  if (threadIdx.x == 0) {
    float best = -1e30f; int bi = 0;
    for (int j = 0; j < KA; ++j) {
      float v = logf(fmaxf(a_t[n*KA + j], 1e-12f)) + g_a[n*KA + j];
      if (v > best) { best = v; bi = j; }
    }
    s_ia = bi;
  }
  if (threadIdx.x == 1) {
    float best = -1e30f; int bi = 0;
    for (int j = 0; j < KC; ++j) {
      float v = logf(fmaxf(c_t[n*KC + j], 1e-12f)) + g_c[n*KC + j];
      if (v > best) { best = v; bi = j; }
    }
    s_ic = bi;
  }
  __syncthreads();
  int k = threadIdx.x;
  float v = tabA[s_ia*HID + k] + tabC[s_ic*HID + k];
  h[n*HID + k] = v;
  hbf[n*HID + k] = f2bf(v);
  if (k < 3) x[n*3 + k] = x_t[n*3 + k];
}

__global__ void edge_init_kernel(const float* __restrict__ e_t, const float* __restrict__ g_e,
                                 int* __restrict__ ie) {
  int e = blockIdx.x * blockDim.x + threadIdx.x;
  if (e >= NE) return;
  float best = -1e30f; int bi = 0;
  for (int j = 0; j < KE; ++j) {
    float v = logf(fmaxf(e_t[e*KE + j], 1e-12f)) + g_e[e*KE + j];
    if (v > best) { best = v; bi = j; }
  }
  ie[e] = bi;
}

// ---------------- CSR build ----------------
__global__ void hist_kernel(const int* __restrict__ dst, int* __restrict__ deg) {
  int e = blockIdx.x * 256 + threadIdx.x;
  if (e < NE) atomicAdd(&deg[dst[e]], 1);
}

__global__ void scan_kernel(const int* __restrict__ deg, int* __restrict__ rowstart,
                            int* __restrict__ cursor) {
  __shared__ int tmp[1024];
  int t = threadIdx.x;
  int base = t * 10;
  int local[10];
  int s = 0;
#pragma unroll
  for (int i = 0; i < 10; ++i) { local[i] = deg[base + i]; s += local[i]; }
  tmp[t] = s;
  __syncthreads();
  for (int off = 1; off < 1024; off <<= 1) {
    int v = (t >= off) ? tmp[t - off] : 0;
    __syncthreads();
    tmp[t] += v;
    __syncthreads();
  }
  int run = (t == 0) ? 0 : tmp[t - 1];
#pragma unroll
  for (int i = 0; i < 10; ++i) {
    rowstart[base + i] = run; cursor[base + i] = run; run += local[i];
  }
  if (t == 1023) rowstart[10240] = run;
}

__global__ void fill_kernel(const int* __restrict__ dst, int* __restrict__ cursor,
                            int* __restrict__ eids) {
  int e = blockIdx.x * 256 + threadIdx.x;
  if (e >= NE) return;
  int pos = atomicAdd(&cursor[dst[e]], 1);
  eids[pos] = e;
}

__global__ void sortrows_kernel(const int* __restrict__ rowstart, int* __restrict__ eids) {
  int n = blockIdx.x * 256 + threadIdx.x;
  if (n >= NN) return;
  int s = rowstart[n], e = rowstart[n + 1];
  for (int i = s + 1; i < e; ++i) {
    int v = eids[i]; int j = i - 1;
    while (j >= s && eids[j] > v) { eids[j + 1] = eids[j]; --j; }
    eids[j + 1] = v;
  }
}

// ---------------- graph boundaries (node_graph is sorted) ----------------
__global__ void gbound_kernel(const int* __restrict__ ng, int* __restrict__ gstart) {
  int n = blockIdx.x * 256 + threadIdx.x;
  if (n >= NN) return;
  if (n == 0) {
    for (int g = 0; g <= ng[0]; ++g) gstart[g] = 0;
  } else {
    int a = ng[n-1], b = ng[n];
    for (int g = a + 1; g <= b; ++g) gstart[g] = n;
  }
  if (n == NN - 1) {
    for (int g = ng[n] + 1; g <= NG; ++g) gstart[g] = NN;
  }
}

// ---------------- combine2: one edge per 64 lanes; windowed rbf (8 centers) ----------------
__global__ __launch_bounds__(256) void combine2_kernel(
    const int* __restrict__ srcp, const int* __restrict__ dstp, const int* __restrict__ iep,
    const float* __restrict__ x,
    const unsigned short* __restrict__ P,      // [4][NN][256] bf16
    const unsigned short* __restrict__ tabE1,  // [5][512] bf16, this depth
    const unsigned short* __restrict__ wR,     // [16][512] bf16, this depth
    unsigned short* __restrict__ c1, unsigned short* __restrict__ ps1) {
  const int tid = threadIdx.x;
  const int lane = tid & 63;
  const int e = blockIdx.x * 4 + (tid >> 6);
  const int half = lane >> 5;            // 0: phim, 1: psim
  const int c8 = (lane & 31) * 8;        // col within 256
  const int ds = dstp[e], sr = srcp[e], ib = iep[e];
  float r0 = x[ds*3+0] - x[sr*3+0];
  float r1 = x[ds*3+1] - x[sr*3+1];
  float r2 = x[ds*3+2] - x[sr*3+2];
  float dist = sqrtf(r0*r0 + r1*r1 + r2*r2);
  int klo = (int)(dist * 1.5f) - 3;
  klo = klo < 0 ? 0 : (klo > 8 ? 8 : klo);
  const unsigned short* Pb0 = P + (size_t)(half * 2) * NN * 256;
  const unsigned short* Pb1 = P + (size_t)(half * 2 + 1) * NN * 256;
  bf16x8 pa = *(const bf16x8*)&Pb0[(size_t)ds * 256 + c8];
  bf16x8 pb = *(const bf16x8*)&Pb1[(size_t)sr * 256 + c8];
  bf16x8 te = *(const bf16x8*)&tabE1[(size_t)ib * 512 + lane * 8];
  float zv[8];
#pragma unroll
  for (int j = 0; j < 8; ++j)
    zv[j] = bf2f((unsigned short)pa[j]) + bf2f((unsigned short)pb[j]) + bf2f((unsigned short)te[j]);
#pragma unroll
  for (int kk = 0; kk < 8; ++kk) {
    int k = klo + kk;
    float z = (dist - 0.66666667f * (float)k) * 1.6f;
    float rk = expf(-0.5f * z * z);
    bf16x8 wv = *(const bf16x8*)&wR[k * 512 + lane * 8];
#pragma unroll
    for (int j = 0; j < 8; ++j)
      zv[j] += rk * bf2f((unsigned short)wv[j]);
  }
  unsigned short ov[8];
#pragma unroll
  for (int j = 0; j < 8; ++j) ov[j] = f2bf(silu_f(zv[j]));
  unsigned short* outp = half ? ps1 : c1;
  *(uint4*)&outp[(size_t)e * 256 + c8] = *(uint4*)ov;
}

// ---------------- MFMA bf16 GEMM: BN=256, BK=64; BM=128 (512 thr) or SMALL BM=64 (256 thr) ----------------
// MODE 0: A bf16 [M][256], Kp=256
// MODE 2: A = [A | A2] (each [M][256]), Kp=512
// MODE 3: multi-chunk C: Cw = C + (bn>>8)*M*256 (no silu; bias = zeros)
// MODE 4: merged dual GEMM: rows >= Msplit use weight chunk 1 / bias2 / C2
// GATE:   gout[row] = sum_col silu(acc+b1[col]) * gw2[col]
// LNOUT:  h/hbf = LayerNorm(h + acc + bias) * lng + lnb  (fused upd2+LN)
template<int MODE, bool SILU, bool GATE, bool LNOUT, bool SMALL>
__global__ __launch_bounds__(SMALL ? 256 : 512, 4) void mfma_gemm(
    const unsigned short* __restrict__ A, const unsigned short* __restrict__ A2,
    const unsigned short* __restrict__ Wt,
    const float* __restrict__ bias, const float* __restrict__ bias2,
    unsigned short* __restrict__ C, unsigned short* __restrict__ C2,
    int M, int Kp, int Msplit,
    const float* __restrict__ gw2, float* __restrict__ gout,
    float* __restrict__ hf, unsigned short* __restrict__ hb,
    const float* __restrict__ lng, const float* __restrict__ lnb) {
  constexpr int BM = SMALL ? 64 : 128;
  constexpr int BQ = SMALL ? 8 : 4;            // B-stage issues per wave
  __shared__ unsigned short lds[SMALL ? 20480 : 24576];   // As BM*64 + Bs 256*64
  unsigned short* As = lds;                    // [BM][64] XOR-swizzled
  unsigned short* Bs = lds + BM * 64;          // [256][64] XOR-swizzled
  const int tid = threadIdx.x;
  const int bn = blockIdx.x * 256;
  const int bm = blockIdx.y * BM;
  const int lane = tid & 63;
  const int w = tid >> 6;
  const int wr = SMALL ? 0 : (w >> 2);
  const int wc = SMALL ? w : (w & 3);
  const int subrow = lane >> 3;
  const int kd = 8 * ((lane & 7) ^ subrow);

  const bool half2 = (MODE == 4) && (bm >= Msplit);
  const unsigned short* Wb = Wt + (half2 ? 256 * 256 : 0);

  unsigned int offB[BQ];
#pragma unroll
  for (int q = 0; q < BQ; ++q)
    offB[q] = (unsigned)(bn + w * (BQ * 8) + q * 8 + subrow) * (unsigned)Kp;

  unsigned int offA[2];
#pragma unroll
  for (int q = 0; q < 2; ++q) {
    int m = bm + w * 16 + q * 8 + subrow;
    int mc = (m < M) ? m : (M - 1);
    offA[q] = (unsigned)mc * 256u;
  }

  const int nt = Kp >> 6;
  f32x4 acc[4][4] = {};

  for (int t = 0; t < nt; ++t) {
    const int k0 = t << 6;
#pragma unroll
    for (int q = 0; q < 2; ++q) {
      const unsigned short* gp;
      if (MODE == 2) gp = (k0 < 256) ? (A + offA[q] + k0 + kd) : (A2 + offA[q] + (k0 - 256) + kd);
      else gp = A + offA[q] + k0 + kd;
      gload16(gp, (char*)As + w * 2048 + q * 1024);
    }
#pragma unroll
    for (int q = 0; q < BQ; ++q)
      gload16(Wb + offB[q] + k0 + kd, (char*)Bs + w * (BQ * 1024) + q * 1024);
    __syncthreads();
#pragma unroll
    for (int ks = 0; ks < 2; ++ks) {
      const int kb = (ks * 64 + ((lane >> 4) << 4)) ^ ((lane & 7) << 4);
      bf16x8 bfv[4];
#pragma unroll
      for (int j = 0; j < 4; ++j)
        bfv[j] = *(const bf16x8*)((const char*)Bs + (wc * 64 + j * 16 + (lane & 15)) * 128 + kb);
#pragma unroll
      for (int i = 0; i < 4; ++i) {
        bf16x8 af = *(const bf16x8*)((const char*)As + (wr * 64 + i * 16 + (lane & 15)) * 128 + kb);
#pragma unroll
        for (int j = 0; j < 4; ++j)
          acc[i][j] = __builtin_amdgcn_mfma_f32_16x16x32_bf16(af, bfv[j], acc[i][j], 0, 0, 0);
      }
    }
    __syncthreads();
  }

  if (GATE) {
    float bcol[4], wcol[4];
#pragma unroll
    for (int j = 0; j < 4; ++j) {
      int col = wc * 64 + j * 16 + (lane & 15);
      bcol[j] = bias[col];
      wcol[j] = gw2[col];
    }
    float* part = (float*)lds;   // [4][BM]
#pragma unroll
    for (int i = 0; i < 4; ++i) {
#pragma unroll
      for (int q = 0; q < 4; ++q) {
        float lsum = 0.f;
#pragma unroll
        for (int j = 0; j < 4; ++j)
          lsum += silu_f(acc[i][j][q] + bcol[j]) * wcol[j];
        lsum += __shfl_xor(lsum, 1, 64);
        lsum += __shfl_xor(lsum, 2, 64);
        lsum += __shfl_xor(lsum, 4, 64);
        lsum += __shfl_xor(lsum, 8, 64);
        if ((lane & 15) == 0) {
          int rl = wr * 64 + i * 16 + ((lane >> 4) << 2) + q;
          part[wc * BM + rl] = lsum;
        }
      }
    }
    __syncthreads();
    if (tid < BM)
      gout[bm + tid] = part[tid] + part[BM + tid] + part[2*BM + tid] + part[3*BM + tid];
    return;
  }

  if (LNOUT) {
    float bcol[4], lgc[4], lbc[4];
#pragma unroll
    for (int j = 0; j < 4; ++j) {
      int col = wc * 64 + j * 16 + (lane & 15);
      bcol[j] = bias[col]; lgc[j] = lng[col]; lbc[j] = lnb[col];
    }
    float* part = (float*)lds;       // [4][BM]
    float* stat = part + 4 * BM;     // mu[BM], rstd[BM]
#pragma unroll
    for (int i = 0; i < 4; ++i)
#pragma unroll
      for (int q = 0; q < 4; ++q) {
        int rl = wr * 64 + i * 16 + ((lane >> 4) << 2) + q;
        int grow = bm + rl;
        float s = 0.f;
#pragma unroll
        for (int j = 0; j < 4; ++j) {
          int col = wc * 64 + j * 16 + (lane & 15);
          float hv = (grow < M) ? hf[(size_t)grow * 256 + col] : 0.f;
          float zz = acc[i][j][q] + bcol[j] + hv;
          acc[i][j][q] = zz;
          s += zz;
        }
        s += __shfl_xor(s, 1, 64); s += __shfl_xor(s, 2, 64);
        s += __shfl_xor(s, 4, 64); s += __shfl_xor(s, 8, 64);
        if ((lane & 15) == 0) part[wc * BM + rl] = s;
      }
    __syncthreads();
    if (tid < BM)
      stat[tid] = (part[tid] + part[BM + tid] + part[2*BM + tid] + part[3*BM + tid]) * (1.f / 256.f);
    __syncthreads();
#pragma unroll
    for (int i = 0; i < 4; ++i)
#pragma unroll
      for (int q = 0; q < 4; ++q) {
        int rl = wr * 64 + i * 16 + ((lane >> 4) << 2) + q;
        float mu = stat[rl];
        float s2 = 0.f;
#pragma unroll
        for (int j = 0; j < 4; ++j) { float d_ = acc[i][j][q] - mu; s2 += d_ * d_; }
        s2 += __shfl_xor(s2, 1, 64); s2 += __shfl_xor(s2, 2, 64);
        s2 += __shfl_xor(s2, 4, 64); s2 += __shfl_xor(s2, 8, 64);
        if ((lane & 15) == 0) part[wc * BM + rl] = s2;
      }
    __syncthreads();
    if (tid < BM)
      stat[BM + tid] = 1.f / sqrtf((part[tid] + part[BM + tid] + part[2*BM + tid] + part[3*BM + tid]) * (1.f / 256.f) + 1e-5f);
    __syncthreads();
#pragma unroll
    for (int i = 0; i < 4; ++i)
#pragma unroll
      for (int q = 0; q < 4; ++q) {
        int rl = wr * 64 + i * 16 + ((lane >> 4) << 2) + q;
        int grow = bm + rl;
        if (grow < M) {
          float mu = stat[rl], rs = stat[BM + rl];
#pragma unroll
          for (int j = 0; j < 4; ++j) {
            int col = wc * 64 + j * 16 + (lane & 15);
            float o = (acc[i][j][q] - mu) * rs * lgc[j] + lbc[j];
            hf[(size_t)grow * 256 + col] = o;
            hb[(size_t)grow * 256 + col] = f2bf(o);
          }
        }
      }
    return;
  }

  // normal epilogue: coalesced C-store via LDS transpose
  const float* biasw = bias;
  unsigned short* Cw = C;
  int rowoff = 0;
  if (MODE == 3) Cw = C + (size_t)(bn >> 8) * (size_t)M * 256;
  if (MODE == 4 && half2) { biasw = bias2; Cw = C2; rowoff = Msplit; }

  float bcol[4];
#pragma unroll
  for (int j = 0; j < 4; ++j) bcol[j] = biasw[wc * 64 + j * 16 + (lane & 15)];

  unsigned short* T = lds;   // [BM][136]
#pragma unroll
  for (int hh = 0; hh < 2; ++hh) {
    if ((wc >> 1) == hh) {
#pragma unroll
      for (int i = 0; i < 4; ++i)
#pragma unroll
        for (int j = 0; j < 4; ++j)
#pragma unroll
          for (int q = 0; q < 4; ++q) {
            int rl = wr * 64 + i * 16 + ((lane >> 4) << 2) + q;
            int cl = (wc & 1) * 64 + j * 16 + (lane & 15);
            float v = acc[i][j][q] + bcol[j];
            if (SILU) v = silu_f(v);
            T[rl * 136 + cl] = f2bf(v);
          }
    }
    __syncthreads();
#pragma unroll
    for (int it = 0; it < 4; ++it) {
      int row = it * (BM / 4) + (tid >> 4);
      int grow = bm + row;
      if (grow < M) {
        uint4 v = *(const uint4*)&T[row * 136 + (tid & 15) * 8];
        *(uint4*)&Cw[(size_t)(grow - rowoff) * 256 + hh * 128 + (tid & 15) * 8] = v;
      }
    }
    __syncthreads();
  }
}

// ---------------- CSR gather: pm_sum (bf16 out) + dx; x double-buffered ----------------
__global__ void gather_pm_dx(const unsigned short* __restrict__ pm, const float* __restrict__ gate,
                             const float* __restrict__ xcur, const int* __restrict__ srcp,
                             const int* __restrict__ rowstart, const int* __restrict__ eids,
                             const float* __restrict__ gb2,
                             unsigned short* __restrict__ pmbf, float* __restrict__ xnxt) {
  int n = blockIdx.x, k = threadIdx.x;
  int s = rowstart[n], e1 = rowstart[n + 1];
  float acc = 0.f, dx = 0.f;
  float b2 = gb2[0];
  float xn = (k < 3) ? xcur[n*3 + k] : 0.f;
  for (int t = s; t < e1; ++t) {
    int e = eids[t];
    acc += bf2f(pm[(size_t)e*HID + k]);
    if (k < 3) dx += (xn - xcur[srcp[e]*3 + k]) * (gate[e] + b2);
  }
  pmbf[(size_t)n*HID + k] = f2bf(acc);
  if (k < 3) xnxt[n*3 + k] = xn + dx;
}

// ---------------- fused readout: per-graph column sums + head dot + sigmoid ----------------
__global__ void readout_kernel(const float* __restrict__ h, const int* __restrict__ gstart,
                               const float* __restrict__ head_W, const float* __restrict__ head_b,
                               float* __restrict__ out) {
  int g = blockIdx.x, k = threadIdx.x;
  int s = gstart[g], e = gstart[g + 1];
  float acc = 0.f;
  for (int n = s; n < e; ++n) acc += h[(size_t)n * HID + k];
  float v = acc * head_W[k];
  __shared__ float red[4];
  int lane = k & 63, wv = k >> 6;
#pragma unroll
  for (int off = 32; off > 0; off >>= 1) v += __shfl_down(v, off, 64);
  if (lane == 0) red[wv] = v;
  __syncthreads();
  if (k == 0) {
    float dot = red[0] + red[1] + red[2] + red[3];
    float c = fmaxf((float)(e - s), 1.0f);
    float val = (dot / c + head_b[0]) * 0.5f;
    out[g] = 1.0f / (1.0f + expf(-val));
  }
}

extern "C" void kernel_launch(void* const* d_in, const int* in_sizes, int n_in,
                              void* d_out, int out_size, void* d_ws, size_t ws_size,
                              hipStream_t stream) {
  (void)in_sizes; (void)n_in; (void)out_size; (void)ws_size;
  const float* a_t      = (const float*)d_in[0];
  const float* c_t      = (const float*)d_in[1];
  const float* e_t      = (const float*)d_in[2];
  const float* x_t      = (const float*)d_in[3];
  const float* g_a      = (const float*)d_in[4];
  const float* g_c      = (const float*)d_in[5];
  const float* g_e      = (const float*)d_in[6];
  const float* atom_W   = (const float*)d_in[7];
  const float* charge_W = (const float*)d_in[8];
  const float* bond_W   = (const float*)d_in[9];
  const float* fuse_W   = (const float*)d_in[10];
  const float* fuse_b   = (const float*)d_in[11];
  const float* lift_W   = (const float*)d_in[12];
  const float* lift_b   = (const float*)d_in[13];
  const float* phim_W1  = (const float*)d_in[14];
  const float* phim_b1  = (const float*)d_in[15];
  const float* phim_W2  = (const float*)d_in[16];
  const float* phim_b2  = (const float*)d_in[17];
  const float* phix_W1  = (const float*)d_in[18];
  const float* phix_b1  = (const float*)d_in[19];
  const float* phix_W2  = (const float*)d_in[20];
  const float* phix_b2  = (const float*)d_in[21];
  const float* psim_W1  = (const float*)d_in[22];
  const float* psim_b1  = (const float*)d_in[23];
  const float* psim_W2  = (const float*)d_in[24];
  const float* psim_b2  = (const float*)d_in[25];
  const float* updh_W1  = (const float*)d_in[26];
  const float* updh_b1  = (const float*)d_in[27];
  const float* updh_W2  = (const float*)d_in[28];
  const float* updh_b2  = (const float*)d_in[29];
  const float* ln_g     = (const float*)d_in[30];
  const float* ln_b     = (const float*)d_in[31];
  const float* head_W   = (const float*)d_in[32];
  const float* head_b   = (const float*)d_in[33];
  const int*   src      = (const int*)d_in[34];
  const int*   dst      = (const int*)d_in[35];
  const int*   ngraph   = (const int*)d_in[36];
  float* out = (float*)d_out;

  char* p = (char*)d_ws;
  auto carve = [&](size_t bytes) -> char* {
    char* r = p; p += (bytes + 255) & ~(size_t)255; return r;
  };
  float*          h     = (float*)carve((size_t)NN*HID*4);
  unsigned short* hbf   = (unsigned short*)carve((size_t)NN*HID*2);
  float*          xposA = (float*)carve((size_t)NN*3*4);
  float*          xposB = (float*)carve((size_t)NN*3*4);
  int*            ie    = (int*)carve((size_t)NE*4);
  float*          tabA  = (float*)carve((size_t)KA*HID*4);
  float*          tabC  = (float*)carve((size_t)KC*HID*4);
  float*          tabEf = (float*)carve((size_t)KE*HID*4);
  float*          gate  = (float*)carve((size_t)NE*4);
  unsigned short* pmbf  = (unsigned short*)carve((size_t)NN*HID*2);
  float*          zbias = (float*)carve(256*4);
  unsigned short* buf01 = (unsigned short*)carve((size_t)2*NE*HID*2);  // c1 | ps1 contiguous
  unsigned short* bufM  = (unsigned short*)carve((size_t)NE*HID*2);    // m
  unsigned short* bufPM = (unsigned short*)carve((size_t)NE*HID*2);    // pm
  unsigned short* P     = (unsigned short*)carve((size_t)4*NN*HID*2);
  // CSR + graph bounds
  int* deg      = (int*)carve(10240*4);
  int* cursor   = (int*)carve(10240*4);
  int* rowstart = (int*)carve(10241*4);
  int* eids     = (int*)carve((size_t)NE*4);
  int* gstart   = (int*)carve((NG+1)*4);
  // transposed bf16 weights
  unsigned short* wNode  = (unsigned short*)carve((size_t)NDEP*1024*256*2);
  unsigned short* wMPM   = (unsigned short*)carve((size_t)NDEP*512*256*2);   // [phimW2 | psimW2]
  unsigned short* wPhix1 = (unsigned short*)carve((size_t)NDEP*256*256*2);
  unsigned short* wUpd1  = (unsigned short*)carve((size_t)NDEP*256*512*2);
  unsigned short* wUpd2  = (unsigned short*)carve((size_t)NDEP*256*256*2);
  unsigned short* wRbf   = (unsigned short*)carve((size_t)NDEP*16*512*2);
  unsigned short* tabE1  = (unsigned short*)carve((size_t)NDEP*5*512*2);

  unsigned short* c1buf = buf01;
  unsigned short* psbuf = buf01 + (size_t)NE*HID;

  // ---- weight conversion ----
  convw_nodeblk<<<dim3(8,4,NDEP), 256, 0, stream>>>(phim_W1, wNode, 0,   0);
  convw_nodeblk<<<dim3(8,4,NDEP), 256, 0, stream>>>(phim_W1, wNode, 256, 256);
  convw_nodeblk<<<dim3(8,4,NDEP), 256, 0, stream>>>(psim_W1, wNode, 0,   512);
  convw_nodeblk<<<dim3(8,4,NDEP), 256, 0, stream>>>(psim_W1, wNode, 256, 768);
  convw_plain<<<dim3(8,4,NDEP), 256, 0, stream>>>(phim_W2, wMPM, 256, 512*256, 0);
  convw_plain<<<dim3(8,4,NDEP), 256, 0, stream>>>(psim_W2, wMPM, 256, 512*256, 256);
  convw_plain<<<dim3(8,4,NDEP), 256, 0, stream>>>(phix_W1, wPhix1, 256, 256*256, 0);
  convw_plain<<<dim3(8,4,NDEP), 256, 0, stream>>>(updh_W2, wUpd2, 256, 256*256, 0);
  convw_plain<<<dim3(16,4,NDEP), 256, 0, stream>>>(updh_W1, wUpd1, 512, 256*512, 0);
  convw_rbf<<<NDEP, 512, 0, stream>>>(phim_W1, psim_W1, wRbf);
  hipMemsetAsync(zbias, 0, 256*4, stream);

  tables_kernel<<<KA + KC + KE, 256, 0, stream>>>(atom_W, charge_W, bond_W, fuse_W, fuse_b,
                                                  lift_W, lift_b, tabA, tabC, tabEf);
  tabe1_kernel<<<dim3(5, NDEP), 512, 0, stream>>>(tabEf, phim_W1, phim_b1, psim_W1, psim_b1, tabE1);
  node_init_kernel<<<NN, 256, 0, stream>>>(a_t, c_t, g_a, g_c, x_t, tabA, tabC, h, hbf, xposA);
  edge_init_kernel<<<(NE + 255)/256, 256, 0, stream>>>(e_t, g_e, ie);

  // ---- CSR build + graph bounds ----
  hipMemsetAsync(deg, 0, 10240*4, stream);
  hist_kernel<<<(NE + 255)/256, 256, 0, stream>>>(dst, deg);
  scan_kernel<<<1, 1024, 0, stream>>>(deg, rowstart, cursor);
  fill_kernel<<<(NE + 255)/256, 256, 0, stream>>>(dst, cursor, eids);
  sortrows_kernel<<<(NN + 255)/256, 256, 0, stream>>>(rowstart, eids);
  gbound_kernel<<<(NN + 255)/256, 256, 0, stream>>>(ngraph, gstart);

  dim3 gridP(4, (NN + 63)/64);     // SMALL: BM=64
  dim3 gridE(1, NE/128);
  dim3 gridE2(1, 2*NE/128);
  dim3 gridNS(1, (NN + 63)/64);    // SMALL node GEMMs

  float* xcur = xposA;
  float* xnxt = xposB;

  for (int d = 0; d < NDEP; ++d) {
    const float* pb2m = phim_b2 + (size_t)d*HID;
    const float* pxb1 = phix_b1 + (size_t)d*HID;
    const float* pxW2 = phix_W2 + (size_t)d*HID;
    const float* pxb2 = phix_b2 + (size_t)d;
    const float* psb2 = psim_b2 + (size_t)d*HID;
    const float* pub1 = updh_b1 + (size_t)d*HID;
    const float* pub2 = updh_b2 + (size_t)d*HID;

    // P = h @ [W1_phim_dst | W1_phim_src | W1_psim_dst | W1_psim_src]  (SMALL tiles)
    mfma_gemm<3, false, false, false, true><<<gridP, 256, 0, stream>>>(
        hbf, nullptr, wNode + (size_t)d*1024*256, zbias, nullptr, P, nullptr, NN, 256, 0,
        nullptr, nullptr, nullptr, nullptr, nullptr, nullptr);
    // c1, ps1 = silu(P[dst]+P[src]+tabE1[ie]+windowed rbf@Wrbf)
    combine2_kernel<<<NE/4, 256, 0, stream>>>(
        src, dst, ie, xcur, P, tabE1 + (size_t)d*5*512, wRbf + (size_t)d*16*512, c1buf, psbuf);
    // merged: m = silu(c1 @ phim_W2 + b2) ; pm = silu(ps1 @ psim_W2 + b2)
    mfma_gemm<4, true, false, false, false><<<gridE2, 512, 0, stream>>>(
        buf01, nullptr, wMPM + (size_t)d*512*256, pb2m, psb2, bufM, bufPM, 2*NE, 256, NE,
        nullptr, nullptr, nullptr, nullptr, nullptr, nullptr);
    // gate = silu(m @ phix_W1 + b1) @ phix_W2
    mfma_gemm<0, false, true, false, false><<<gridE, 512, 0, stream>>>(
        bufM, nullptr, wPhix1 + (size_t)d*256*256, pxb1, nullptr, nullptr, nullptr, NE, 256, 0,
        pxW2, gate, nullptr, nullptr, nullptr, nullptr);
    // pm_sum -> pmbf ; xnxt = xcur + dx (race-free double-buffer)
    gather_pm_dx<<<NN, 256, 0, stream>>>(bufPM, gate, xcur, src, rowstart, eids, pxb2, pmbf, xnxt);
    // u1 = silu([h, pm] @ updh_W1 + b1)  (SMALL tiles)
    mfma_gemm<2, true, false, false, true><<<gridNS, 256, 0, stream>>>(
        hbf, pmbf, wUpd1 + (size_t)d*256*512, pub1, nullptr, bufM, nullptr, NN, 512, 0,
        nullptr, nullptr, nullptr, nullptr, nullptr, nullptr);
    // h = LN(h + u1 @ updh_W2 + b2)  (fused, SMALL tiles)
    mfma_gemm<0, false, false, true, true><<<gridNS, 256, 0, stream>>>(
        bufM, nullptr, wUpd2 + (size_t)d*256*256, pub2, nullptr, nullptr, nullptr, NN, 256, 0,
        nullptr, nullptr, h, hbf, ln_g + (size_t)d*HID, ln_b + (size_t)d*HID);

    float* tmp = xcur; xcur = xnxt; xnxt = tmp;
  }

  // fused readout (no atomics; node_graph sorted -> contiguous ranges)
  readout_kernel<<<NG, 256, 0, stream>>>(h, gstart, head_W, head_b, out);
}

// Round 15
// 1807.978 us; speedup vs baseline: 2.0479x; 1.0266x over previous
//
#include <hip/hip_runtime.h>
#include <math.h>

#define NN   10000
#define NE   80000
#define NG   64
#define HID  256
#define RBFK 16
#define NDEP 6
#define KA   16
#define KC   6
#define KE   5
#define DE   85
#define CATW 784

typedef __attribute__((ext_vector_type(8))) short bf16x8;
typedef __attribute__((ext_vector_type(4))) float f32x4;
typedef __attribute__((ext_vector_type(2))) __bf16 bf16v2;

#if __has_builtin(__builtin_amdgcn_fdot2_f32_bf16)
#define HAVE_BF16_DOT2 1
#else
#define HAVE_BF16_DOT2 0
#endif

static __device__ __forceinline__ float silu_f(float v) { return v / (1.0f + expf(-v)); }

static __device__ __forceinline__ unsigned short f2bf(float f) {
  union { float f; unsigned int u; } v; v.f = f;
  unsigned int r = v.u + 0x7fff + ((v.u >> 16) & 1);
  return (unsigned short)(r >> 16);
}
static __device__ __forceinline__ float bf2f(unsigned short h) {
  union { unsigned int u; float f; } v; v.u = ((unsigned int)h) << 16;
  return v.f;
}
static __device__ __forceinline__ bf16v2 u2bf2(unsigned int u) {
  union { unsigned int u; bf16v2 v; } x; x.u = u; return x.v;
}

static __device__ __forceinline__ void gload16(const void* g, void* l) {
  __builtin_amdgcn_global_load_lds((const __attribute__((address_space(1))) unsigned int*)g,
                                   (__attribute__((address_space(3))) unsigned int*)l, 16, 0, 0);
}

// ---------------- weight transpose-converts ----------------
__global__ void convw_plain(const float* __restrict__ W, unsigned short* __restrict__ Wt, int K,
                            long long wt_dstride, int wt_rowoff) {
  __shared__ float T[32][65];
  int k0 = blockIdx.x * 32, n0 = blockIdx.y * 64, d = blockIdx.z;
  int tid = threadIdx.x;
  int nn = tid & 63, kr = tid >> 6;
  const float* Wd = W + (size_t)d * K * 256;
#pragma unroll
  for (int i = 0; i < 8; ++i) {
    int k = kr + i * 4;
    T[k][nn] = Wd[(size_t)(k0 + k) * 256 + n0 + nn];
  }
  __syncthreads();
  unsigned short* Wtd = Wt + (size_t)d * wt_dstride;
  int kk = tid & 31, nr = tid >> 5;
#pragma unroll
  for (int i = 0; i < 8; ++i) {
    int n = nr + i * 8;
    Wtd[(size_t)(wt_rowoff + n0 + n) * K + k0 + kk] = f2bf(T[kk][n]);
  }
}

__global__ void convw_nodeblk(const float* __restrict__ W, unsigned short* __restrict__ Wt,
                              int src_k0, int nt_base) {
  __shared__ float T[32][65];
  int k0 = blockIdx.x * 32, n0 = blockIdx.y * 64, d = blockIdx.z;
  int tid = threadIdx.x;
  int nn = tid & 63, kr = tid >> 6;
  const float* Wd = W + (size_t)d * CATW * 256;
#pragma unroll
  for (int i = 0; i < 8; ++i) {
    int k = kr + i * 4;
    T[k][nn] = Wd[(size_t)(src_k0 + k0 + k) * 256 + n0 + nn];
  }
  __syncthreads();
  unsigned short* Wtd = Wt + (size_t)d * 1024 * 256;
  int kk = tid & 31, nr = tid >> 5;
#pragma unroll
  for (int i = 0; i < 8; ++i) {
    int n = nr + i * 8;
    Wtd[(size_t)(nt_base + n0 + n) * 256 + k0 + kk] = f2bf(T[kk][n]);
  }
}

// wR [D][16][512] bf16: rbf rows (512..527) of phim_W1 (cols 0:256) / psim_W1 (cols 256:512)
__global__ void convw_rbf(const float* __restrict__ phimW1, const float* __restrict__ psimW1,
                          unsigned short* __restrict__ wR) {
  int d = blockIdx.x, j = threadIdx.x;
  int jj = j & 255;
  const float* W = (j < 256) ? phimW1 : psimW1;
  for (int k = 0; k < 16; ++k)
    wR[((size_t)d * 16 + k) * 512 + j] = f2bf(W[(size_t)d * CATW * 256 + (size_t)(512 + k) * 256 + jj]);
}

// wRp [D][8][512] dwords: pair-packed (k=2p low | k=2p+1 high)
__global__ void convw_rbf2(const float* __restrict__ phimW1, const float* __restrict__ psimW1,
                           unsigned int* __restrict__ wRp) {
  int d = blockIdx.x, j = threadIdx.x;
  int jj = j & 255;
  const float* W = (j < 256) ? phimW1 : psimW1;
  const float* base = W + (size_t)d * CATW * 256;
  for (int p = 0; p < 8; ++p) {
    unsigned int lo = f2bf(base[(size_t)(512 + 2*p) * 256 + jj]);
    unsigned int hi = f2bf(base[(size_t)(512 + 2*p + 1) * 256 + jj]);
    wRp[((size_t)d * 8 + p) * 512 + j] = lo | (hi << 16);
  }
}

// ---------------- tables ----------------
__global__ void tables_kernel(const float* __restrict__ atom_W, const float* __restrict__ charge_W,
                              const float* __restrict__ bond_W, const float* __restrict__ fuse_W,
                              const float* __restrict__ fuse_b, const float* __restrict__ lift_W,
                              const float* __restrict__ lift_b,
                              float* __restrict__ tabA, float* __restrict__ tabC,
                              float* __restrict__ tabEf) {
  int r = blockIdx.x, k = threadIdx.x;
  if (r < KA) {
    float s = 0.f;
    for (int d = 0; d < DE; ++d) s += atom_W[r*DE + d] * fuse_W[d*HID + k];
    tabA[r*HID + k] = s + fuse_b[k];
  } else if (r < KA + KC) {
    int rr = r - KA;
    float s = 0.f;
    for (int d = 0; d < DE; ++d) s += charge_W[rr*DE + d] * fuse_W[(DE + d)*HID + k];
    tabC[rr*HID + k] = s;
  } else {
    int rr = r - KA - KC;
    float s = 0.f;
    for (int d = 0; d < DE; ++d) s += bond_W[rr*DE + d] * lift_W[d*HID + k];
    tabEf[rr*HID + k] = s + lift_b[k];
  }
}

// tabE1 [D][5][512] bf16 = tabEf @ W1_eemb (+ b1), phim cols 0:256, psim cols 256:512
__global__ void tabe1_kernel(const float* __restrict__ tabEf,
                             const float* __restrict__ phimW1, const float* __restrict__ phimb1,
                             const float* __restrict__ psimW1, const float* __restrict__ psimb1,
                             unsigned short* __restrict__ tabE1) {
  int r = blockIdx.x, d = blockIdx.y, j = threadIdx.x;
  const float* W = (j < 256) ? phimW1 : psimW1;
  const float* b = (j < 256) ? phimb1 : psimb1;
  int jj = j & 255;
  float s = b[d*256 + jj];
  for (int k = 0; k < 256; ++k)
    s += tabEf[r*256 + k] * W[(size_t)d*CATW*256 + (size_t)(528 + k)*256 + jj];
  tabE1[((size_t)d*5 + r)*512 + j] = f2bf(s);
}

// ---------------- node / edge init ----------------
__global__ void node_init_kernel(const float* __restrict__ a_t, const float* __restrict__ c_t,
                                 const float* __restrict__ g_a, const float* __restrict__ g_c,
                                 const float* __restrict__ x_t, const float* __restrict__ tabA,
                                 const float* __restrict__ tabC, float* __restrict__ h,
                                 unsigned short* __restrict__ hbf, float* __restrict__ x) {
  int n = blockIdx.x;
  __shared__ int s_ia, s_ic;
  if (threadIdx.x == 0) {
    float best = -1e30f; int bi = 0;
    for (int j = 0; j < KA; ++j) {
      float v = logf(fmaxf(a_t[n*KA + j], 1e-12f)) + g_a[n*KA + j];
      if (v > best) { best = v; bi = j; }
    }
    s_ia = bi;
  }
  if (threadIdx.x == 1) {
    float best = -1e30f; int bi = 0;
    for (int j = 0; j < KC; ++j) {
      float v = logf(fmaxf(c_t[n*KC + j], 1e-12f)) + g_c[n*KC + j];
      if (v > best) { best = v; bi = j; }
    }
    s_ic = bi;
  }
  __syncthreads();
  int k = threadIdx.x;
  float v = tabA[s_ia*HID + k] + tabC[s_ic*HID + k];
  h[n*HID + k] = v;
  hbf[n*HID + k] = f2bf(v);
  if (k < 3) x[n*3 + k] = x_t[n*3 + k];
}

__global__ void edge_init_kernel(const float* __restrict__ e_t, const float* __restrict__ g_e,
                                 int* __restrict__ ie) {
  int e = blockIdx.x * blockDim.x + threadIdx.x;
  if (e >= NE) return;
  float best = -1e30f; int bi = 0;
  for (int j = 0; j < KE; ++j) {
    float v = logf(fmaxf(e_t[e*KE + j], 1e-12f)) + g_e[e*KE + j];
    if (v > best) { best = v; bi = j; }
  }
  ie[e] = bi;
}

// ---------------- CSR build ----------------
__global__ void hist_kernel(const int* __restrict__ dst, int* __restrict__ deg) {
  int e = blockIdx.x * 256 + threadIdx.x;
  if (e < NE) atomicAdd(&deg[dst[e]], 1);
}

__global__ void scan_kernel(const int* __restrict__ deg, int* __restrict__ rowstart,
                            int* __restrict__ cursor) {
  __shared__ int tmp[1024];
  int t = threadIdx.x;
  int base = t * 10;
  int local[10];
  int s = 0;
#pragma unroll
  for (int i = 0; i < 10; ++i) { local[i] = deg[base + i]; s += local[i]; }
  tmp[t] = s;
  __syncthreads();
  for (int off = 1; off < 1024; off <<= 1) {
    int v = (t >= off) ? tmp[t - off] : 0;
    __syncthreads();
    tmp[t] += v;
    __syncthreads();
  }
  int run = (t == 0) ? 0 : tmp[t - 1];
#pragma unroll
  for (int i = 0; i < 10; ++i) {
    rowstart[base + i] = run; cursor[base + i] = run; run += local[i];
  }
  if (t == 1023) rowstart[10240] = run;
}

__global__ void fill_kernel(const int* __restrict__ dst, int* __restrict__ cursor,
                            int* __restrict__ eids) {
  int e = blockIdx.x * 256 + threadIdx.x;
  if (e >= NE) return;
  int pos = atomicAdd(&cursor[dst[e]], 1);
  eids[pos] = e;
}

__global__ void sortrows_kernel(const int* __restrict__ rowstart, int* __restrict__ eids) {
  int n = blockIdx.x * 256 + threadIdx.x;
  if (n >= NN) return;
  int s = rowstart[n], e = rowstart[n + 1];
  for (int i = s + 1; i < e; ++i) {
    int v = eids[i]; int j = i - 1;
    while (j >= s && eids[j] > v) { eids[j + 1] = eids[j]; --j; }
    eids[j + 1] = v;
  }
}

// ---------------- graph boundaries (node_graph is sorted) ----------------
__global__ void gbound_kernel(const int* __restrict__ ng, int* __restrict__ gstart) {
  int n = blockIdx.x * 256 + threadIdx.x;
  if (n >= NN) return;
  if (n == 0) {
    for (int g = 0; g <= ng[0]; ++g) gstart[g] = 0;
  } else {
    int a = ng[n-1], b = ng[n];
    for (int g = a + 1; g <= b; ++g) gstart[g] = n;
  }
  if (n == NN - 1) {
    for (int g = ng[n] + 1; g <= NG; ++g) gstart[g] = NN;
  }
}

// ---------------- combine2: one edge per 64 lanes; windowed rbf (8 centers) ----------------
__global__ __launch_bounds__(256) void combine2_kernel(
    const int* __restrict__ srcp, const int* __restrict__ dstp, const int* __restrict__ iep,
    const float* __restrict__ x,
    const unsigned short* __restrict__ P,      // [4][NN][256] bf16
    const unsigned short* __restrict__ tabE1,  // [5][512] bf16, this depth
    const unsigned short* __restrict__ wR,     // [16][512] bf16, this depth (scalar path)
    const unsigned int* __restrict__ wRp,      // [8][512] packed pairs, this depth (dot2 path)
    unsigned short* __restrict__ c1, unsigned short* __restrict__ ps1) {
  const int tid = threadIdx.x;
  const int lane = tid & 63;
  const int e = blockIdx.x * 4 + (tid >> 6);
  const int half = lane >> 5;            // 0: phim, 1: psim
  const int c8 = (lane & 31) * 8;        // col within 256
  const int ds = dstp[e], sr = srcp[e], ib = iep[e];
  float r0 = x[ds*3+0] - x[sr*3+0];
  float r1 = x[ds*3+1] - x[sr*3+1];
  float r2 = x[ds*3+2] - x[sr*3+2];
  float dist = sqrtf(r0*r0 + r1*r1 + r2*r2);
  int klo = (int)(dist * 1.5f) - 3;
  klo = klo < 0 ? 0 : (klo > 8 ? 8 : klo);
  const unsigned short* Pb0 = P + (size_t)(half * 2) * NN * 256;
  const unsigned short* Pb1 = P + (size_t)(half * 2 + 1) * NN * 256;
  bf16x8 pa = *(const bf16x8*)&Pb0[(size_t)ds * 256 + c8];
  bf16x8 pb = *(const bf16x8*)&Pb1[(size_t)sr * 256 + c8];
  bf16x8 te = *(const bf16x8*)&tabE1[(size_t)ib * 512 + lane * 8];
  float zv[8];
#pragma unroll
  for (int j = 0; j < 8; ++j)
    zv[j] = bf2f((unsigned short)pa[j]) + bf2f((unsigned short)pb[j]) + bf2f((unsigned short)te[j]);
#if HAVE_BF16_DOT2
  int plo = klo >> 1;                    // even-aligned 8-center window as 4 pairs
  if (plo > 4) plo = 4;
#pragma unroll
  for (int pp = 0; pp < 4; ++pp) {
    int pr = plo + pp;
    float k0f = (float)(2 * pr);
    float z0 = (dist - 0.66666667f * k0f) * 1.6f;
    float z1 = (dist - 0.66666667f * (k0f + 1.0f)) * 1.6f;
    unsigned int rkp = (unsigned int)f2bf(expf(-0.5f * z0 * z0)) |
                       ((unsigned int)f2bf(expf(-0.5f * z1 * z1)) << 16);
    bf16v2 rv = u2bf2(rkp);
    const unsigned int* w8 = wRp + (size_t)pr * 512 + lane * 8;
    uint4 wa = *(const uint4*)w8;
    uint4 wb = *(const uint4*)(w8 + 4);
    zv[0] = __builtin_amdgcn_fdot2_f32_bf16(rv, u2bf2(wa.x), zv[0], false);
    zv[1] = __builtin_amdgcn_fdot2_f32_bf16(rv, u2bf2(wa.y), zv[1], false);
    zv[2] = __builtin_amdgcn_fdot2_f32_bf16(rv, u2bf2(wa.z), zv[2], false);
    zv[3] = __builtin_amdgcn_fdot2_f32_bf16(rv, u2bf2(wa.w), zv[3], false);
    zv[4] = __builtin_amdgcn_fdot2_f32_bf16(rv, u2bf2(wb.x), zv[4], false);
    zv[5] = __builtin_amdgcn_fdot2_f32_bf16(rv, u2bf2(wb.y), zv[5], false);
    zv[6] = __builtin_amdgcn_fdot2_f32_bf16(rv, u2bf2(wb.z), zv[6], false);
    zv[7] = __builtin_amdgcn_fdot2_f32_bf16(rv, u2bf2(wb.w), zv[7], false);
  }
#else
  (void)wRp;
#pragma unroll
  for (int kk = 0; kk < 8; ++kk) {
    int k = klo + kk;
    float z = (dist - 0.66666667f * (float)k) * 1.6f;
    float rk = expf(-0.5f * z * z);
    bf16x8 wv = *(const bf16x8*)&wR[k * 512 + lane * 8];
#pragma unroll
    for (int j = 0; j < 8; ++j)
      zv[j] += rk * bf2f((unsigned short)wv[j]);
  }
#endif
  unsigned short ov[8];
#pragma unroll
  for (int j = 0; j < 8; ++j) ov[j] = f2bf(silu_f(zv[j]));
  unsigned short* outp = half ? ps1 : c1;
  *(uint4*)&outp[(size_t)e * 256 + c8] = *(uint4*)ov;
}

// ---------------- MFMA bf16 GEMM: BN=256, BK=64; BM=128 (512 thr) or SMALL BM=64 (256 thr) ----------------
// MODE 0: A bf16 [M][256], Kp=256
// MODE 2: A = [A | A2] (each [M][256]), Kp=512
// MODE 3: multi-chunk C: Cw = C + (bn>>8)*M*256 (no silu; bias = zeros)
// MODE 4: merged dual GEMM: rows >= Msplit use weight chunk 1 / bias2 / C2
// GATE:   gout[row] = sum_col silu(acc+b1[col]) * gw2[col]
// LNOUT:  h/hbf = LayerNorm(h + acc + bias) * lng + lnb  (fused upd2+LN)
template<int MODE, bool SILU, bool GATE, bool LNOUT, bool SMALL>
__global__ __launch_bounds__(SMALL ? 256 : 512, 4) void mfma_gemm(
    const unsigned short* __restrict__ A, const unsigned short* __restrict__ A2,
    const unsigned short* __restrict__ Wt,
    const float* __restrict__ bias, const float* __restrict__ bias2,
    unsigned short* __restrict__ C, unsigned short* __restrict__ C2,
    int M, int Kp, int Msplit,
    const float* __restrict__ gw2, float* __restrict__ gout,
    float* __restrict__ hf, unsigned short* __restrict__ hb,
    const float* __restrict__ lng, const float* __restrict__ lnb) {
  constexpr int BM = SMALL ? 64 : 128;
  constexpr int BQ = SMALL ? 8 : 4;            // B-stage issues per wave
  __shared__ unsigned short lds[SMALL ? 20480 : 24576];   // As BM*64 + Bs 256*64
  unsigned short* As = lds;                    // [BM][64] XOR-swizzled
  unsigned short* Bs = lds + BM * 64;          // [256][64] XOR-swizzled
  const int tid = threadIdx.x;
  const int bn = blockIdx.x * 256;
  const int bm = blockIdx.y * BM;
  const int lane = tid & 63;
  const int w = tid >> 6;
  const int wr = SMALL ? 0 : (w >> 2);
  const int wc = SMALL ? w : (w & 3);
  const int subrow = lane >> 3;
  const int kd = 8 * ((lane & 7) ^ subrow);

  const bool half2 = (MODE == 4) && (bm >= Msplit);
  const unsigned short* Wb = Wt + (half2 ? 256 * 256 : 0);

  unsigned int offB[BQ];
#pragma unroll
  for (int q = 0; q < BQ; ++q)
    offB[q] = (unsigned)(bn + w * (BQ * 8) + q * 8 + subrow) * (unsigned)Kp;

  unsigned int offA[2];
#pragma unroll
  for (int q = 0; q < 2; ++q) {
    int m = bm + w * 16 + q * 8 + subrow;
    int mc = (m < M) ? m : (M - 1);
    offA[q] = (unsigned)mc * 256u;
  }

  const int nt = Kp >> 6;
  f32x4 acc[4][4] = {};

  for (int t = 0; t < nt; ++t) {
    const int k0 = t << 6;
#pragma unroll
    for (int q = 0; q < 2; ++q) {
      const unsigned short* gp;
      if (MODE == 2) gp = (k0 < 256) ? (A + offA[q] + k0 + kd) : (A2 + offA[q] + (k0 - 256) + kd);
      else gp = A + offA[q] + k0 + kd;
      gload16(gp, (char*)As + w * 2048 + q * 1024);
    }
#pragma unroll
    for (int q = 0; q < BQ; ++q)
      gload16(Wb + offB[q] + k0 + kd, (char*)Bs + w * (BQ * 1024) + q * 1024);
    __syncthreads();
#pragma unroll
    for (int ks = 0; ks < 2; ++ks) {
      const int kb = (ks * 64 + ((lane >> 4) << 4)) ^ ((lane & 7) << 4);
      bf16x8 bfv[4];
#pragma unroll
      for (int j = 0; j < 4; ++j)
        bfv[j] = *(const bf16x8*)((const char*)Bs + (wc * 64 + j * 16 + (lane & 15)) * 128 + kb);
#pragma unroll
      for (int i = 0; i < 4; ++i) {
        bf16x8 af = *(const bf16x8*)((const char*)As + (wr * 64 + i * 16 + (lane & 15)) * 128 + kb);
#pragma unroll
        for (int j = 0; j < 4; ++j)
          acc[i][j] = __builtin_amdgcn_mfma_f32_16x16x32_bf16(af, bfv[j], acc[i][j], 0, 0, 0);
      }
    }
    __syncthreads();
  }

  if (GATE) {
    float bcol[4], wcol[4];
#pragma unroll
    for (int j = 0; j < 4; ++j) {
      int col = wc * 64 + j * 16 + (lane & 15);
      bcol[j] = bias[col];
      wcol[j] = gw2[col];
    }
    float* part = (float*)lds;   // [4][BM]
#pragma unroll
    for (int i = 0; i < 4; ++i) {
#pragma unroll
      for (int q = 0; q < 4; ++q) {
        float lsum = 0.f;
#pragma unroll
        for (int j = 0; j < 4; ++j)
          lsum += silu_f(acc[i][j][q] + bcol[j]) * wcol[j];
        lsum += __shfl_xor(lsum, 1, 64);
        lsum += __shfl_xor(lsum, 2, 64);
        lsum += __shfl_xor(lsum, 4, 64);
        lsum += __shfl_xor(lsum, 8, 64);
        if ((lane & 15) == 0) {
          int rl = wr * 64 + i * 16 + ((lane >> 4) << 2) + q;
          part[wc * BM + rl] = lsum;
        }
      }
    }
    __syncthreads();
    if (tid < BM)
      gout[bm + tid] = part[tid] + part[BM + tid] + part[2*BM + tid] + part[3*BM + tid];
    return;
  }

  if (LNOUT) {
    float bcol[4], lgc[4], lbc[4];
#pragma unroll
    for (int j = 0; j < 4; ++j) {
      int col = wc * 64 + j * 16 + (lane & 15);
      bcol[j] = bias[col]; lgc[j] = lng[col]; lbc[j] = lnb[col];
    }
    float* part = (float*)lds;       // [4][BM]
    float* stat = part + 4 * BM;     // mu[BM], rstd[BM]
#pragma unroll
    for (int i = 0; i < 4; ++i)
#pragma unroll
      for (int q = 0; q < 4; ++q) {
        int rl = wr * 64 + i * 16 + ((lane >> 4) << 2) + q;
        int grow = bm + rl;
        float s = 0.f;
#pragma unroll
        for (int j = 0; j < 4; ++j) {
          int col = wc * 64 + j * 16 + (lane & 15);
          float hv = (grow < M) ? hf[(size_t)grow * 256 + col] : 0.f;
          float zz = acc[i][j][q] + bcol[j] + hv;
          acc[i][j][q] = zz;
          s += zz;
        }
        s += __shfl_xor(s, 1, 64); s += __shfl_xor(s, 2, 64);
        s += __shfl_xor(s, 4, 64); s += __shfl_xor(s, 8, 64);
        if ((lane & 15) == 0) part[wc * BM + rl] = s;
      }
    __syncthreads();
    if (tid < BM)
      stat[tid] = (part[tid] + part[BM + tid] + part[2*BM + tid] + part[3*BM + tid]) * (1.f / 256.f);
    __syncthreads();
#pragma unroll
    for (int i = 0; i < 4; ++i)
#pragma unroll
      for (int q = 0; q < 4; ++q) {
        int rl = wr * 64 + i * 16 + ((lane >> 4) << 2) + q;
        float mu = stat[rl];
        float s2 = 0.f;
#pragma unroll
        for (int j = 0; j < 4; ++j) { float d_ = acc[i][j][q] - mu; s2 += d_ * d_; }
        s2 += __shfl_xor(s2, 1, 64); s2 += __shfl_xor(s2, 2, 64);
        s2 += __shfl_xor(s2, 4, 64); s2 += __shfl_xor(s2, 8, 64);
        if ((lane & 15) == 0) part[wc * BM + rl] = s2;
      }
    __syncthreads();
    if (tid < BM)
      stat[BM + tid] = 1.f / sqrtf((part[tid] + part[BM + tid] + part[2*BM + tid] + part[3*BM + tid]) * (1.f / 256.f) + 1e-5f);
    __syncthreads();
#pragma unroll
    for (int i = 0; i < 4; ++i)
#pragma unroll
      for (int q = 0; q < 4; ++q) {
        int rl = wr * 64 + i * 16 + ((lane >> 4) << 2) + q;
        int grow = bm + rl;
        if (grow < M) {
          float mu = stat[rl], rs = stat[BM + rl];
#pragma unroll
          for (int j = 0; j < 4; ++j) {
            int col = wc * 64 + j * 16 + (lane & 15);
            float o = (acc[i][j][q] - mu) * rs * lgc[j] + lbc[j];
            hf[(size_t)grow * 256 + col] = o;
            hb[(size_t)grow * 256 + col] = f2bf(o);
          }
        }
      }
    return;
  }

  // normal epilogue: coalesced C-store via LDS transpose
  const float* biasw = bias;
  unsigned short* Cw = C;
  int rowoff = 0;
  if (MODE == 3) Cw = C + (size_t)(bn >> 8) * (size_t)M * 256;
  if (MODE == 4 && half2) { biasw = bias2; Cw = C2; rowoff = Msplit; }

  float bcol[4];
#pragma unroll
  for (int j = 0; j < 4; ++j) bcol[j] = biasw[wc * 64 + j * 16 + (lane & 15)];

  unsigned short* T = lds;   // [BM][136]
#pragma unroll
  for (int hh = 0; hh < 2; ++hh) {
    if ((wc >> 1) == hh) {
#pragma unroll
      for (int i = 0; i < 4; ++i)
#pragma unroll
        for (int j = 0; j < 4; ++j)
#pragma unroll
          for (int q = 0; q < 4; ++q) {
            int rl = wr * 64 + i * 16 + ((lane >> 4) << 2) + q;
            int cl = (wc & 1) * 64 + j * 16 + (lane & 15);
            float v = acc[i][j][q] + bcol[j];
            if (SILU) v = silu_f(v);
            T[rl * 136 + cl] = f2bf(v);
          }
    }
    __syncthreads();
#pragma unroll
    for (int it = 0; it < 4; ++it) {
      int row = it * (BM / 4) + (tid >> 4);
      int grow = bm + row;
      if (grow < M) {
        uint4 v = *(const uint4*)&T[row * 136 + (tid & 15) * 8];
        *(uint4*)&Cw[(size_t)(grow - rowoff) * 256 + hh * 128 + (tid & 15) * 8] = v;
      }
    }
    __syncthreads();
  }
}

// ---------------- CSR gather: pm_sum (bf16 out) + dx; x double-buffered ----------------
__global__ void gather_pm_dx(const unsigned short* __restrict__ pm, const float* __restrict__ gate,
                             const float* __restrict__ xcur, const int* __restrict__ srcp,
                             const int* __restrict__ rowstart, const int* __restrict__ eids,
                             const float* __restrict__ gb2,
                             unsigned short* __restrict__ pmbf, float* __restrict__ xnxt) {
  int n = blockIdx.x, k = threadIdx.x;
  int s = rowstart[n], e1 = rowstart[n + 1];
  float acc = 0.f, dx = 0.f;
  float b2 = gb2[0];
  float xn = (k < 3) ? xcur[n*3 + k] : 0.f;
  for (int t = s; t < e1; ++t) {
    int e = eids[t];
    acc += bf2f(pm[(size_t)e*HID + k]);
    if (k < 3) dx += (xn - xcur[srcp[e]*3 + k]) * (gate[e] + b2);
  }
  pmbf[(size_t)n*HID + k] = f2bf(acc);
  if (k < 3) xnxt[n*3 + k] = xn + dx;
}

// ---------------- fused readout: per-graph column sums + head dot + sigmoid ----------------
__global__ void readout_kernel(const float* __restrict__ h, const int* __restrict__ gstart,
                               const float* __restrict__ head_W, const float* __restrict__ head_b,
                               float* __restrict__ out) {
  int g = blockIdx.x, k = threadIdx.x;
  int s = gstart[g], e = gstart[g + 1];
  float acc = 0.f;
  for (int n = s; n < e; ++n) acc += h[(size_t)n * HID + k];
  float v = acc * head_W[k];
  __shared__ float red[4];
  int lane = k & 63, wv = k >> 6;
#pragma unroll
  for (int off = 32; off > 0; off >>= 1) v += __shfl_down(v, off, 64);
  if (lane == 0) red[wv] = v;
  __syncthreads();
  if (k == 0) {
    float dot = red[0] + red[1] + red[2] + red[3];
    float c = fmaxf((float)(e - s), 1.0f);
    float val = (dot / c + head_b[0]) * 0.5f;
    out[g] = 1.0f / (1.0f + expf(-val));
  }
}

extern "C" void kernel_launch(void* const* d_in, const int* in_sizes, int n_in,
                              void* d_out, int out_size, void* d_ws, size_t ws_size,
                              hipStream_t stream) {
  (void)in_sizes; (void)n_in; (void)out_size; (void)ws_size;
  const float* a_t      = (const float*)d_in[0];
  const float* c_t      = (const float*)d_in[1];
  const float* e_t      = (const float*)d_in[2];
  const float* x_t      = (const float*)d_in[3];
  const float* g_a      = (const float*)d_in[4];
  const float* g_c      = (const float*)d_in[5];
  const float* g_e      = (const float*)d_in[6];
  const float* atom_W   = (const float*)d_in[7];
  const float* charge_W = (const float*)d_in[8];
  const float* bond_W   = (const float*)d_in[9];
  const float* fuse_W   = (const float*)d_in[10];
  const float* fuse_b   = (const float*)d_in[11];
  const float* lift_W   = (const float*)d_in[12];
  const float* lift_b   = (const float*)d_in[13];
  const float* phim_W1  = (const float*)d_in[14];
  const float* phim_b1  = (const float*)d_in[15];
  const float* phim_W2  = (const float*)d_in[16];
  const float* phim_b2  = (const float*)d_in[17];
  const float* phix_W1  = (const float*)d_in[18];
  const float* phix_b1  = (const float*)d_in[19];
  const float* phix_W2  = (const float*)d_in[20];
  const float* phix_b2  = (const float*)d_in[21];
  const float* psim_W1  = (const float*)d_in[22];
  const float* psim_b1  = (const float*)d_in[23];
  const float* psim_W2  = (const float*)d_in[24];
  const float* psim_b2  = (const float*)d_in[25];
  const float* updh_W1  = (const float*)d_in[26];
  const float* updh_b1  = (const float*)d_in[27];
  const float* updh_W2  = (const float*)d_in[28];
  const float* updh_b2  = (const float*)d_in[29];
  const float* ln_g     = (const float*)d_in[30];
  const float* ln_b     = (const float*)d_in[31];
  const float* head_W   = (const float*)d_in[32];
  const float* head_b   = (const float*)d_in[33];
  const int*   src      = (const int*)d_in[34];
  const int*   dst      = (const int*)d_in[35];
  const int*   ngraph   = (const int*)d_in[36];
  float* out = (float*)d_out;

  char* p = (char*)d_ws;
  auto carve = [&](size_t bytes) -> char* {
    char* r = p; p += (bytes + 255) & ~(size_t)255; return r;
  };
  float*          h     = (float*)carve((size_t)NN*HID*4);
  unsigned short* hbf   = (unsigned short*)carve((size_t)NN*HID*2);
  float*          xposA = (float*)carve((size_t)NN*3*4);
  float*          xposB = (float*)carve((size_t)NN*3*4);
  int*            ie    = (int*)carve((size_t)NE*4);
  float*          tabA  = (float*)carve((size_t)KA*HID*4);
  float*          tabC  = (float*)carve((size_t)KC*HID*4);
  float*          tabEf = (float*)carve((size_t)KE*HID*4);
  float*          gate  = (float*)carve((size_t)NE*4);
  unsigned short* pmbf  = (unsigned short*)carve((size_t)NN*HID*2);
  float*          zbias = (float*)carve(256*4);
  unsigned short* buf01 = (unsigned short*)carve((size_t)2*NE*HID*2);  // c1 | ps1 contiguous
  unsigned short* bufM  = (unsigned short*)carve((size_t)NE*HID*2);    // m
  unsigned short* bufPM = (unsigned short*)carve((size_t)NE*HID*2);    // pm
  unsigned short* P     = (unsigned short*)carve((size_t)4*NN*HID*2);
  // CSR + graph bounds
  int* deg      = (int*)carve(10240*4);
  int* cursor   = (int*)carve(10240*4);
  int* rowstart = (int*)carve(10241*4);
  int* eids     = (int*)carve((size_t)NE*4);
  int* gstart   = (int*)carve((NG+1)*4);
  // transposed bf16 weights
  unsigned short* wNode  = (unsigned short*)carve((size_t)NDEP*1024*256*2);
  unsigned short* wMPM   = (unsigned short*)carve((size_t)NDEP*512*256*2);   // [phimW2 | psimW2]
  unsigned short* wPhix1 = (unsigned short*)carve((size_t)NDEP*256*256*2);
  unsigned short* wUpd1  = (unsigned short*)carve((size_t)NDEP*256*512*2);
  unsigned short* wUpd2  = (unsigned short*)carve((size_t)NDEP*256*256*2);
  unsigned short* wRbf   = (unsigned short*)carve((size_t)NDEP*16*512*2);
  unsigned int*   wRbfP  = (unsigned int*)carve((size_t)NDEP*8*512*4);
  unsigned short* tabE1  = (unsigned short*)carve((size_t)NDEP*5*512*2);

  unsigned short* c1buf = buf01;
  unsigned short* psbuf = buf01 + (size_t)NE*HID;

  // ---- weight conversion ----
  convw_nodeblk<<<dim3(8,4,NDEP), 256, 0, stream>>>(phim_W1, wNode, 0,   0);
  convw_nodeblk<<<dim3(8,4,NDEP), 256, 0, stream>>>(phim_W1, wNode, 256, 256);
  convw_nodeblk<<<dim3(8,4,NDEP), 256, 0, stream>>>(psim_W1, wNode, 0,   512);
  convw_nodeblk<<<dim3(8,4,NDEP), 256, 0, stream>>>(psim_W1, wNode, 256, 768);
  convw_plain<<<dim3(8,4,NDEP), 256, 0, stream>>>(phim_W2, wMPM, 256, 512*256, 0);
  convw_plain<<<dim3(8,4,NDEP), 256, 0, stream>>>(psim_W2, wMPM, 256, 512*256, 256);
  convw_plain<<<dim3(8,4,NDEP), 256, 0, stream>>>(phix_W1, wPhix1, 256, 256*256, 0);
  convw_plain<<<dim3(8,4,NDEP), 256, 0, stream>>>(updh_W2, wUpd2, 256, 256*256, 0);
  convw_plain<<<dim3(16,4,NDEP), 256, 0, stream>>>(updh_W1, wUpd1, 512, 256*512, 0);
  convw_rbf<<<NDEP, 512, 0, stream>>>(phim_W1, psim_W1, wRbf);
  convw_rbf2<<<NDEP, 512, 0, stream>>>(phim_W1, psim_W1, wRbfP);
  hipMemsetAsync(zbias, 0, 256*4, stream);

  tables_kernel<<<KA + KC + KE, 256, 0, stream>>>(atom_W, charge_W, bond_W, fuse_W, fuse_b,
                                                  lift_W, lift_b, tabA, tabC, tabEf);
  tabe1_kernel<<<dim3(5, NDEP), 512, 0, stream>>>(tabEf, phim_W1, phim_b1, psim_W1, psim_b1, tabE1);
  node_init_kernel<<<NN, 256, 0, stream>>>(a_t, c_t, g_a, g_c, x_t, tabA, tabC, h, hbf, xposA);
  edge_init_kernel<<<(NE + 255)/256, 256, 0, stream>>>(e_t, g_e, ie);

  // ---- CSR build + graph bounds ----
  hipMemsetAsync(deg, 0, 10240*4, stream);
  hist_kernel<<<(NE + 255)/256, 256, 0, stream>>>(dst, deg);
  scan_kernel<<<1, 1024, 0, stream>>>(deg, rowstart, cursor);
  fill_kernel<<<(NE + 255)/256, 256, 0, stream>>>(dst, cursor, eids);
  sortrows_kernel<<<(NN + 255)/256, 256, 0, stream>>>(rowstart, eids);
  gbound_kernel<<<(NN + 255)/256, 256, 0, stream>>>(ngraph, gstart);

  dim3 gridP(4, (NN + 63)/64);     // SMALL: BM=64
  dim3 gridE(1, NE/128);
  dim3 gridE2(1, 2*NE/128);
  dim3 gridNS(1, (NN + 63)/64);    // SMALL node GEMMs

  float* xcur = xposA;
  float* xnxt = xposB;

  for (int d = 0; d < NDEP; ++d) {
    const float* pb2m = phim_b2 + (size_t)d*HID;
    const float* pxb1 = phix_b1 + (size_t)d*HID;
    const float* pxW2 = phix_W2 + (size_t)d*HID;
    const float* pxb2 = phix_b2 + (size_t)d;
    const float* psb2 = psim_b2 + (size_t)d*HID;
    const float* pub1 = updh_b1 + (size_t)d*HID;
    const float* pub2 = updh_b2 + (size_t)d*HID;

    // P = h @ [W1_phim_dst | W1_phim_src | W1_psim_dst | W1_psim_src]  (SMALL tiles)
    mfma_gemm<3, false, false, false, true><<<gridP, 256, 0, stream>>>(
        hbf, nullptr, wNode + (size_t)d*1024*256, zbias, nullptr, P, nullptr, NN, 256, 0,
        nullptr, nullptr, nullptr, nullptr, nullptr, nullptr);
    // c1, ps1 = silu(P[dst]+P[src]+tabE1[ie]+windowed rbf@Wrbf)
    combine2_kernel<<<NE/4, 256, 0, stream>>>(
        src, dst, ie, xcur, P, tabE1 + (size_t)d*5*512, wRbf + (size_t)d*16*512,
        wRbfP + (size_t)d*8*512, c1buf, psbuf);
    // merged: m = silu(c1 @ phim_W2 + b2) ; pm = silu(ps1 @ psim_W2 + b2)
    mfma_gemm<4, true, false, false, false><<<gridE2, 512, 0, stream>>>(
        buf01, nullptr, wMPM + (size_t)d*512*256, pb2m, psb2, bufM, bufPM, 2*NE, 256, NE,
        nullptr, nullptr, nullptr, nullptr, nullptr, nullptr);
    // gate = silu(m @ phix_W1 + b1) @ phix_W2
    mfma_gemm<0, false, true, false, false><<<gridE, 512, 0, stream>>>(
        bufM, nullptr, wPhix1 + (size_t)d*256*256, pxb1, nullptr, nullptr, nullptr, NE, 256, 0,
        pxW2, gate, nullptr, nullptr, nullptr, nullptr);
    // pm_sum -> pmbf ; xnxt = xcur + dx (race-free double-buffer)
    gather_pm_dx<<<NN, 256, 0, stream>>>(bufPM, gate, xcur, src, rowstart, eids, pxb2, pmbf, xnxt);
    // u1 = silu([h, pm] @ updh_W1 + b1)  (SMALL tiles)
    mfma_gemm<2, true, false, false, true><<<gridNS, 256, 0, stream>>>(
        hbf, pmbf, wUpd1 + (size_t)d*256*512, pub1, nullptr, bufM, nullptr, NN, 512, 0,
        nullptr, nullptr, nullptr, nullptr, nullptr, nullptr);
    // h = LN(h + u1 @ updh_W2 + b2)  (fused, SMALL tiles)
    mfma_gemm<0, false, false, true, true><<<gridNS, 256, 0, stream>>>(
        bufM, nullptr, wUpd2 + (size_t)d*256*256, pub2, nullptr, nullptr, nullptr, NN, 256, 0,
        nullptr, nullptr, h, hbf, ln_g + (size_t)d*HID, ln_b + (size_t)d*HID);

    float* tmp = xcur; xcur = xnxt; xnxt = tmp;
  }

  // fused readout (no atomics; node_graph sorted -> contiguous ranges)
  readout_kernel<<<NG, 256, 0, stream>>>(h, gstart, head_W, head_b, out);
}

// Round 16
// 1555.430 us; speedup vs baseline: 2.3804x; 1.1624x over previous
//
#include <hip/hip_runtime.h>
#include <math.h>

#define NN   10000
#define NE   80000
#define NG   64
#define HID  256
#define RBFK 16
#define NDEP 6
#define KA   16
#define KC   6
#define KE   5
#define DE   85
#define CATW 784

typedef __attribute__((ext_vector_type(8))) short bf16x8;
typedef __attribute__((ext_vector_type(4))) float f32x4;
typedef __attribute__((ext_vector_type(2))) __bf16 bf16v2;

#if __has_builtin(__builtin_amdgcn_fdot2_f32_bf16)
#define HAVE_BF16_DOT2 1
#else
#define HAVE_BF16_DOT2 0
#endif

// fast silu: v_exp_f32-based exp + fast divide (rel err ~1e-6, << bf16 ulp)
static __device__ __forceinline__ float silu_f(float v) {
  return __fdividef(v, 1.0f + __expf(-v));
}

static __device__ __forceinline__ unsigned short f2bf(float f) {
  union { float f; unsigned int u; } v; v.f = f;
  unsigned int r = v.u + 0x7fff + ((v.u >> 16) & 1);
  return (unsigned short)(r >> 16);
}
static __device__ __forceinline__ float bf2f(unsigned short h) {
  union { unsigned int u; float f; } v; v.u = ((unsigned int)h) << 16;
  return v.f;
}
static __device__ __forceinline__ bf16v2 u2bf2(unsigned int u) {
  union { unsigned int u; bf16v2 v; } x; x.u = u; return x.v;
}

static __device__ __forceinline__ void gload16(const void* g, void* l) {
  __builtin_amdgcn_global_load_lds((const __attribute__((address_space(1))) unsigned int*)g,
                                   (__attribute__((address_space(3))) unsigned int*)l, 16, 0, 0);
}

// ---------------- weight transpose-converts ----------------
__global__ void convw_plain(const float* __restrict__ W, unsigned short* __restrict__ Wt, int K,
                            long long wt_dstride, int wt_rowoff) {
  __shared__ float T[32][65];
  int k0 = blockIdx.x * 32, n0 = blockIdx.y * 64, d = blockIdx.z;
  int tid = threadIdx.x;
  int nn = tid & 63, kr = tid >> 6;
  const float* Wd = W + (size_t)d * K * 256;
#pragma unroll
  for (int i = 0; i < 8; ++i) {
    int k = kr + i * 4;
    T[k][nn] = Wd[(size_t)(k0 + k) * 256 + n0 + nn];
  }
  __syncthreads();
  unsigned short* Wtd = Wt + (size_t)d * wt_dstride;
  int kk = tid & 31, nr = tid >> 5;
#pragma unroll
  for (int i = 0; i < 8; ++i) {
    int n = nr + i * 8;
    Wtd[(size_t)(wt_rowoff + n0 + n) * K + k0 + kk] = f2bf(T[kk][n]);
  }
}

__global__ void convw_nodeblk(const float* __restrict__ W, unsigned short* __restrict__ Wt,
                              int src_k0, int nt_base) {
  __shared__ float T[32][65];
  int k0 = blockIdx.x * 32, n0 = blockIdx.y * 64, d = blockIdx.z;
  int tid = threadIdx.x;
  int nn = tid & 63, kr = tid >> 6;
  const float* Wd = W + (size_t)d * CATW * 256;
#pragma unroll
  for (int i = 0; i < 8; ++i) {
    int k = kr + i * 4;
    T[k][nn] = Wd[(size_t)(src_k0 + k0 + k) * 256 + n0 + nn];
  }
  __syncthreads();
  unsigned short* Wtd = Wt + (size_t)d * 1024 * 256;
  int kk = tid & 31, nr = tid >> 5;
#pragma unroll
  for (int i = 0; i < 8; ++i) {
    int n = nr + i * 8;
    Wtd[(size_t)(nt_base + n0 + n) * 256 + k0 + kk] = f2bf(T[kk][n]);
  }
}

// wR [D][16][512] bf16: rbf rows (512..527) of phim_W1 (cols 0:256) / psim_W1 (cols 256:512)
__global__ void convw_rbf(const float* __restrict__ phimW1, const float* __restrict__ psimW1,
                          unsigned short* __restrict__ wR) {
  int d = blockIdx.x, j = threadIdx.x;
  int jj = j & 255;
  const float* W = (j < 256) ? phimW1 : psimW1;
  for (int k = 0; k < 16; ++k)
    wR[((size_t)d * 16 + k) * 512 + j] = f2bf(W[(size_t)d * CATW * 256 + (size_t)(512 + k) * 256 + jj]);
}

// wRp [D][8][512] dwords: pair-packed (k=2p low | k=2p+1 high)
__global__ void convw_rbf2(const float* __restrict__ phimW1, const float* __restrict__ psimW1,
                           unsigned int* __restrict__ wRp) {
  int d = blockIdx.x, j = threadIdx.x;
  int jj = j & 255;
  const float* W = (j < 256) ? phimW1 : psimW1;
  const float* base = W + (size_t)d * CATW * 256;
  for (int p = 0; p < 8; ++p) {
    unsigned int lo = f2bf(base[(size_t)(512 + 2*p) * 256 + jj]);
    unsigned int hi = f2bf(base[(size_t)(512 + 2*p + 1) * 256 + jj]);
    wRp[((size_t)d * 8 + p) * 512 + j] = lo | (hi << 16);
  }
}

// ---------------- tables ----------------
__global__ void tables_kernel(const float* __restrict__ atom_W, const float* __restrict__ charge_W,
                              const float* __restrict__ bond_W, const float* __restrict__ fuse_W,
                              const float* __restrict__ fuse_b, const float* __restrict__ lift_W,
                              const float* __restrict__ lift_b,
                              float* __restrict__ tabA, float* __restrict__ tabC,
                              float* __restrict__ tabEf) {
  int r = blockIdx.x, k = threadIdx.x;
  if (r < KA) {
    float s = 0.f;
    for (int d = 0; d < DE; ++d) s += atom_W[r*DE + d] * fuse_W[d*HID + k];
    tabA[r*HID + k] = s + fuse_b[k];
  } else if (r < KA + KC) {
    int rr = r - KA;
    float s = 0.f;
    for (int d = 0; d < DE; ++d) s += charge_W[rr*DE + d] * fuse_W[(DE + d)*HID + k];
    tabC[rr*HID + k] = s;
  } else {
    int rr = r - KA - KC;
    float s = 0.f;
    for (int d = 0; d < DE; ++d) s += bond_W[rr*DE + d] * lift_W[d*HID + k];
    tabEf[rr*HID + k] = s + lift_b[k];
  }
}

// tabE1 [D][5][512] bf16 = tabEf @ W1_eemb (+ b1), phim cols 0:256, psim cols 256:512
__global__ void tabe1_kernel(const float* __restrict__ tabEf,
                             const float* __restrict__ phimW1, const float* __restrict__ phimb1,
                             const float* __restrict__ psimW1, const float* __restrict__ psimb1,
                             unsigned short* __restrict__ tabE1) {
  int r = blockIdx.x, d = blockIdx.y, j = threadIdx.x;
  const float* W = (j < 256) ? phimW1 : psimW1;
  const float* b = (j < 256) ? phimb1 : psimb1;
  int jj = j & 255;
  float s = b[d*256 + jj];
  for (int k = 0; k < 256; ++k)
    s += tabEf[r*256 + k] * W[(size_t)d*CATW*256 + (size_t)(528 + k)*256 + jj];
  tabE1[((size_t)d*5 + r)*512 + j] = f2bf(s);
}

// ---------------- node / edge init (accurate logf: argmax must match reference) ----------------
__global__ void node_init_kernel(const float* __restrict__ a_t, const float* __restrict__ c_t,
                                 const float* __restrict__ g_a, const float* __restrict__ g_c,
                                 const float* __restrict__ x_t, const float* __restrict__ tabA,
                                 const float* __restrict__ tabC, float* __restrict__ h,
                                 unsigned short* __restrict__ hbf, float* __restrict__ x) {
  int n = blockIdx.x;
  __shared__ int s_ia, s_ic;
  if (threadIdx.x == 0) {
    float best = -1e30f; int bi = 0;
    for (int j = 0; j < KA; ++j) {
      float v = logf(fmaxf(a_t[n*KA + j], 1e-12f)) + g_a[n*KA + j];
      if (v > best) { best = v; bi = j; }
    }
    s_ia = bi;
  }
  if (threadIdx.x == 1) {
    float best = -1e30f; int bi = 0;
    for (int j = 0; j < KC; ++j) {
      float v = logf(fmaxf(c_t[n*KC + j], 1e-12f)) + g_c[n*KC + j];
      if (v > best) { best = v; bi = j; }
    }
    s_ic = bi;
  }
  __syncthreads();
  int k = threadIdx.x;
  float v = tabA[s_ia*HID + k] + tabC[s_ic*HID + k];
  h[n*HID + k] = v;
  hbf[n*HID + k] = f2bf(v);
  if (k < 3) x[n*3 + k] = x_t[n*3 + k];
}

__global__ void edge_init_kernel(const float* __restrict__ e_t, const float* __restrict__ g_e,
                                 int* __restrict__ ie) {
  int e = blockIdx.x * blockDim.x + threadIdx.x;
  if (e >= NE) return;
  float best = -1e30f; int bi = 0;
  for (int j = 0; j < KE; ++j) {
    float v = logf(fmaxf(e_t[e*KE + j], 1e-12f)) + g_e[e*KE + j];
    if (v > best) { best = v; bi = j; }
  }
  ie[e] = bi;
}

// ---------------- CSR build ----------------
__global__ void hist_kernel(const int* __restrict__ dst, int* __restrict__ deg) {
  int e = blockIdx.x * 256 + threadIdx.x;
  if (e < NE) atomicAdd(&deg[dst[e]], 1);
}

__global__ void scan_kernel(const int* __restrict__ deg, int* __restrict__ rowstart,
                            int* __restrict__ cursor) {
  __shared__ int tmp[1024];
  int t = threadIdx.x;
  int base = t * 10;
  int local[10];
  int s = 0;
#pragma unroll
  for (int i = 0; i < 10; ++i) { local[i] = deg[base + i]; s += local[i]; }
  tmp[t] = s;
  __syncthreads();
  for (int off = 1; off < 1024; off <<= 1) {
    int v = (t >= off) ? tmp[t - off] : 0;
    __syncthreads();
    tmp[t] += v;
    __syncthreads();
  }
  int run = (t == 0) ? 0 : tmp[t - 1];
#pragma unroll
  for (int i = 0; i < 10; ++i) {
    rowstart[base + i] = run; cursor[base + i] = run; run += local[i];
  }
  if (t == 1023) rowstart[10240] = run;
}

__global__ void fill_kernel(const int* __restrict__ dst, int* __restrict__ cursor,
                            int* __restrict__ eids) {
  int e = blockIdx.x * 256 + threadIdx.x;
  if (e >= NE) return;
  int pos = atomicAdd(&cursor[dst[e]], 1);
  eids[pos] = e;
}

__global__ void sortrows_kernel(const int* __restrict__ rowstart, int* __restrict__ eids) {
  int n = blockIdx.x * 256 + threadIdx.x;
  if (n >= NN) return;
  int s = rowstart[n], e = rowstart[n + 1];
  for (int i = s + 1; i < e; ++i) {
    int v = eids[i]; int j = i - 1;
    while (j >= s && eids[j] > v) { eids[j + 1] = eids[j]; --j; }
    eids[j + 1] = v;
  }
}

// ---------------- graph boundaries (node_graph is sorted) ----------------
__global__ void gbound_kernel(const int* __restrict__ ng, int* __restrict__ gstart) {
  int n = blockIdx.x * 256 + threadIdx.x;
  if (n >= NN) return;
  if (n == 0) {
    for (int g = 0; g <= ng[0]; ++g) gstart[g] = 0;
  } else {
    int a = ng[n-1], b = ng[n];
    for (int g = a + 1; g <= b; ++g) gstart[g] = n;
  }
  if (n == NN - 1) {
    for (int g = ng[n] + 1; g <= NG; ++g) gstart[g] = NN;
  }
}

// ---------------- combine2: one edge per 64 lanes; windowed rbf (8 centers) ----------------
__global__ __launch_bounds__(256) void combine2_kernel(
    const int* __restrict__ srcp, const int* __restrict__ dstp, const int* __restrict__ iep,
    const float* __restrict__ x,
    const unsigned short* __restrict__ P,      // [4][NN][256] bf16
    const unsigned short* __restrict__ tabE1,  // [5][512] bf16, this depth
    const unsigned short* __restrict__ wR,     // [16][512] bf16, this depth (scalar path)
    const unsigned int* __restrict__ wRp,      // [8][512] packed pairs, this depth (dot2 path)
    unsigned short* __restrict__ c1, unsigned short* __restrict__ ps1) {
  const int tid = threadIdx.x;
  const int lane = tid & 63;
  const int e = blockIdx.x * 4 + (tid >> 6);
  const int half = lane >> 5;            // 0: phim, 1: psim
  const int c8 = (lane & 31) * 8;        // col within 256
  const int ds = dstp[e], sr = srcp[e], ib = iep[e];
  float r0 = x[ds*3+0] - x[sr*3+0];
  float r1 = x[ds*3+1] - x[sr*3+1];
  float r2 = x[ds*3+2] - x[sr*3+2];
  float dist = sqrtf(r0*r0 + r1*r1 + r2*r2);
  int klo = (int)(dist * 1.5f) - 3;
  klo = klo < 0 ? 0 : (klo > 8 ? 8 : klo);
  const unsigned short* Pb0 = P + (size_t)(half * 2) * NN * 256;
  const unsigned short* Pb1 = P + (size_t)(half * 2 + 1) * NN * 256;
  bf16x8 pa = *(const bf16x8*)&Pb0[(size_t)ds * 256 + c8];
  bf16x8 pb = *(const bf16x8*)&Pb1[(size_t)sr * 256 + c8];
  bf16x8 te = *(const bf16x8*)&tabE1[(size_t)ib * 512 + lane * 8];
  float zv[8];
#pragma unroll
  for (int j = 0; j < 8; ++j)
    zv[j] = bf2f((unsigned short)pa[j]) + bf2f((unsigned short)pb[j]) + bf2f((unsigned short)te[j]);
#if HAVE_BF16_DOT2
  int plo = klo >> 1;                    // even-aligned 8-center window as 4 pairs
  if (plo > 4) plo = 4;
#pragma unroll
  for (int pp = 0; pp < 4; ++pp) {
    int pr = plo + pp;
    float k0f = (float)(2 * pr);
    float z0 = (dist - 0.66666667f * k0f) * 1.6f;
    float z1 = (dist - 0.66666667f * (k0f + 1.0f)) * 1.6f;
    unsigned int rkp = (unsigned int)f2bf(__expf(-0.5f * z0 * z0)) |
                       ((unsigned int)f2bf(__expf(-0.5f * z1 * z1)) << 16);
    bf16v2 rv = u2bf2(rkp);
    const unsigned int* w8 = wRp + (size_t)pr * 512 + lane * 8;
    uint4 wa = *(const uint4*)w8;
    uint4 wb = *(const uint4*)(w8 + 4);
    zv[0] = __builtin_amdgcn_fdot2_f32_bf16(rv, u2bf2(wa.x), zv[0], false);
    zv[1] = __builtin_amdgcn_fdot2_f32_bf16(rv, u2bf2(wa.y), zv[1], false);
    zv[2] = __builtin_amdgcn_fdot2_f32_bf16(rv, u2bf2(wa.z), zv[2], false);
    zv[3] = __builtin_amdgcn_fdot2_f32_bf16(rv, u2bf2(wa.w), zv[3], false);
    zv[4] = __builtin_amdgcn_fdot2_f32_bf16(rv, u2bf2(wb.x), zv[4], false);
    zv[5] = __builtin_amdgcn_fdot2_f32_bf16(rv, u2bf2(wb.y), zv[5], false);
    zv[6] = __builtin_amdgcn_fdot2_f32_bf16(rv, u2bf2(wb.z), zv[6], false);
    zv[7] = __builtin_amdgcn_fdot2_f32_bf16(rv, u2bf2(wb.w), zv[7], false);
  }
#else
  (void)wRp;
#pragma unroll
  for (int kk = 0; kk < 8; ++kk) {
    int k = klo + kk;
    float z = (dist - 0.66666667f * (float)k) * 1.6f;
    float rk = __expf(-0.5f * z * z);
    bf16x8 wv = *(const bf16x8*)&wR[k * 512 + lane * 8];
#pragma unroll
    for (int j = 0; j < 8; ++j)
      zv[j] += rk * bf2f((unsigned short)wv[j]);
  }
#endif
  unsigned short ov[8];
#pragma unroll
  for (int j = 0; j < 8; ++j) ov[j] = f2bf(silu_f(zv[j]));
  unsigned short* outp = half ? ps1 : c1;
  *(uint4*)&outp[(size_t)e * 256 + c8] = *(uint4*)ov;
}

// ---------------- MFMA bf16 GEMM: BN=256, BK=64; BM=128 (512 thr) or SMALL BM=64 (256 thr) ----------------
// MODE 0: A bf16 [M][256], Kp=256
// MODE 2: A = [A | A2] (each [M][256]), Kp=512
// MODE 3: multi-chunk C: Cw = C + (bn>>8)*M*256 (no silu; bias = zeros)
// MODE 4: merged dual GEMM: rows >= Msplit use weight chunk 1 / bias2 / C2
// GATE:   gout[row] = sum_col silu(acc+b1[col]) * gw2[col]
// LNOUT:  h/hbf = LayerNorm(h + acc + bias) * lng + lnb  (fused upd2+LN)
template<int MODE, bool SILU, bool GATE, bool LNOUT, bool SMALL>
__global__ __launch_bounds__(SMALL ? 256 : 512, 4) void mfma_gemm(
    const unsigned short* __restrict__ A, const unsigned short* __restrict__ A2,
    const unsigned short* __restrict__ Wt,
    const float* __restrict__ bias, const float* __restrict__ bias2,
    unsigned short* __restrict__ C, unsigned short* __restrict__ C2,
    int M, int Kp, int Msplit,
    const float* __restrict__ gw2, float* __restrict__ gout,
    float* __restrict__ hf, unsigned short* __restrict__ hb,
    const float* __restrict__ lng, const float* __restrict__ lnb) {
  constexpr int BM = SMALL ? 64 : 128;
  constexpr int BQ = SMALL ? 8 : 4;            // B-stage issues per wave
  __shared__ unsigned short lds[SMALL ? 20480 : 24576];   // As BM*64 + Bs 256*64
  unsigned short* As = lds;                    // [BM][64] XOR-swizzled
  unsigned short* Bs = lds + BM * 64;          // [256][64] XOR-swizzled
  const int tid = threadIdx.x;
  const int bn = blockIdx.x * 256;
  const int bm = blockIdx.y * BM;
  const int lane = tid & 63;
  const int w = tid >> 6;
  const int wr = SMALL ? 0 : (w >> 2);
  const int wc = SMALL ? w : (w & 3);
  const int subrow = lane >> 3;
  const int kd = 8 * ((lane & 7) ^ subrow);

  const bool half2 = (MODE == 4) && (bm >= Msplit);
  const unsigned short* Wb = Wt + (half2 ? 256 * 256 : 0);

  unsigned int offB[BQ];
#pragma unroll
  for (int q = 0; q < BQ; ++q)
    offB[q] = (unsigned)(bn + w * (BQ * 8) + q * 8 + subrow) * (unsigned)Kp;

  unsigned int offA[2];
#pragma unroll
  for (int q = 0; q < 2; ++q) {
    int m = bm + w * 16 + q * 8 + subrow;
    int mc = (m < M) ? m : (M - 1);
    offA[q] = (unsigned)mc * 256u;
  }

  const int nt = Kp >> 6;
  f32x4 acc[4][4] = {};

  for (int t = 0; t < nt; ++t) {
    const int k0 = t << 6;
#pragma unroll
    for (int q = 0; q < 2; ++q) {
      const unsigned short* gp;
      if (MODE == 2) gp = (k0 < 256) ? (A + offA[q] + k0 + kd) : (A2 + offA[q] + (k0 - 256) + kd);
      else gp = A + offA[q] + k0 + kd;
      gload16(gp, (char*)As + w * 2048 + q * 1024);
    }
#pragma unroll
    for (int q = 0; q < BQ; ++q)
      gload16(Wb + offB[q] + k0 + kd, (char*)Bs + w * (BQ * 1024) + q * 1024);
    __syncthreads();
#pragma unroll
    for (int ks = 0; ks < 2; ++ks) {
      const int kb = (ks * 64 + ((lane >> 4) << 4)) ^ ((lane & 7) << 4);
      bf16x8 bfv[4];
#pragma unroll
      for (int j = 0; j < 4; ++j)
        bfv[j] = *(const bf16x8*)((const char*)Bs + (wc * 64 + j * 16 + (lane & 15)) * 128 + kb);
#pragma unroll
      for (int i = 0; i < 4; ++i) {
        bf16x8 af = *(const bf16x8*)((const char*)As + (wr * 64 + i * 16 + (lane & 15)) * 128 + kb);
#pragma unroll
        for (int j = 0; j < 4; ++j)
          acc[i][j] = __builtin_amdgcn_mfma_f32_16x16x32_bf16(af, bfv[j], acc[i][j], 0, 0, 0);
      }
    }
    __syncthreads();
  }

  if (GATE) {
    float bcol[4], wcol[4];
#pragma unroll
    for (int j = 0; j < 4; ++j) {
      int col = wc * 64 + j * 16 + (lane & 15);
      bcol[j] = bias[col];
      wcol[j] = gw2[col];
    }
    float* part = (float*)lds;   // [4][BM]
#pragma unroll
    for (int i = 0; i < 4; ++i) {
#pragma unroll
      for (int q = 0; q < 4; ++q) {
        float lsum = 0.f;
#pragma unroll
        for (int j = 0; j < 4; ++j)
          lsum += silu_f(acc[i][j][q] + bcol[j]) * wcol[j];
        lsum += __shfl_xor(lsum, 1, 64);
        lsum += __shfl_xor(lsum, 2, 64);
        lsum += __shfl_xor(lsum, 4, 64);
        lsum += __shfl_xor(lsum, 8, 64);
        if ((lane & 15) == 0) {
          int rl = wr * 64 + i * 16 + ((lane >> 4) << 2) + q;
          part[wc * BM + rl] = lsum;
        }
      }
    }
    __syncthreads();
    if (tid < BM)
      gout[bm + tid] = part[tid] + part[BM + tid] + part[2*BM + tid] + part[3*BM + tid];
    return;
  }

  if (LNOUT) {
    float bcol[4], lgc[4], lbc[4];
#pragma unroll
    for (int j = 0; j < 4; ++j) {
      int col = wc * 64 + j * 16 + (lane & 15);
      bcol[j] = bias[col]; lgc[j] = lng[col]; lbc[j] = lnb[col];
    }
    float* part = (float*)lds;       // [4][BM]
    float* stat = part + 4 * BM;     // mu[BM], rstd[BM]
#pragma unroll
    for (int i = 0; i < 4; ++i)
#pragma unroll
      for (int q = 0; q < 4; ++q) {
        int rl = wr * 64 + i * 16 + ((lane >> 4) << 2) + q;
        int grow = bm + rl;
        float s = 0.f;
#pragma unroll
        for (int j = 0; j < 4; ++j) {
          int col = wc * 64 + j * 16 + (lane & 15);
          float hv = (grow < M) ? hf[(size_t)grow * 256 + col] : 0.f;
          float zz = acc[i][j][q] + bcol[j] + hv;
          acc[i][j][q] = zz;
          s += zz;
        }
        s += __shfl_xor(s, 1, 64); s += __shfl_xor(s, 2, 64);
        s += __shfl_xor(s, 4, 64); s += __shfl_xor(s, 8, 64);
        if ((lane & 15) == 0) part[wc * BM + rl] = s;
      }
    __syncthreads();
    if (tid < BM)
      stat[tid] = (part[tid] + part[BM + tid] + part[2*BM + tid] + part[3*BM + tid]) * (1.f / 256.f);
    __syncthreads();
#pragma unroll
    for (int i = 0; i < 4; ++i)
#pragma unroll
      for (int q = 0; q < 4; ++q) {
        int rl = wr * 64 + i * 16 + ((lane >> 4) << 2) + q;
        float mu = stat[rl];
        float s2 = 0.f;
#pragma unroll
        for (int j = 0; j < 4; ++j) { float d_ = acc[i][j][q] - mu; s2 += d_ * d_; }
        s2 += __shfl_xor(s2, 1, 64); s2 += __shfl_xor(s2, 2, 64);
        s2 += __shfl_xor(s2, 4, 64); s2 += __shfl_xor(s2, 8, 64);
        if ((lane & 15) == 0) part[wc * BM + rl] = s2;
      }
    __syncthreads();
    if (tid < BM)
      stat[BM + tid] = 1.f / sqrtf((part[tid] + part[BM + tid] + part[2*BM + tid] + part[3*BM + tid]) * (1.f / 256.f) + 1e-5f);
    __syncthreads();
#pragma unroll
    for (int i = 0; i < 4; ++i)
#pragma unroll
      for (int q = 0; q < 4; ++q) {
        int rl = wr * 64 + i * 16 + ((lane >> 4) << 2) + q;
        int grow = bm + rl;
        if (grow < M) {
          float mu = stat[rl], rs = stat[BM + rl];
#pragma unroll
          for (int j = 0; j < 4; ++j) {
            int col = wc * 64 + j * 16 + (lane & 15);
            float o = (acc[i][j][q] - mu) * rs * lgc[j] + lbc[j];
            hf[(size_t)grow * 256 + col] = o;
            hb[(size_t)grow * 256 + col] = f2bf(o);
          }
        }
      }
    return;
  }

  // normal epilogue: coalesced C-store via LDS transpose
  const float* biasw = bias;
  unsigned short* Cw = C;
  int rowoff = 0;
  if (MODE == 3) Cw = C + (size_t)(bn >> 8) * (size_t)M * 256;
  if (MODE == 4 && half2) { biasw = bias2; Cw = C2; rowoff = Msplit; }

  float bcol[4];
#pragma unroll
  for (int j = 0; j < 4; ++j) bcol[j] = biasw[wc * 64 + j * 16 + (lane & 15)];

  unsigned short* T = lds;   // [BM][136]
#pragma unroll
  for (int hh = 0; hh < 2; ++hh) {
    if ((wc >> 1) == hh) {
#pragma unroll
      for (int i = 0; i < 4; ++i)
#pragma unroll
        for (int j = 0; j < 4; ++j)
#pragma unroll
          for (int q = 0; q < 4; ++q) {
            int rl = wr * 64 + i * 16 + ((lane >> 4) << 2) + q;
            int cl = (wc & 1) * 64 + j * 16 + (lane & 15);
            float v = acc[i][j][q] + bcol[j];
            if (SILU) v = silu_f(v);
            T[rl * 136 + cl] = f2bf(v);
          }
    }
    __syncthreads();
#pragma unroll
    for (int it = 0; it < 4; ++it) {
      int row = it * (BM / 4) + (tid >> 4);
      int grow = bm + row;
      if (grow < M) {
        uint4 v = *(const uint4*)&T[row * 136 + (tid & 15) * 8];
        *(uint4*)&Cw[(size_t)(grow - rowoff) * 256 + hh * 128 + (tid & 15) * 8] = v;
      }
    }
    __syncthreads();
  }
}

// ---------------- CSR gather: pm_sum (bf16 out) + dx; x double-buffered ----------------
__global__ void gather_pm_dx(const unsigned short* __restrict__ pm, const float* __restrict__ gate,
                             const float* __restrict__ xcur, const int* __restrict__ srcp,
                             const int* __restrict__ rowstart, const int* __restrict__ eids,
                             const float* __restrict__ gb2,
                             unsigned short* __restrict__ pmbf, float* __restrict__ xnxt) {
  int n = blockIdx.x, k = threadIdx.x;
  int s = rowstart[n], e1 = rowstart[n + 1];
  float acc = 0.f, dx = 0.f;
  float b2 = gb2[0];
  float xn = (k < 3) ? xcur[n*3 + k] : 0.f;
  for (int t = s; t < e1; ++t) {
    int e = eids[t];
    acc += bf2f(pm[(size_t)e*HID + k]);
    if (k < 3) dx += (xn - xcur[srcp[e]*3 + k]) * (gate[e] + b2);
  }
  pmbf[(size_t)n*HID + k] = f2bf(acc);
  if (k < 3) xnxt[n*3 + k] = xn + dx;
}

// ---------------- fused readout: per-graph column sums + head dot + sigmoid ----------------
__global__ void readout_kernel(const float* __restrict__ h, const int* __restrict__ gstart,
                               const float* __restrict__ head_W, const float* __restrict__ head_b,
                               float* __restrict__ out) {
  int g = blockIdx.x, k = threadIdx.x;
  int s = gstart[g], e = gstart[g + 1];
  float acc = 0.f;
  for (int n = s; n < e; ++n) acc += h[(size_t)n * HID + k];
  float v = acc * head_W[k];
  __shared__ float red[4];
  int lane = k & 63, wv = k >> 6;
#pragma unroll
  for (int off = 32; off > 0; off >>= 1) v += __shfl_down(v, off, 64);
  if (lane == 0) red[wv] = v;
  __syncthreads();
  if (k == 0) {
    float dot = red[0] + red[1] + red[2] + red[3];
    float c = fmaxf((float)(e - s), 1.0f);
    float val = (dot / c + head_b[0]) * 0.5f;
    out[g] = __fdividef(1.0f, 1.0f + __expf(-val));
  }
}

extern "C" void kernel_launch(void* const* d_in, const int* in_sizes, int n_in,
                              void* d_out, int out_size, void* d_ws, size_t ws_size,
                              hipStream_t stream) {
  (void)in_sizes; (void)n_in; (void)out_size; (void)ws_size;
  const float* a_t      = (const float*)d_in[0];
  const float* c_t      = (const float*)d_in[1];
  const float* e_t      = (const float*)d_in[2];
  const float* x_t      = (const float*)d_in[3];
  const float* g_a      = (const float*)d_in[4];
  const float* g_c      = (const float*)d_in[5];
  const float* g_e      = (const float*)d_in[6];
  const float* atom_W   = (const float*)d_in[7];
  const float* charge_W = (const float*)d_in[8];
  const float* bond_W   = (const float*)d_in[9];
  const float* fuse_W   = (const float*)d_in[10];
  const float* fuse_b   = (const float*)d_in[11];
  const float* lift_W   = (const float*)d_in[12];
  const float* lift_b   = (const float*)d_in[13];
  const float* phim_W1  = (const float*)d_in[14];
  const float* phim_b1  = (const float*)d_in[15];
  const float* phim_W2  = (const float*)d_in[16];
  const float* phim_b2  = (const float*)d_in[17];
  const float* phix_W1  = (const float*)d_in[18];
  const float* phix_b1  = (const float*)d_in[19];
  const float* phix_W2  = (const float*)d_in[20];
  const float* phix_b2  = (const float*)d_in[21];
  const float* psim_W1  = (const float*)d_in[22];
  const float* psim_b1  = (const float*)d_in[23];
  const float* psim_W2  = (const float*)d_in[24];
  const float* psim_b2  = (const float*)d_in[25];
  const float* updh_W1  = (const float*)d_in[26];
  const float* updh_b1  = (const float*)d_in[27];
  const float* updh_W2  = (const float*)d_in[28];
  const float* updh_b2  = (const float*)d_in[29];
  const float* ln_g     = (const float*)d_in[30];
  const float* ln_b     = (const float*)d_in[31];
  const float* head_W   = (const float*)d_in[32];
  const float* head_b   = (const float*)d_in[33];
  const int*   src      = (const int*)d_in[34];
  const int*   dst      = (const int*)d_in[35];
  const int*   ngraph   = (const int*)d_in[36];
  float* out = (float*)d_out;

  char* p = (char*)d_ws;
  auto carve = [&](size_t bytes) -> char* {
    char* r = p; p += (bytes + 255) & ~(size_t)255; return r;
  };
  float*          h     = (float*)carve((size_t)NN*HID*4);
  unsigned short* hbf   = (unsigned short*)carve((size_t)NN*HID*2);
  float*          xposA = (float*)carve((size_t)NN*3*4);
  float*          xposB = (float*)carve((size_t)NN*3*4);
  int*            ie    = (int*)carve((size_t)NE*4);
  float*          tabA  = (float*)carve((size_t)KA*HID*4);
  float*          tabC  = (float*)carve((size_t)KC*HID*4);
  float*          tabEf = (float*)carve((size_t)KE*HID*4);
  float*          gate  = (float*)carve((size_t)NE*4);
  unsigned short* pmbf  = (unsigned short*)carve((size_t)NN*HID*2);
  float*          zbias = (float*)carve(256*4);
  unsigned short* buf01 = (unsigned short*)carve((size_t)2*NE*HID*2);  // c1 | ps1 contiguous
  unsigned short* bufM  = (unsigned short*)carve((size_t)NE*HID*2);    // m
  unsigned short* bufPM = (unsigned short*)carve((size_t)NE*HID*2);    // pm
  unsigned short* P     = (unsigned short*)carve((size_t)4*NN*HID*2);
  // CSR + graph bounds
  int* deg      = (int*)carve(10240*4);
  int* cursor   = (int*)carve(10240*4);
  int* rowstart = (int*)carve(10241*4);
  int* eids     = (int*)carve((size_t)NE*4);
  int* gstart   = (int*)carve((NG+1)*4);
  // transposed bf16 weights
  unsigned short* wNode  = (unsigned short*)carve((size_t)NDEP*1024*256*2);
  unsigned short* wMPM   = (unsigned short*)carve((size_t)NDEP*512*256*2);   // [phimW2 | psimW2]
  unsigned short* wPhix1 = (unsigned short*)carve((size_t)NDEP*256*256*2);
  unsigned short* wUpd1  = (unsigned short*)carve((size_t)NDEP*256*512*2);
  unsigned short* wUpd2  = (unsigned short*)carve((size_t)NDEP*256*256*2);
  unsigned short* wRbf   = (unsigned short*)carve((size_t)NDEP*16*512*2);
  unsigned int*   wRbfP  = (unsigned int*)carve((size_t)NDEP*8*512*4);
  unsigned short* tabE1  = (unsigned short*)carve((size_t)NDEP*5*512*2);

  unsigned short* c1buf = buf01;
  unsigned short* psbuf = buf01 + (size_t)NE*HID;

  // ---- weight conversion ----
  convw_nodeblk<<<dim3(8,4,NDEP), 256, 0, stream>>>(phim_W1, wNode, 0,   0);
  convw_nodeblk<<<dim3(8,4,NDEP), 256, 0, stream>>>(phim_W1, wNode, 256, 256);
  convw_nodeblk<<<dim3(8,4,NDEP), 256, 0, stream>>>(psim_W1, wNode, 0,   512);
  convw_nodeblk<<<dim3(8,4,NDEP), 256, 0, stream>>>(psim_W1, wNode, 256, 768);
  convw_plain<<<dim3(8,4,NDEP), 256, 0, stream>>>(phim_W2, wMPM, 256, 512*256, 0);
  convw_plain<<<dim3(8,4,NDEP), 256, 0, stream>>>(psim_W2, wMPM, 256, 512*256, 256);
  convw_plain<<<dim3(8,4,NDEP), 256, 0, stream>>>(phix_W1, wPhix1, 256, 256*256, 0);
  convw_plain<<<dim3(8,4,NDEP), 256, 0, stream>>>(updh_W2, wUpd2, 256, 256*256, 0);
  convw_plain<<<dim3(16,4,NDEP), 256, 0, stream>>>(updh_W1, wUpd1, 512, 256*512, 0);
  convw_rbf<<<NDEP, 512, 0, stream>>>(phim_W1, psim_W1, wRbf);
  convw_rbf2<<<NDEP, 512, 0, stream>>>(phim_W1, psim_W1, wRbfP);
  hipMemsetAsync(zbias, 0, 256*4, stream);

  tables_kernel<<<KA + KC + KE, 256, 0, stream>>>(atom_W, charge_W, bond_W, fuse_W, fuse_b,
                                                  lift_W, lift_b, tabA, tabC, tabEf);
  tabe1_kernel<<<dim3(5, NDEP), 512, 0, stream>>>(tabEf, phim_W1, phim_b1, psim_W1, psim_b1, tabE1);
  node_init_kernel<<<NN, 256, 0, stream>>>(a_t, c_t, g_a, g_c, x_t, tabA, tabC, h, hbf, xposA);
  edge_init_kernel<<<(NE + 255)/256, 256, 0, stream>>>(e_t, g_e, ie);

  // ---- CSR build + graph bounds ----
  hipMemsetAsync(deg, 0, 10240*4, stream);
  hist_kernel<<<(NE + 255)/256, 256, 0, stream>>>(dst, deg);
  scan_kernel<<<1, 1024, 0, stream>>>(deg, rowstart, cursor);
  fill_kernel<<<(NE + 255)/256, 256, 0, stream>>>(dst, cursor, eids);
  sortrows_kernel<<<(NN + 255)/256, 256, 0, stream>>>(rowstart, eids);
  gbound_kernel<<<(NN + 255)/256, 256, 0, stream>>>(ngraph, gstart);

  dim3 gridP(4, (NN + 63)/64);     // SMALL: BM=64
  dim3 gridE(1, NE/128);
  dim3 gridE2(1, 2*NE/128);
  dim3 gridNS(1, (NN + 63)/64);    // SMALL node GEMMs

  float* xcur = xposA;
  float* xnxt = xposB;

  for (int d = 0; d < NDEP; ++d) {
    const float* pb2m = phim_b2 + (size_t)d*HID;
    const float* pxb1 = phix_b1 + (size_t)d*HID;
    const float* pxW2 = phix_W2 + (size_t)d*HID;
    const float* pxb2 = phix_b2 + (size_t)d;
    const float* psb2 = psim_b2 + (size_t)d*HID;
    const float* pub1 = updh_b1 + (size_t)d*HID;
    const float* pub2 = updh_b2 + (size_t)d*HID;

    // P = h @ [W1_phim_dst | W1_phim_src | W1_psim_dst | W1_psim_src]  (SMALL tiles)
    mfma_gemm<3, false, false, false, true><<<gridP, 256, 0, stream>>>(
        hbf, nullptr, wNode + (size_t)d*1024*256, zbias, nullptr, P, nullptr, NN, 256, 0,
        nullptr, nullptr, nullptr, nullptr, nullptr, nullptr);
    // c1, ps1 = silu(P[dst]+P[src]+tabE1[ie]+windowed rbf@Wrbf)
    combine2_kernel<<<NE/4, 256, 0, stream>>>(
        src, dst, ie, xcur, P, tabE1 + (size_t)d*5*512, wRbf + (size_t)d*16*512,
        wRbfP + (size_t)d*8*512, c1buf, psbuf);
    // merged: m = silu(c1 @ phim_W2 + b2) ; pm = silu(ps1 @ psim_W2 + b2)
    mfma_gemm<4, true, false, false, false><<<gridE2, 512, 0, stream>>>(
        buf01, nullptr, wMPM + (size_t)d*512*256, pb2m, psb2, bufM, bufPM, 2*NE, 256, NE,
        nullptr, nullptr, nullptr, nullptr, nullptr, nullptr);
    // gate = silu(m @ phix_W1 + b1) @ phix_W2
    mfma_gemm<0, false, true, false, false><<<gridE, 512, 0, stream>>>(
        bufM, nullptr, wPhix1 + (size_t)d*256*256, pxb1, nullptr, nullptr, nullptr, NE, 256, 0,
        pxW2, gate, nullptr, nullptr, nullptr, nullptr);
    // pm_sum -> pmbf ; xnxt = xcur + dx (race-free double-buffer)
    gather_pm_dx<<<NN, 256, 0, stream>>>(bufPM, gate, xcur, src, rowstart, eids, pxb2, pmbf, xnxt);
    // u1 = silu([h, pm] @ updh_W1 + b1)  (SMALL tiles)
    mfma_gemm<2, true, false, false, true><<<gridNS, 256, 0, stream>>>(
        hbf, pmbf, wUpd1 + (size_t)d*256*512, pub1, nullptr, bufM, nullptr, NN, 512, 0,
        nullptr, nullptr, nullptr, nullptr, nullptr, nullptr);
    // h = LN(h + u1 @ updh_W2 + b2)  (fused, SMALL tiles)
    mfma_gemm<0, false, false, true, true><<<gridNS, 256, 0, stream>>>(
        bufM, nullptr, wUpd2 + (size_t)d*256*256, pub2, nullptr, nullptr, nullptr, NN, 256, 0,
        nullptr, nullptr, h, hbf, ln_g + (size_t)d*HID, ln_b + (size_t)d*HID);

    float* tmp = xcur; xcur = xnxt; xnxt = tmp;
  }

  // fused readout (no atomics; node_graph sorted -> contiguous ranges)
  readout_kernel<<<NG, 256, 0, stream>>>(h, gstart, head_W, head_b, out);
}

// Round 17
// 1373.608 us; speedup vs baseline: 2.6955x; 1.1324x over previous
//
#include <hip/hip_runtime.h>
#include <math.h>

#define NN   10000
#define NE   80000
#define NG   64
#define HID  256
#define RBFK 16
#define NDEP 6
#define KA   16
#define KC   6
#define KE   5
#define DE   85
#define CATW 784

typedef __attribute__((ext_vector_type(8))) short bf16x8;
typedef __attribute__((ext_vector_type(4))) float f32x4;
typedef __attribute__((ext_vector_type(2))) __bf16 bf16v2;

#if __has_builtin(__builtin_amdgcn_fdot2_f32_bf16)
#define HAVE_BF16_DOT2 1
#else
#define HAVE_BF16_DOT2 0
#endif

// fast silu: v_exp_f32-based exp + fast divide (rel err ~1e-6, << bf16 ulp)
static __device__ __forceinline__ float silu_f(float v) {
  return __fdividef(v, 1.0f + __expf(-v));
}

static __device__ __forceinline__ unsigned short f2bf(float f) {
  union { float f; unsigned int u; } v; v.f = f;
  unsigned int r = v.u + 0x7fff + ((v.u >> 16) & 1);
  return (unsigned short)(r >> 16);
}
static __device__ __forceinline__ float bf2f(unsigned short h) {
  union { unsigned int u; float f; } v; v.u = ((unsigned int)h) << 16;
  return v.f;
}
static __device__ __forceinline__ bf16v2 u2bf2(unsigned int u) {
  union { unsigned int u; bf16v2 v; } x; x.u = u; return x.v;
}

static __device__ __forceinline__ void gload16(const void* g, void* l) {
  __builtin_amdgcn_global_load_lds((const __attribute__((address_space(1))) unsigned int*)g,
                                   (__attribute__((address_space(3))) unsigned int*)l, 16, 0, 0);
}

// ---------------- weight transpose-converts ----------------
__global__ void convw_plain(const float* __restrict__ W, unsigned short* __restrict__ Wt, int K,
                            long long wt_dstride, int wt_rowoff) {
  __shared__ float T[32][65];
  int k0 = blockIdx.x * 32, n0 = blockIdx.y * 64, d = blockIdx.z;
  int tid = threadIdx.x;
  int nn = tid & 63, kr = tid >> 6;
  const float* Wd = W + (size_t)d * K * 256;
#pragma unroll
  for (int i = 0; i < 8; ++i) {
    int k = kr + i * 4;
    T[k][nn] = Wd[(size_t)(k0 + k) * 256 + n0 + nn];
  }
  __syncthreads();
  unsigned short* Wtd = Wt + (size_t)d * wt_dstride;
  int kk = tid & 31, nr = tid >> 5;
#pragma unroll
  for (int i = 0; i < 8; ++i) {
    int n = nr + i * 8;
    Wtd[(size_t)(wt_rowoff + n0 + n) * K + k0 + kk] = f2bf(T[kk][n]);
  }
}

__global__ void convw_nodeblk(const float* __restrict__ W, unsigned short* __restrict__ Wt,
                              int src_k0, int nt_base) {
  __shared__ float T[32][65];
  int k0 = blockIdx.x * 32, n0 = blockIdx.y * 64, d = blockIdx.z;
  int tid = threadIdx.x;
  int nn = tid & 63, kr = tid >> 6;
  const float* Wd = W + (size_t)d * CATW * 256;
#pragma unroll
  for (int i = 0; i < 8; ++i) {
    int k = kr + i * 4;
    T[k][nn] = Wd[(size_t)(src_k0 + k0 + k) * 256 + n0 + nn];
  }
  __syncthreads();
  unsigned short* Wtd = Wt + (size_t)d * 1024 * 256;
  int kk = tid & 31, nr = tid >> 5;
#pragma unroll
  for (int i = 0; i < 8; ++i) {
    int n = nr + i * 8;
    Wtd[(size_t)(nt_base + n0 + n) * 256 + k0 + kk] = f2bf(T[kk][n]);
  }
}

// wR [D][16][512] bf16
__global__ void convw_rbf(const float* __restrict__ phimW1, const float* __restrict__ psimW1,
                          unsigned short* __restrict__ wR) {
  int d = blockIdx.x, j = threadIdx.x;
  int jj = j & 255;
  const float* W = (j < 256) ? phimW1 : psimW1;
  for (int k = 0; k < 16; ++k)
    wR[((size_t)d * 16 + k) * 512 + j] = f2bf(W[(size_t)d * CATW * 256 + (size_t)(512 + k) * 256 + jj]);
}

// wRp [D][8][512] dwords: pair-packed (k=2p low | k=2p+1 high)
__global__ void convw_rbf2(const float* __restrict__ phimW1, const float* __restrict__ psimW1,
                           unsigned int* __restrict__ wRp) {
  int d = blockIdx.x, j = threadIdx.x;
  int jj = j & 255;
  const float* W = (j < 256) ? phimW1 : psimW1;
  const float* base = W + (size_t)d * CATW * 256;
  for (int p = 0; p < 8; ++p) {
    unsigned int lo = f2bf(base[(size_t)(512 + 2*p) * 256 + jj]);
    unsigned int hi = f2bf(base[(size_t)(512 + 2*p + 1) * 256 + jj]);
    wRp[((size_t)d * 8 + p) * 512 + j] = lo | (hi << 16);
  }
}

// ---------------- tables ----------------
__global__ void tables_kernel(const float* __restrict__ atom_W, const float* __restrict__ charge_W,
                              const float* __restrict__ bond_W, const float* __restrict__ fuse_W,
                              const float* __restrict__ fuse_b, const float* __restrict__ lift_W,
                              const float* __restrict__ lift_b,
                              float* __restrict__ tabA, float* __restrict__ tabC,
                              float* __restrict__ tabEf) {
  int r = blockIdx.x, k = threadIdx.x;
  if (r < KA) {
    float s = 0.f;
    for (int d = 0; d < DE; ++d) s += atom_W[r*DE + d] * fuse_W[d*HID + k];
    tabA[r*HID + k] = s + fuse_b[k];
  } else if (r < KA + KC) {
    int rr = r - KA;
    float s = 0.f;
    for (int d = 0; d < DE; ++d) s += charge_W[rr*DE + d] * fuse_W[(DE + d)*HID + k];
    tabC[rr*HID + k] = s;
  } else {
    int rr = r - KA - KC;
    float s = 0.f;
    for (int d = 0; d < DE; ++d) s += bond_W[rr*DE + d] * lift_W[d*HID + k];
    tabEf[rr*HID + k] = s + lift_b[k];
  }
}

// tabE1 [D][5][512] bf16
__global__ void tabe1_kernel(const float* __restrict__ tabEf,
                             const float* __restrict__ phimW1, const float* __restrict__ phimb1,
                             const float* __restrict__ psimW1, const float* __restrict__ psimb1,
                             unsigned short* __restrict__ tabE1) {
  int r = blockIdx.x, d = blockIdx.y, j = threadIdx.x;
  const float* W = (j < 256) ? phimW1 : psimW1;
  const float* b = (j < 256) ? phimb1 : psimb1;
  int jj = j & 255;
  float s = b[d*256 + jj];
  for (int k = 0; k < 256; ++k)
    s += tabEf[r*256 + k] * W[(size_t)d*CATW*256 + (size_t)(528 + k)*256 + jj];
  tabE1[((size_t)d*5 + r)*512 + j] = f2bf(s);
}

// ---------------- node / edge init (accurate logf: argmax must match reference) ----------------
__global__ void node_init_kernel(const float* __restrict__ a_t, const float* __restrict__ c_t,
                                 const float* __restrict__ g_a, const float* __restrict__ g_c,
                                 const float* __restrict__ x_t, const float* __restrict__ tabA,
                                 const float* __restrict__ tabC, float* __restrict__ h,
                                 unsigned short* __restrict__ hbf, float* __restrict__ x) {
  int n = blockIdx.x;
  __shared__ int s_ia, s_ic;
  if (threadIdx.x == 0) {
    float best = -1e30f; int bi = 0;
    for (int j = 0; j < KA; ++j) {
      float v = logf(fmaxf(a_t[n*KA + j], 1e-12f)) + g_a[n*KA + j];
      if (v > best) { best = v; bi = j; }
    }
    s_ia = bi;
  }
  if (threadIdx.x == 1) {
    float best = -1e30f; int bi = 0;
    for (int j = 0; j < KC; ++j) {
      float v = logf(fmaxf(c_t[n*KC + j], 1e-12f)) + g_c[n*KC + j];
      if (v > best) { best = v; bi = j; }
    }
    s_ic = bi;
  }
  __syncthreads();
  int k = threadIdx.x;
  float v = tabA[s_ia*HID + k] + tabC[s_ic*HID + k];
  h[n*HID + k] = v;
  hbf[n*HID + k] = f2bf(v);
  if (k < 3) x[n*3 + k] = x_t[n*3 + k];
}

__global__ void edge_init_kernel(const float* __restrict__ e_t, const float* __restrict__ g_e,
                                 int* __restrict__ ie) {
  int e = blockIdx.x * blockDim.x + threadIdx.x;
  if (e >= NE) return;
  float best = -1e30f; int bi = 0;
  for (int j = 0; j < KE; ++j) {
    float v = logf(fmaxf(e_t[e*KE + j], 1e-12f)) + g_e[e*KE + j];
    if (v > best) { best = v; bi = j; }
  }
  ie[e] = bi;
}

// ---------------- CSR build ----------------
__global__ void hist_kernel(const int* __restrict__ dst, int* __restrict__ deg) {
  int e = blockIdx.x * 256 + threadIdx.x;
  if (e < NE) atomicAdd(&deg[dst[e]], 1);
}

__global__ void scan_kernel(const int* __restrict__ deg, int* __restrict__ rowstart,
                            int* __restrict__ cursor) {
  __shared__ int tmp[1024];
  int t = threadIdx.x;
  int base = t * 10;
  int local[10];
  int s = 0;
#pragma unroll
  for (int i = 0; i < 10; ++i) { local[i] = deg[base + i]; s += local[i]; }
  tmp[t] = s;
  __syncthreads();
  for (int off = 1; off < 1024; off <<= 1) {
    int v = (t >= off) ? tmp[t - off] : 0;
    __syncthreads();
    tmp[t] += v;
    __syncthreads();
  }
  int run = (t == 0) ? 0 : tmp[t - 1];
#pragma unroll
  for (int i = 0; i < 10; ++i) {
    rowstart[base + i] = run; cursor[base + i] = run; run += local[i];
  }
  if (t == 1023) rowstart[10240] = run;
}

__global__ void fill_kernel(const int* __restrict__ dst, int* __restrict__ cursor,
                            int* __restrict__ eids) {
  int e = blockIdx.x * 256 + threadIdx.x;
  if (e >= NE) return;
  int pos = atomicAdd(&cursor[dst[e]], 1);
  eids[pos] = e;
}

__global__ void sortrows_kernel(const int* __restrict__ rowstart, int* __restrict__ eids) {
  int n = blockIdx.x * 256 + threadIdx.x;
  if (n >= NN) return;
  int s = rowstart[n], e = rowstart[n + 1];
  for (int i = s + 1; i < e; ++i) {
    int v = eids[i]; int j = i - 1;
    while (j >= s && eids[j] > v) { eids[j + 1] = eids[j]; --j; }
    eids[j + 1] = v;
  }
}

// ---------------- graph boundaries ----------------
__global__ void gbound_kernel(const int* __restrict__ ng, int* __restrict__ gstart) {
  int n = blockIdx.x * 256 + threadIdx.x;
  if (n >= NN) return;
  if (n == 0) {
    for (int g = 0; g <= ng[0]; ++g) gstart[g] = 0;
  } else {
    int a = ng[n-1], b = ng[n];
    for (int g = a + 1; g <= b; ++g) gstart[g] = n;
  }
  if (n == NN - 1) {
    for (int g = ng[n] + 1; g <= NG; ++g) gstart[g] = NN;
  }
}

// ---------------- combine2 ----------------
__global__ __launch_bounds__(256) void combine2_kernel(
    const int* __restrict__ srcp, const int* __restrict__ dstp, const int* __restrict__ iep,
    const float* __restrict__ x,
    const unsigned short* __restrict__ P,
    const unsigned short* __restrict__ tabE1,
    const unsigned short* __restrict__ wR,
    const unsigned int* __restrict__ wRp,
    unsigned short* __restrict__ c1, unsigned short* __restrict__ ps1) {
  const int tid = threadIdx.x;
  const int lane = tid & 63;
  const int e = blockIdx.x * 4 + (tid >> 6);
  const int half = lane >> 5;
  const int c8 = (lane & 31) * 8;
  const int ds = dstp[e], sr = srcp[e], ib = iep[e];
  float r0 = x[ds*3+0] - x[sr*3+0];
  float r1 = x[ds*3+1] - x[sr*3+1];
  float r2 = x[ds*3+2] - x[sr*3+2];
  float dist = sqrtf(r0*r0 + r1*r1 + r2*r2);
  int klo = (int)(dist * 1.5f) - 3;
  klo = klo < 0 ? 0 : (klo > 8 ? 8 : klo);
  const unsigned short* Pb0 = P + (size_t)(half * 2) * NN * 256;
  const unsigned short* Pb1 = P + (size_t)(half * 2 + 1) * NN * 256;
  bf16x8 pa = *(const bf16x8*)&Pb0[(size_t)ds * 256 + c8];
  bf16x8 pb = *(const bf16x8*)&Pb1[(size_t)sr * 256 + c8];
  bf16x8 te = *(const bf16x8*)&tabE1[(size_t)ib * 512 + lane * 8];
  float zv[8];
#pragma unroll
  for (int j = 0; j < 8; ++j)
    zv[j] = bf2f((unsigned short)pa[j]) + bf2f((unsigned short)pb[j]) + bf2f((unsigned short)te[j]);
#if HAVE_BF16_DOT2
  int plo = klo >> 1;
  if (plo > 4) plo = 4;
#pragma unroll
  for (int pp = 0; pp < 4; ++pp) {
    int pr = plo + pp;
    float k0f = (float)(2 * pr);
    float z0 = (dist - 0.66666667f * k0f) * 1.6f;
    float z1 = (dist - 0.66666667f * (k0f + 1.0f)) * 1.6f;
    unsigned int rkp = (unsigned int)f2bf(__expf(-0.5f * z0 * z0)) |
                       ((unsigned int)f2bf(__expf(-0.5f * z1 * z1)) << 16);
    bf16v2 rv = u2bf2(rkp);
    const unsigned int* w8 = wRp + (size_t)pr * 512 + lane * 8;
    uint4 wa = *(const uint4*)w8;
    uint4 wb = *(const uint4*)(w8 + 4);
    zv[0] = __builtin_amdgcn_fdot2_f32_bf16(rv, u2bf2(wa.x), zv[0], false);
    zv[1] = __builtin_amdgcn_fdot2_f32_bf16(rv, u2bf2(wa.y), zv[1], false);
    zv[2] = __builtin_amdgcn_fdot2_f32_bf16(rv, u2bf2(wa.z), zv[2], false);
    zv[3] = __builtin_amdgcn_fdot2_f32_bf16(rv, u2bf2(wa.w), zv[3], false);
    zv[4] = __builtin_amdgcn_fdot2_f32_bf16(rv, u2bf2(wb.x), zv[4], false);
    zv[5] = __builtin_amdgcn_fdot2_f32_bf16(rv, u2bf2(wb.y), zv[5], false);
    zv[6] = __builtin_amdgcn_fdot2_f32_bf16(rv, u2bf2(wb.z), zv[6], false);
    zv[7] = __builtin_amdgcn_fdot2_f32_bf16(rv, u2bf2(wb.w), zv[7], false);
  }
#else
  (void)wRp;
#pragma unroll
  for (int kk = 0; kk < 8; ++kk) {
    int k = klo + kk;
    float z = (dist - 0.66666667f * (float)k) * 1.6f;
    float rk = __expf(-0.5f * z * z);
    bf16x8 wv = *(const bf16x8*)&wR[k * 512 + lane * 8];
#pragma unroll
    for (int j = 0; j < 8; ++j)
      zv[j] += rk * bf2f((unsigned short)wv[j]);
  }
#endif
  unsigned short ov[8];
#pragma unroll
  for (int j = 0; j < 8; ++j) ov[j] = f2bf(silu_f(zv[j]));
  unsigned short* outp = half ? ps1 : c1;
  *(uint4*)&outp[(size_t)e * 256 + c8] = *(uint4*)ov;
}

// ---------------- MFMA bf16 GEMM (unchanged proven structure) ----------------
template<int MODE, bool SILU, bool GATE, bool LNOUT, bool SMALL>
__global__ __launch_bounds__(SMALL ? 256 : 512, 4) void mfma_gemm(
    const unsigned short* __restrict__ A, const unsigned short* __restrict__ A2,
    const unsigned short* __restrict__ Wt,
    const float* __restrict__ bias, const float* __restrict__ bias2,
    unsigned short* __restrict__ C, unsigned short* __restrict__ C2,
    int M, int Kp, int Msplit,
    const float* __restrict__ gw2, float* __restrict__ gout,
    float* __restrict__ hf, unsigned short* __restrict__ hb,
    const float* __restrict__ lng, const float* __restrict__ lnb) {
  constexpr int BM = SMALL ? 64 : 128;
  constexpr int BQ = SMALL ? 8 : 4;
  __shared__ unsigned short lds[SMALL ? 20480 : 24576];
  unsigned short* As = lds;
  unsigned short* Bs = lds + BM * 64;
  const int tid = threadIdx.x;
  const int bn = blockIdx.x * 256;
  const int bm = blockIdx.y * BM;
  const int lane = tid & 63;
  const int w = tid >> 6;
  const int wr = SMALL ? 0 : (w >> 2);
  const int wc = SMALL ? w : (w & 3);
  const int subrow = lane >> 3;
  const int kd = 8 * ((lane & 7) ^ subrow);

  const bool half2 = (MODE == 4) && (bm >= Msplit);
  const unsigned short* Wb = Wt + (half2 ? 256 * 256 : 0);

  unsigned int offB[BQ];
#pragma unroll
  for (int q = 0; q < BQ; ++q)
    offB[q] = (unsigned)(bn + w * (BQ * 8) + q * 8 + subrow) * (unsigned)Kp;

  unsigned int offA[2];
#pragma unroll
  for (int q = 0; q < 2; ++q) {
    int m = bm + w * 16 + q * 8 + subrow;
    int mc = (m < M) ? m : (M - 1);
    offA[q] = (unsigned)mc * 256u;
  }

  const int nt = Kp >> 6;
  f32x4 acc[4][4] = {};

  for (int t = 0; t < nt; ++t) {
    const int k0 = t << 6;
#pragma unroll
    for (int q = 0; q < 2; ++q) {
      const unsigned short* gp;
      if (MODE == 2) gp = (k0 < 256) ? (A + offA[q] + k0 + kd) : (A2 + offA[q] + (k0 - 256) + kd);
      else gp = A + offA[q] + k0 + kd;
      gload16(gp, (char*)As + w * 2048 + q * 1024);
    }
#pragma unroll
    for (int q = 0; q < BQ; ++q)
      gload16(Wb + offB[q] + k0 + kd, (char*)Bs + w * (BQ * 1024) + q * 1024);
    __syncthreads();
#pragma unroll
    for (int ks = 0; ks < 2; ++ks) {
      const int kb = (ks * 64 + ((lane >> 4) << 4)) ^ ((lane & 7) << 4);
      bf16x8 bfv[4];
#pragma unroll
      for (int j = 0; j < 4; ++j)
        bfv[j] = *(const bf16x8*)((const char*)Bs + (wc * 64 + j * 16 + (lane & 15)) * 128 + kb);
#pragma unroll
      for (int i = 0; i < 4; ++i) {
        bf16x8 af = *(const bf16x8*)((const char*)As + (wr * 64 + i * 16 + (lane & 15)) * 128 + kb);
#pragma unroll
        for (int j = 0; j < 4; ++j)
          acc[i][j] = __builtin_amdgcn_mfma_f32_16x16x32_bf16(af, bfv[j], acc[i][j], 0, 0, 0);
      }
    }
    __syncthreads();
  }

  if (GATE) {
    float bcol[4], wcol[4];
#pragma unroll
    for (int j = 0; j < 4; ++j) {
      int col = wc * 64 + j * 16 + (lane & 15);
      bcol[j] = bias[col];
      wcol[j] = gw2[col];
    }
    float* part = (float*)lds;
#pragma unroll
    for (int i = 0; i < 4; ++i) {
#pragma unroll
      for (int q = 0; q < 4; ++q) {
        float lsum = 0.f;
#pragma unroll
        for (int j = 0; j < 4; ++j)
          lsum += silu_f(acc[i][j][q] + bcol[j]) * wcol[j];
        lsum += __shfl_xor(lsum, 1, 64);
        lsum += __shfl_xor(lsum, 2, 64);
        lsum += __shfl_xor(lsum, 4, 64);
        lsum += __shfl_xor(lsum, 8, 64);
        if ((lane & 15) == 0) {
          int rl = wr * 64 + i * 16 + ((lane >> 4) << 2) + q;
          part[wc * BM + rl] = lsum;
        }
      }
    }
    __syncthreads();
    if (tid < BM)
      gout[bm + tid] = part[tid] + part[BM + tid] + part[2*BM + tid] + part[3*BM + tid];
    return;
  }

  if (LNOUT) {
    float bcol[4], lgc[4], lbc[4];
#pragma unroll
    for (int j = 0; j < 4; ++j) {
      int col = wc * 64 + j * 16 + (lane & 15);
      bcol[j] = bias[col]; lgc[j] = lng[col]; lbc[j] = lnb[col];
    }
    float* part = (float*)lds;
    float* stat = part + 4 * BM;
#pragma unroll
    for (int i = 0; i < 4; ++i)
#pragma unroll
      for (int q = 0; q < 4; ++q) {
        int rl = wr * 64 + i * 16 + ((lane >> 4) << 2) + q;
        int grow = bm + rl;
        float s = 0.f;
#pragma unroll
        for (int j = 0; j < 4; ++j) {
          int col = wc * 64 + j * 16 + (lane & 15);
          float hv = (grow < M) ? hf[(size_t)grow * 256 + col] : 0.f;
          float zz = acc[i][j][q] + bcol[j] + hv;
          acc[i][j][q] = zz;
          s += zz;
        }
        s += __shfl_xor(s, 1, 64); s += __shfl_xor(s, 2, 64);
        s += __shfl_xor(s, 4, 64); s += __shfl_xor(s, 8, 64);
        if ((lane & 15) == 0) part[wc * BM + rl] = s;
      }
    __syncthreads();
    if (tid < BM)
      stat[tid] = (part[tid] + part[BM + tid] + part[2*BM + tid] + part[3*BM + tid]) * (1.f / 256.f);
    __syncthreads();
#pragma unroll
    for (int i = 0; i < 4; ++i)
#pragma unroll
      for (int q = 0; q < 4; ++q) {
        int rl = wr * 64 + i * 16 + ((lane >> 4) << 2) + q;
        float mu = stat[rl];
        float s2 = 0.f;
#pragma unroll
        for (int j = 0; j < 4; ++j) { float d_ = acc[i][j][q] - mu; s2 += d_ * d_; }
        s2 += __shfl_xor(s2, 1, 64); s2 += __shfl_xor(s2, 2, 64);
        s2 += __shfl_xor(s2, 4, 64); s2 += __shfl_xor(s2, 8, 64);
        if ((lane & 15) == 0) part[wc * BM + rl] = s2;
      }
    __syncthreads();
    if (tid < BM)
      stat[BM + tid] = 1.f / sqrtf((part[tid] + part[BM + tid] + part[2*BM + tid] + part[3*BM + tid]) * (1.f / 256.f) + 1e-5f);
    __syncthreads();
#pragma unroll
    for (int i = 0; i < 4; ++i)
#pragma unroll
      for (int q = 0; q < 4; ++q) {
        int rl = wr * 64 + i * 16 + ((lane >> 4) << 2) + q;
        int grow = bm + rl;
        if (grow < M) {
          float mu = stat[rl], rs = stat[BM + rl];
#pragma unroll
          for (int j = 0; j < 4; ++j) {
            int col = wc * 64 + j * 16 + (lane & 15);
            float o = (acc[i][j][q] - mu) * rs * lgc[j] + lbc[j];
            hf[(size_t)grow * 256 + col] = o;
            hb[(size_t)grow * 256 + col] = f2bf(o);
          }
        }
      }
    return;
  }

  // normal epilogue
  const float* biasw = bias;
  unsigned short* Cw = C;
  int rowoff = 0;
  if (MODE == 3) Cw = C + (size_t)(bn >> 8) * (size_t)M * 256;
  if (MODE == 4 && half2) { biasw = bias2; Cw = C2; rowoff = Msplit; }

  float bcol[4];
#pragma unroll
  for (int j = 0; j < 4; ++j) bcol[j] = biasw[wc * 64 + j * 16 + (lane & 15)];

  unsigned short* T = lds;
#pragma unroll
  for (int hh = 0; hh < 2; ++hh) {
    if ((wc >> 1) == hh) {
#pragma unroll
      for (int i = 0; i < 4; ++i)
#pragma unroll
        for (int j = 0; j < 4; ++j)
#pragma unroll
          for (int q = 0; q < 4; ++q) {
            int rl = wr * 64 + i * 16 + ((lane >> 4) << 2) + q;
            int cl = (wc & 1) * 64 + j * 16 + (lane & 15);
            float v = acc[i][j][q] + bcol[j];
            if (SILU) v = silu_f(v);
            T[rl * 136 + cl] = f2bf(v);
          }
    }
    __syncthreads();
#pragma unroll
    for (int it = 0; it < 4; ++it) {
      int row = it * (BM / 4) + (tid >> 4);
      int grow = bm + row;
      if (grow < M) {
        uint4 v = *(const uint4*)&T[row * 136 + (tid & 15) * 8];
        *(uint4*)&Cw[(size_t)(grow - rowoff) * 256 + hh * 128 + (tid & 15) * 8] = v;
      }
    }
    __syncthreads();
  }
}

// ---------------- fused node update: u1 = silu([h,pm]@W1+b1); h = LN(h + u1@W2 + b2) ----------------
// 256 threads, BM=64, BN=256. u1 kept in LDS (bf16, [64][264]).
__global__ __launch_bounds__(256, 2) void upd_fused_kernel(
    const unsigned short* __restrict__ hbf, const unsigned short* __restrict__ pmbf,
    const unsigned short* __restrict__ W1t,   // [256][512]
    const unsigned short* __restrict__ W2t,   // [256][256]
    const float* __restrict__ b1, const float* __restrict__ b2,
    float* __restrict__ hf, unsigned short* __restrict__ hb,
    const float* __restrict__ lng, const float* __restrict__ lnb, int M) {
  __shared__ unsigned short lds[16384 + 16896];   // Bs [256][64] | T [64][264]
  unsigned short* Bs = lds;
  unsigned short* As = lds + 16384;               // phase-1 A (aliases T region head)
  unsigned short* T  = lds + 16384;               // [64][264] u1 bf16
  const int tid = threadIdx.x;
  const int bm = blockIdx.y * 64;
  const int lane = tid & 63;
  const int w = tid >> 6;                         // 0..3 (col band)
  const int subrow = lane >> 3;
  const int kd = 8 * ((lane & 7) ^ subrow);

  unsigned int offA[2];
#pragma unroll
  for (int q = 0; q < 2; ++q) {
    int m = bm + w * 16 + q * 8 + subrow;
    int mc = (m < M) ? m : (M - 1);
    offA[q] = (unsigned)mc * 256u;
  }
  unsigned int offB1[8];
#pragma unroll
  for (int q = 0; q < 8; ++q)
    offB1[q] = (unsigned)(w * 64 + q * 8 + subrow) * 512u;

  // ---- phase 1: acc = [h|pm] @ W1  (K=512) ----
  f32x4 acc[4][4] = {};
  for (int t = 0; t < 8; ++t) {
    const int k0 = t << 6;
#pragma unroll
    for (int q = 0; q < 2; ++q) {
      const unsigned short* gp = (k0 < 256) ? (hbf + offA[q] + k0 + kd)
                                            : (pmbf + offA[q] + (k0 - 256) + kd);
      gload16(gp, (char*)As + w * 2048 + q * 1024);
    }
#pragma unroll
    for (int q = 0; q < 8; ++q)
      gload16(W1t + offB1[q] + k0 + kd, (char*)Bs + w * 8192 + q * 1024);
    __syncthreads();
#pragma unroll
    for (int ks = 0; ks < 2; ++ks) {
      const int kb = (ks * 64 + ((lane >> 4) << 4)) ^ ((lane & 7) << 4);
      bf16x8 bfv[4];
#pragma unroll
      for (int j = 0; j < 4; ++j)
        bfv[j] = *(const bf16x8*)((const char*)Bs + (w * 64 + j * 16 + (lane & 15)) * 128 + kb);
#pragma unroll
      for (int i = 0; i < 4; ++i) {
        bf16x8 af = *(const bf16x8*)((const char*)As + (i * 16 + (lane & 15)) * 128 + kb);
#pragma unroll
        for (int j = 0; j < 4; ++j)
          acc[i][j] = __builtin_amdgcn_mfma_f32_16x16x32_bf16(af, bfv[j], acc[i][j], 0, 0, 0);
      }
    }
    __syncthreads();
  }

  // ---- u1 -> T (bf16, silu) ----
  {
    float bcol[4];
#pragma unroll
    for (int j = 0; j < 4; ++j) bcol[j] = b1[w * 64 + j * 16 + (lane & 15)];
#pragma unroll
    for (int i = 0; i < 4; ++i)
#pragma unroll
      for (int j = 0; j < 4; ++j)
#pragma unroll
        for (int q = 0; q < 4; ++q) {
          int rl = i * 16 + ((lane >> 4) << 2) + q;
          int cl = w * 64 + j * 16 + (lane & 15);
          T[rl * 264 + cl] = f2bf(silu_f(acc[i][j][q] + bcol[j]));
        }
  }
  __syncthreads();

  // ---- phase 2: acc2 = u1 @ W2  (K=256, A from T) ----
  unsigned int offB2[8];
#pragma unroll
  for (int q = 0; q < 8; ++q)
    offB2[q] = (unsigned)(w * 64 + q * 8 + subrow) * 256u;

  f32x4 acc2[4][4] = {};
  for (int t = 0; t < 4; ++t) {
    const int k0 = t << 6;
#pragma unroll
    for (int q = 0; q < 8; ++q)
      gload16(W2t + offB2[q] + k0 + kd, (char*)Bs + w * 8192 + q * 1024);
    __syncthreads();
#pragma unroll
    for (int ks = 0; ks < 2; ++ks) {
      const int kb = (ks * 64 + ((lane >> 4) << 4)) ^ ((lane & 7) << 4);
      const int ka = k0 + ks * 32 + ((lane >> 4) << 3);   // plain (unswizzled) A k-offset
      bf16x8 bfv[4];
#pragma unroll
      for (int j = 0; j < 4; ++j)
        bfv[j] = *(const bf16x8*)((const char*)Bs + (w * 64 + j * 16 + (lane & 15)) * 128 + kb);
#pragma unroll
      for (int i = 0; i < 4; ++i) {
        bf16x8 af = *(const bf16x8*)&T[(i * 16 + (lane & 15)) * 264 + ka];
#pragma unroll
        for (int j = 0; j < 4; ++j)
          acc2[i][j] = __builtin_amdgcn_mfma_f32_16x16x32_bf16(af, bfv[j], acc2[i][j], 0, 0, 0);
      }
    }
    __syncthreads();
  }

  // ---- LN epilogue (identical math to LNOUT path) ----
  {
    float bcol[4], lgc[4], lbc[4];
#pragma unroll
    for (int j = 0; j < 4; ++j) {
      int col = w * 64 + j * 16 + (lane & 15);
      bcol[j] = b2[col]; lgc[j] = lng[col]; lbc[j] = lnb[col];
    }
    float* part = (float*)lds;       // overlaps Bs (dead)
    float* stat = part + 256;
#pragma unroll
    for (int i = 0; i < 4; ++i)
#pragma unroll
      for (int q = 0; q < 4; ++q) {
        int rl = i * 16 + ((lane >> 4) << 2) + q;
        int grow = bm + rl;
        float s = 0.f;
#pragma unroll
        for (int j = 0; j < 4; ++j) {
          int col = w * 64 + j * 16 + (lane & 15);
          float hv = (grow < M) ? hf[(size_t)grow * 256 + col] : 0.f;
          float zz = acc2[i][j][q] + bcol[j] + hv;
          acc2[i][j][q] = zz;
          s += zz;
        }
        s += __shfl_xor(s, 1, 64); s += __shfl_xor(s, 2, 64);
        s += __shfl_xor(s, 4, 64); s += __shfl_xor(s, 8, 64);
        if ((lane & 15) == 0) part[w * 64 + rl] = s;
      }
    __syncthreads();
    if (tid < 64)
      stat[tid] = (part[tid] + part[64 + tid] + part[128 + tid] + part[192 + tid]) * (1.f / 256.f);
    __syncthreads();
#pragma unroll
    for (int i = 0; i < 4; ++i)
#pragma unroll
      for (int q = 0; q < 4; ++q) {
        int rl = i * 16 + ((lane >> 4) << 2) + q;
        float mu = stat[rl];
        float s2 = 0.f;
#pragma unroll
        for (int j = 0; j < 4; ++j) { float d_ = acc2[i][j][q] - mu; s2 += d_ * d_; }
        s2 += __shfl_xor(s2, 1, 64); s2 += __shfl_xor(s2, 2, 64);
        s2 += __shfl_xor(s2, 4, 64); s2 += __shfl_xor(s2, 8, 64);
        if ((lane & 15) == 0) part[w * 64 + rl] = s2;
      }
    __syncthreads();
    if (tid < 64)
      stat[64 + tid] = 1.f / sqrtf((part[tid] + part[64 + tid] + part[128 + tid] + part[192 + tid]) * (1.f / 256.f) + 1e-5f);
    __syncthreads();
#pragma unroll
    for (int i = 0; i < 4; ++i)
#pragma unroll
      for (int q = 0; q < 4; ++q) {
        int rl = i * 16 + ((lane >> 4) << 2) + q;
        int grow = bm + rl;
        if (grow < M) {
          float mu = stat[rl], rs = stat[64 + rl];
#pragma unroll
          for (int j = 0; j < 4; ++j) {
            int col = w * 64 + j * 16 + (lane & 15);
            float o = (acc2[i][j][q] - mu) * rs * lgc[j] + lbc[j];
            hf[(size_t)grow * 256 + col] = o;
            hb[(size_t)grow * 256 + col] = f2bf(o);
          }
        }
      }
  }
}

// ---------------- CSR gather ----------------
__global__ void gather_pm_dx(const unsigned short* __restrict__ pm, const float* __restrict__ gate,
                             const float* __restrict__ xcur, const int* __restrict__ srcp,
                             const int* __restrict__ rowstart, const int* __restrict__ eids,
                             const float* __restrict__ gb2,
                             unsigned short* __restrict__ pmbf, float* __restrict__ xnxt) {
  int n = blockIdx.x, k = threadIdx.x;
  int s = rowstart[n], e1 = rowstart[n + 1];
  float acc = 0.f, dx = 0.f;
  float b2 = gb2[0];
  float xn = (k < 3) ? xcur[n*3 + k] : 0.f;
  for (int t = s; t < e1; ++t) {
    int e = eids[t];
    acc += bf2f(pm[(size_t)e*HID + k]);
    if (k < 3) dx += (xn - xcur[srcp[e]*3 + k]) * (gate[e] + b2);
  }
  pmbf[(size_t)n*HID + k] = f2bf(acc);
  if (k < 3) xnxt[n*3 + k] = xn + dx;
}

// ---------------- fused readout ----------------
__global__ void readout_kernel(const float* __restrict__ h, const int* __restrict__ gstart,
                               const float* __restrict__ head_W, const float* __restrict__ head_b,
                               float* __restrict__ out) {
  int g = blockIdx.x, k = threadIdx.x;
  int s = gstart[g], e = gstart[g + 1];
  float acc = 0.f;
  for (int n = s; n < e; ++n) acc += h[(size_t)n * HID + k];
  float v = acc * head_W[k];
  __shared__ float red[4];
  int lane = k & 63, wv = k >> 6;
#pragma unroll
  for (int off = 32; off > 0; off >>= 1) v += __shfl_down(v, off, 64);
  if (lane == 0) red[wv] = v;
  __syncthreads();
  if (k == 0) {
    float dot = red[0] + red[1] + red[2] + red[3];
    float c = fmaxf((float)(e - s), 1.0f);
    float val = (dot / c + head_b[0]) * 0.5f;
    out[g] = __fdividef(1.0f, 1.0f + __expf(-val));
  }
}

extern "C" void kernel_launch(void* const* d_in, const int* in_sizes, int n_in,
                              void* d_out, int out_size, void* d_ws, size_t ws_size,
                              hipStream_t stream) {
  (void)in_sizes; (void)n_in; (void)out_size; (void)ws_size;
  const float* a_t      = (const float*)d_in[0];
  const float* c_t      = (const float*)d_in[1];
  const float* e_t      = (const float*)d_in[2];
  const float* x_t      = (const float*)d_in[3];
  const float* g_a      = (const float*)d_in[4];
  const float* g_c      = (const float*)d_in[5];
  const float* g_e      = (const float*)d_in[6];
  const float* atom_W   = (const float*)d_in[7];
  const float* charge_W = (const float*)d_in[8];
  const float* bond_W   = (const float*)d_in[9];
  const float* fuse_W   = (const float*)d_in[10];
  const float* fuse_b   = (const float*)d_in[11];
  const float* lift_W   = (const float*)d_in[12];
  const float* lift_b   = (const float*)d_in[13];
  const float* phim_W1  = (const float*)d_in[14];
  const float* phim_b1  = (const float*)d_in[15];
  const float* phim_W2  = (const float*)d_in[16];
  const float* phim_b2  = (const float*)d_in[17];
  const float* phix_W1  = (const float*)d_in[18];
  const float* phix_b1  = (const float*)d_in[19];
  const float* phix_W2  = (const float*)d_in[20];
  const float* phix_b2  = (const float*)d_in[21];
  const float* psim_W1  = (const float*)d_in[22];
  const float* psim_b1  = (const float*)d_in[23];
  const float* psim_W2  = (const float*)d_in[24];
  const float* psim_b2  = (const float*)d_in[25];
  const float* updh_W1  = (const float*)d_in[26];
  const float* updh_b1  = (const float*)d_in[27];
  const float* updh_W2  = (const float*)d_in[28];
  const float* updh_b2  = (const float*)d_in[29];
  const float* ln_g     = (const float*)d_in[30];
  const float* ln_b     = (const float*)d_in[31];
  const float* head_W   = (const float*)d_in[32];
  const float* head_b   = (const float*)d_in[33];
  const int*   src      = (const int*)d_in[34];
  const int*   dst      = (const int*)d_in[35];
  const int*   ngraph   = (const int*)d_in[36];
  float* out = (float*)d_out;

  char* p = (char*)d_ws;
  auto carve = [&](size_t bytes) -> char* {
    char* r = p; p += (bytes + 255) & ~(size_t)255; return r;
  };
  float*          h     = (float*)carve((size_t)NN*HID*4);
  unsigned short* hbf   = (unsigned short*)carve((size_t)NN*HID*2);
  float*          xposA = (float*)carve((size_t)NN*3*4);
  float*          xposB = (float*)carve((size_t)NN*3*4);
  int*            ie    = (int*)carve((size_t)NE*4);
  float*          tabA  = (float*)carve((size_t)KA*HID*4);
  float*          tabC  = (float*)carve((size_t)KC*HID*4);
  float*          tabEf = (float*)carve((size_t)KE*HID*4);
  float*          gate  = (float*)carve((size_t)NE*4);
  unsigned short* pmbf  = (unsigned short*)carve((size_t)NN*HID*2);
  float*          zbias = (float*)carve(256*4);
  unsigned short* buf01 = (unsigned short*)carve((size_t)2*NE*HID*2);
  unsigned short* bufM  = (unsigned short*)carve((size_t)NE*HID*2);
  unsigned short* bufPM = (unsigned short*)carve((size_t)NE*HID*2);
  unsigned short* P     = (unsigned short*)carve((size_t)4*NN*HID*2);
  int* deg      = (int*)carve(10240*4);
  int* cursor   = (int*)carve(10240*4);
  int* rowstart = (int*)carve(10241*4);
  int* eids     = (int*)carve((size_t)NE*4);
  int* gstart   = (int*)carve((NG+1)*4);
  unsigned short* wNode  = (unsigned short*)carve((size_t)NDEP*1024*256*2);
  unsigned short* wMPM   = (unsigned short*)carve((size_t)NDEP*512*256*2);
  unsigned short* wPhix1 = (unsigned short*)carve((size_t)NDEP*256*256*2);
  unsigned short* wUpd1  = (unsigned short*)carve((size_t)NDEP*256*512*2);
  unsigned short* wUpd2  = (unsigned short*)carve((size_t)NDEP*256*256*2);
  unsigned short* wRbf   = (unsigned short*)carve((size_t)NDEP*16*512*2);
  unsigned int*   wRbfP  = (unsigned int*)carve((size_t)NDEP*8*512*4);
  unsigned short* tabE1  = (unsigned short*)carve((size_t)NDEP*5*512*2);

  unsigned short* c1buf = buf01;
  unsigned short* psbuf = buf01 + (size_t)NE*HID;

  convw_nodeblk<<<dim3(8,4,NDEP), 256, 0, stream>>>(phim_W1, wNode, 0,   0);
  convw_nodeblk<<<dim3(8,4,NDEP), 256, 0, stream>>>(phim_W1, wNode, 256, 256);
  convw_nodeblk<<<dim3(8,4,NDEP), 256, 0, stream>>>(psim_W1, wNode, 0,   512);
  convw_nodeblk<<<dim3(8,4,NDEP), 256, 0, stream>>>(psim_W1, wNode, 256, 768);
  convw_plain<<<dim3(8,4,NDEP), 256, 0, stream>>>(phim_W2, wMPM, 256, 512*256, 0);
  convw_plain<<<dim3(8,4,NDEP), 256, 0, stream>>>(psim_W2, wMPM, 256, 512*256, 256);
  convw_plain<<<dim3(8,4,NDEP), 256, 0, stream>>>(phix_W1, wPhix1, 256, 256*256, 0);
  convw_plain<<<dim3(8,4,NDEP), 256, 0, stream>>>(updh_W2, wUpd2, 256, 256*256, 0);
  convw_plain<<<dim3(16,4,NDEP), 256, 0, stream>>>(updh_W1, wUpd1, 512, 256*512, 0);
  convw_rbf<<<NDEP, 512, 0, stream>>>(phim_W1, psim_W1, wRbf);
  convw_rbf2<<<NDEP, 512, 0, stream>>>(phim_W1, psim_W1, wRbfP);
  hipMemsetAsync(zbias, 0, 256*4, stream);

  tables_kernel<<<KA + KC + KE, 256, 0, stream>>>(atom_W, charge_W, bond_W, fuse_W, fuse_b,
                                                  lift_W, lift_b, tabA, tabC, tabEf);
  tabe1_kernel<<<dim3(5, NDEP), 512, 0, stream>>>(tabEf, phim_W1, phim_b1, psim_W1, psim_b1, tabE1);
  node_init_kernel<<<NN, 256, 0, stream>>>(a_t, c_t, g_a, g_c, x_t, tabA, tabC, h, hbf, xposA);
  edge_init_kernel<<<(NE + 255)/256, 256, 0, stream>>>(e_t, g_e, ie);

  hipMemsetAsync(deg, 0, 10240*4, stream);
  hist_kernel<<<(NE + 255)/256, 256, 0, stream>>>(dst, deg);
  scan_kernel<<<1, 1024, 0, stream>>>(deg, rowstart, cursor);
  fill_kernel<<<(NE + 255)/256, 256, 0, stream>>>(dst, cursor, eids);
  sortrows_kernel<<<(NN + 255)/256, 256, 0, stream>>>(rowstart, eids);
  gbound_kernel<<<(NN + 255)/256, 256, 0, stream>>>(ngraph, gstart);

  dim3 gridP(4, (NN + 63)/64);
  dim3 gridE(1, NE/128);
  dim3 gridE2(1, 2*NE/128);
  dim3 gridNU(1, (NN + 63)/64);

  float* xcur = xposA;
  float* xnxt = xposB;

  for (int d = 0; d < NDEP; ++d) {
    const float* pb2m = phim_b2 + (size_t)d*HID;
    const float* pxb1 = phix_b1 + (size_t)d*HID;
    const float* pxW2 = phix_W2 + (size_t)d*HID;
    const float* pxb2 = phix_b2 + (size_t)d;
    const float* psb2 = psim_b2 + (size_t)d*HID;
    const float* pub1 = updh_b1 + (size_t)d*HID;
    const float* pub2 = updh_b2 + (size_t)d*HID;

    // P = h @ [W1_phim_dst | W1_phim_src | W1_psim_dst | W1_psim_src]
    mfma_gemm<3, false, false, false, true><<<gridP, 256, 0, stream>>>(
        hbf, nullptr, wNode + (size_t)d*1024*256, zbias, nullptr, P, nullptr, NN, 256, 0,
        nullptr, nullptr, nullptr, nullptr, nullptr, nullptr);
    // c1, ps1
    combine2_kernel<<<NE/4, 256, 0, stream>>>(
        src, dst, ie, xcur, P, tabE1 + (size_t)d*5*512, wRbf + (size_t)d*16*512,
        wRbfP + (size_t)d*8*512, c1buf, psbuf);
    // merged m / pm
    mfma_gemm<4, true, false, false, false><<<gridE2, 512, 0, stream>>>(
        buf01, nullptr, wMPM + (size_t)d*512*256, pb2m, psb2, bufM, bufPM, 2*NE, 256, NE,
        nullptr, nullptr, nullptr, nullptr, nullptr, nullptr);
    // gate
    mfma_gemm<0, false, true, false, false><<<gridE, 512, 0, stream>>>(
        bufM, nullptr, wPhix1 + (size_t)d*256*256, pxb1, nullptr, nullptr, nullptr, NE, 256, 0,
        pxW2, gate, nullptr, nullptr, nullptr, nullptr);
    // pm_sum -> pmbf ; x update
    gather_pm_dx<<<NN, 256, 0, stream>>>(bufPM, gate, xcur, src, rowstart, eids, pxb2, pmbf, xnxt);
    // fused upd1 + upd2 + LN
    upd_fused_kernel<<<gridNU, 256, 0, stream>>>(
        hbf, pmbf, wUpd1 + (size_t)d*256*512, wUpd2 + (size_t)d*256*256,
        pub1, pub2, h, hbf, ln_g + (size_t)d*HID, ln_b + (size_t)d*HID, NN);

    float* tmp = xcur; xcur = xnxt; xnxt = tmp;
  }

  readout_kernel<<<NG, 256, 0, stream>>>(h, gstart, head_W, head_b, out);
}